// Round 5
// baseline (471.334 us; speedup 1.0000x reference)
//
#include <hip/hip_runtime.h>
#include <cstdint>

#define D 128
#define GG 64
#define SLICES 16
#define NPASS 4

typedef short bf16x8 __attribute__((ext_vector_type(8)));
typedef float f32x4 __attribute__((ext_vector_type(4)));

// ---------- bf16 helpers ----------
__device__ inline unsigned short bf16u(float f) {
  unsigned u = __float_as_uint(f);
  u = (u + 0x7FFFu + ((u >> 16) & 1u)) >> 16;
  return (unsigned short)u;
}
__device__ inline float2 unpackbf2(unsigned u) {
  return make_float2(__uint_as_float(u << 16), __uint_as_float(u & 0xFFFF0000u));
}

// ======================= CSR build =======================
__global__ void count_edges_k(const int* __restrict__ dst, int* __restrict__ cnt, int E) {
  int e = blockIdx.x * blockDim.x + threadIdx.x;
  if (e < E) atomicAdd(&cnt[dst[e]], 1);
}

__global__ void bounds_init_k(int* __restrict__ gstart, int* __restrict__ gend) {
  int g = threadIdx.x;
  gstart[g] = 0;
  gend[g] = 0;
}

__global__ void graph_bounds_k(const int* __restrict__ batch, int* __restrict__ gstart,
                               int* __restrict__ gend, int n) {
  int i = blockIdx.x * blockDim.x + threadIdx.x;
  if (i >= n) return;
  int b = batch[i];
  if (i == 0) {
    gstart[b] = 0;
  } else {
    int pb = batch[i - 1];
    if (pb != b) { gstart[b] = i; gend[pb] = i; }
  }
  if (i == n - 1) gend[b] = n;
}

__global__ void gcnt_k(const int* __restrict__ gstart, const int* __restrict__ gend,
                       int* __restrict__ gcnt) {
  int g = threadIdx.x;
  gcnt[g] = gend[g] - gstart[g];
}

__global__ __launch_bounds__(256) void scan1_k(const int* __restrict__ cnt, int* __restrict__ rp,
                                               int* __restrict__ bsum, int n) {
  __shared__ int sd[256];
  int t = threadIdx.x;
  int i = blockIdx.x * 256 + t;
  int v = (i < n) ? cnt[i] : 0;
  sd[t] = v;
  __syncthreads();
#pragma unroll
  for (int off = 1; off < 256; off <<= 1) {
    int u = (t >= off) ? sd[t - off] : 0;
    __syncthreads();
    sd[t] += u;
    __syncthreads();
  }
  if (i < n) rp[i] = sd[t] - v;
  if (t == 255) bsum[blockIdx.x] = sd[255];
}

__global__ __launch_bounds__(256) void scan2_k(int* __restrict__ bsum, int nb) {
  __shared__ int sd[256];
  int t = threadIdx.x;
  int v = (t < nb) ? bsum[t] : 0;
  sd[t] = v;
  __syncthreads();
#pragma unroll
  for (int off = 1; off < 256; off <<= 1) {
    int u = (t >= off) ? sd[t - off] : 0;
    __syncthreads();
    sd[t] += u;
    __syncthreads();
  }
  if (t < nb) bsum[t] = sd[t] - v;
}

__global__ __launch_bounds__(256) void scan3_k(int* __restrict__ rp, const int* __restrict__ bsum,
                                               int* __restrict__ cur, int n, int E) {
  int i = blockIdx.x * 256 + threadIdx.x;
  if (i < n) {
    int r = rp[i] + bsum[blockIdx.x];
    rp[i] = r;
    cur[i] = r;
  }
  if (i == 0) rp[n] = E;
}

// Multi-pass fill: pass p only handles dst in [p*slice,(p+1)*slice) so the
// col/cur working set per pass is L2-resident -> scatter lines assembled in L2,
// written back once (kills the 64B write-allocate amplification).
__global__ __launch_bounds__(256) void fill_csr_mp_k(const int* __restrict__ src,
                                                     const int* __restrict__ dst,
                                                     int* __restrict__ cur, int* __restrict__ col,
                                                     int E, int slice, int chunks) {
  int pass = blockIdx.x / chunks;
  int e = (blockIdx.x % chunks) * 256 + threadIdx.x;
  if (e >= E) return;
  int d = dst[e];
  if (d >= pass * slice && d < (pass + 1) * slice) {
    int p = atomicAdd(&cur[d], 1);
    col[p] = src[e];
  }
}

__global__ void dinv_k(const int* __restrict__ cnt, float* __restrict__ dinv, int n) {
  int i = blockIdx.x * blockDim.x + threadIdx.x;
  if (i < n) dinv[i] = rsqrtf((float)cnt[i] + 1.0f);
}

// ======================= bf16 cast =======================
__global__ void cast_bf16_k(const float* __restrict__ in, unsigned short* __restrict__ outp, int n4) {
  int i = blockIdx.x * blockDim.x + threadIdx.x;
  if (i >= n4) return;
  float4 v = ((const float4*)in)[i];
  ushort4 o;
  o.x = bf16u(v.x); o.y = bf16u(v.y); o.z = bf16u(v.z); o.w = bf16u(v.w);
  ((ushort4*)outp)[i] = o;
}

// ======================= Weight pack into MFMA B-fragment order =======================
__global__ void packB_k(const float* __restrict__ B, unsigned short* __restrict__ Bp, int ldb, int ct) {
  int idx = blockIdx.x * 256 + threadIdx.x;
  if (idx >= ct * 256) return;
  int lane = idx & 63;
  int kc = (idx >> 6) & 3;
  int c = idx >> 8;
  int kb = kc * 32 + (lane >> 4) * 8;
  int colq = c * 16 + (lane & 15);
  unsigned short o[8];
#pragma unroll
  for (int j = 0; j < 8; ++j) o[j] = bf16u(B[(size_t)(kb + j) * ldb + colq]);
  uint4 p;
  p.x = (unsigned)o[0] | ((unsigned)o[1] << 16);
  p.y = (unsigned)o[2] | ((unsigned)o[3] << 16);
  p.z = (unsigned)o[4] | ((unsigned)o[5] << 16);
  p.w = (unsigned)o[6] | ((unsigned)o[7] << 16);
  *(uint4*)&Bp[(size_t)idx * 8] = p;
}

// ======================= MFMA GEMM: [M,128]x[128,128] =======================
__global__ __launch_bounds__(256) void gemm_mfma_k(const unsigned short* __restrict__ Ab,
                                                   const unsigned short* __restrict__ Bp,
                                                   const float* __restrict__ bias,
                                                   float* __restrict__ Cf,
                                                   unsigned short* __restrict__ Cb, int M) {
  __shared__ unsigned short Bs[16384];
  int t = threadIdx.x;
  for (int i = t; i < 2048; i += 256) ((uint4*)Bs)[i] = ((const uint4*)Bp)[i];
  __syncthreads();
  int w = t >> 6, lane = t & 63;
  int row0 = blockIdx.x * 64 + w * 16;
  int arow = row0 + (lane & 15);
  f32x4 acc[8];
#pragma unroll
  for (int c = 0; c < 8; ++c) acc[c] = {0.f, 0.f, 0.f, 0.f};
#pragma unroll
  for (int kc = 0; kc < 4; ++kc) {
    bf16x8 a = {0, 0, 0, 0, 0, 0, 0, 0};
    if (arow < M) a = *(const bf16x8*)&Ab[(size_t)arow * 128 + kc * 32 + (lane >> 4) * 8];
#pragma unroll
    for (int c = 0; c < 8; ++c) {
      bf16x8 b = *(const bf16x8*)&Bs[((c * 4 + kc) * 64 + lane) * 8];
      acc[c] = __builtin_amdgcn_mfma_f32_16x16x32_bf16(a, b, acc[c], 0, 0, 0);
    }
  }
  int rbase = row0 + (lane >> 4) * 4;
#pragma unroll
  for (int c = 0; c < 8; ++c) {
    int colq = c * 16 + (lane & 15);
    float bb = bias ? bias[colq] : 0.f;
#pragma unroll
    for (int r = 0; r < 4; ++r) {
      int row = rbase + r;
      if (row < M) {
        float v = acc[c][r] + bb;
        if (Cf) Cf[(size_t)row * 128 + colq] = v;
        if (Cb) Cb[(size_t)row * 128 + colq] = bf16u(v);
      }
    }
  }
}

// ======================= GCN aggregation (bf16 gathers, 8-way + predicated tail) ============
__global__ __launch_bounds__(256) void gcn_gather_k(const unsigned* __restrict__ xwb,
                                                    const int* __restrict__ rp, const int* __restrict__ col,
                                                    const float* __restrict__ dinv, const float* __restrict__ bias,
                                                    float* __restrict__ out, int n) {
  int i = blockIdx.x * 4 + (threadIdx.x >> 6);
  if (i >= n) return;
  int lane = threadIdx.x & 63;
  int e0 = __builtin_amdgcn_readfirstlane(rp[i]);
  int e1 = __builtin_amdgcn_readfirstlane(rp[i + 1]);
  float di = dinv[i];
  float2 sv = unpackbf2(xwb[(size_t)i * 64 + lane]);
  float ax[4], ay[4];
  ax[0] = sv.x * di * di; ay[0] = sv.y * di * di;
  ax[1] = ax[2] = ax[3] = ay[1] = ay[2] = ay[3] = 0.f;
  for (int e = e0; e < e1; e += 8) {
    int s[8]; float w[8];
#pragma unroll
    for (int j = 0; j < 8; ++j) {
      bool ok = (e + j < e1);
      s[j] = ok ? __builtin_amdgcn_readfirstlane(col[e + j]) : i;
      w[j] = ok ? dinv[s[j]] * di : 0.f;
    }
    float2 v[8];
#pragma unroll
    for (int j = 0; j < 8; ++j) v[j] = unpackbf2(xwb[(size_t)s[j] * 64 + lane]);
#pragma unroll
    for (int j = 0; j < 8; ++j) { ax[j & 3] += v[j].x * w[j]; ay[j & 3] += v[j].y * w[j]; }
  }
  float2 bb = ((const float2*)bias)[lane];
  ((float2*)out)[(size_t)i * 64 + lane] =
      make_float2(ax[0] + ax[1] + ax[2] + ax[3] + bb.x, ay[0] + ay[1] + ay[2] + ay[3] + bb.y);
}

// ======================= GAT attention coefficients (bf16 input) =======================
__global__ void attn_coef_k(const unsigned short* __restrict__ hb, const float* __restrict__ a_s,
                            const float* __restrict__ a_d, float* __restrict__ es,
                            float* __restrict__ ed, int n) {
  int idx = blockIdx.x * blockDim.x + threadIdx.x;
  if (idx >= n * 4) return;
  int node = idx >> 2, hh = idx & 3;
  const uint4* hr = (const uint4*)(hb + (size_t)node * 128 + hh * 32);
  const float4* av = (const float4*)(a_s + hh * 32);
  const float4* dv = (const float4*)(a_d + hh * 32);
  float s = 0.f, d2 = 0.f;
#pragma unroll
  for (int q = 0; q < 4; ++q) {
    uint4 u = hr[q];
    float2 p0 = unpackbf2(u.x), p1 = unpackbf2(u.y), p2 = unpackbf2(u.z), p3 = unpackbf2(u.w);
    float4 a0 = av[q * 2], a1 = av[q * 2 + 1];
    float4 d0 = dv[q * 2], d1 = dv[q * 2 + 1];
    s  += p0.x * a0.x + p0.y * a0.y + p1.x * a0.z + p1.y * a0.w
        + p2.x * a1.x + p2.y * a1.y + p3.x * a1.z + p3.y * a1.w;
    d2 += p0.x * d0.x + p0.y * d0.y + p1.x * d0.z + p1.y * d0.w
        + p2.x * d1.x + p2.y * d1.y + p3.x * d1.z + p3.y * d1.w;
  }
  es[idx] = s;
  ed[idx] = d2;
}

// ======================= GAT alpha precompute (unnormalized; winv factored out) ==============
__global__ __launch_bounds__(256) void alpha_k(const float* __restrict__ es, const float* __restrict__ ed,
                                               const int* __restrict__ rp, const int* __restrict__ col,
                                               float* __restrict__ alpha, float* __restrict__ aself,
                                               float* __restrict__ winv, int n) {
  int i = blockIdx.x * 4 + (threadIdx.x >> 6);
  if (i >= n) return;
  int lane = threadIdx.x & 63;
  int hh = lane >> 4, slot = lane & 15;
  int e0 = __builtin_amdgcn_readfirstlane(rp[i]);
  int e1 = __builtin_amdgcn_readfirstlane(rp[i + 1]);
  float edi = ed[i * 4 + hh];
  float esf = es[i * 4 + hh] + edi;
  esf = esf >= 0.f ? esf : 0.2f * esf;
  float m = esf;
  for (int e = e0 + slot; e < e1; e += 16) {
    int sj = col[e];
    float ev = es[sj * 4 + hh] + edi;
    ev = ev >= 0.f ? ev : 0.2f * ev;
    alpha[(size_t)e * 4 + hh] = ev;
    m = fmaxf(m, ev);
  }
#pragma unroll
  for (int off = 1; off < 16; off <<= 1) m = fmaxf(m, __shfl_xor(m, off, 64));
  float s = (slot == 0) ? __expf(esf - m) : 0.f;
  for (int e = e0 + slot; e < e1; e += 16) {
    float w = __expf(alpha[(size_t)e * 4 + hh] - m);
    alpha[(size_t)e * 4 + hh] = w;
    s += w;
  }
#pragma unroll
  for (int off = 1; off < 16; off <<= 1) s += __shfl_xor(s, off, 64);
  if (slot == 0) {
    aself[i * 4 + hh] = __expf(esf - m);
    winv[i * 4 + hh] = 1.0f / (s + 1e-16f);
  }
}

// ======================= GAT gather (bf16, unnormalized alpha, 8-way + tail) ================
__global__ __launch_bounds__(256) void gat_gather_k(const unsigned* __restrict__ hfb,
                                                    const int* __restrict__ rp, const int* __restrict__ col,
                                                    const float* __restrict__ alpha, const float* __restrict__ aself,
                                                    const float* __restrict__ winv,
                                                    const float* __restrict__ bias, float* __restrict__ out, int n) {
  int i = blockIdx.x * 4 + (threadIdx.x >> 6);
  if (i >= n) return;
  int lane = threadIdx.x & 63;
  int hh = lane >> 4;
  int e0 = __builtin_amdgcn_readfirstlane(rp[i]);
  int e1 = __builtin_amdgcn_readfirstlane(rp[i + 1]);
  float2 sv = unpackbf2(hfb[(size_t)i * 64 + lane]);
  float a0 = aself[i * 4 + hh];
  float ax[4], ay[4];
  ax[0] = sv.x * a0; ay[0] = sv.y * a0;
  ax[1] = ax[2] = ax[3] = ay[1] = ay[2] = ay[3] = 0.f;
  for (int e = e0; e < e1; e += 8) {
    int s[8]; float aa[8];
#pragma unroll
    for (int j = 0; j < 8; ++j) {
      bool ok = (e + j < e1);
      s[j] = ok ? __builtin_amdgcn_readfirstlane(col[e + j]) : i;
      aa[j] = ok ? alpha[(size_t)(e + j) * 4 + hh] : 0.f;
    }
    float2 v[8];
#pragma unroll
    for (int j = 0; j < 8; ++j) v[j] = unpackbf2(hfb[(size_t)s[j] * 64 + lane]);
#pragma unroll
    for (int j = 0; j < 8; ++j) { ax[j & 3] += v[j].x * aa[j]; ay[j & 3] += v[j].y * aa[j]; }
  }
  float wi = winv[i * 4 + hh];
  float2 bb = ((const float2*)bias)[lane];
  ((float2*)out)[(size_t)i * 64 + lane] =
      make_float2((ax[0] + ax[1] + ax[2] + ax[3]) * wi + bb.x,
                  (ay[0] + ay[1] + ay[2] + ay[3]) * wi + bb.y);
}

// ======================= GraphNorm =======================
__global__ __launch_bounds__(256) void gn_stats_k(const float* __restrict__ h, const int* __restrict__ gstart,
                                                  const int* __restrict__ gcnt, float* __restrict__ gsum,
                                                  float* __restrict__ gsq) {
  int g = blockIdx.x / SLICES, sl = blockIdx.x % SLICES;
  int st = gstart[g], cn = gcnt[g];
  int d = threadIdx.x & 127, half = threadIdx.x >> 7;
  float s = 0.f, ss = 0.f;
  for (int r = sl * 2 + half; r < cn; r += 2 * SLICES) {
    float v = h[(size_t)(st + r) * D + d];
    s += v; ss += v * v;
  }
  __shared__ float l1[128], l2[128];
  if (half) { l1[d] = s; l2[d] = ss; }
  __syncthreads();
  if (!half) {
    atomicAdd(&gsum[g * D + d], s + l1[d]);
    atomicAdd(&gsq[g * D + d], ss + l2[d]);
  }
}

__global__ void gn_finalize_k(const float* __restrict__ gsum, const float* __restrict__ gsq,
                              const int* __restrict__ gcnt, const float* __restrict__ ms,
                              float* __restrict__ mean, float* __restrict__ rstd) {
  int g = blockIdx.x, d = threadIdx.x;
  float cnt = fmaxf((float)gcnt[g], 1.0f);
  float mu = gsum[g * D + d] / cnt;
  float m2 = gsq[g * D + d] / cnt;
  float s = ms[d];
  float var = m2 - (2.0f * s - s * s) * mu * mu;
  mean[g * D + d] = mu;
  rstd[g * D + d] = rsqrtf(fmaxf(var, 0.0f) + 1e-5f);
}

__global__ void gn_apply_k(const float* __restrict__ h, float* __restrict__ x,
                           unsigned short* __restrict__ xb,
                           const int* __restrict__ batch, const float* __restrict__ mean,
                           const float* __restrict__ rstd, const float* __restrict__ w,
                           const float* __restrict__ b, const float* __restrict__ ms, int n) {
  int idx = blockIdx.x * blockDim.x + threadIdx.x;
  if (idx >= n * 32) return;
  int node = idx >> 5, q = idx & 31;
  int g = batch[node];
  int d0 = q * 4;
  float4 hv = ((const float4*)h)[idx];
  float4 xv = ((const float4*)x)[idx];
  float ha[4] = {hv.x, hv.y, hv.z, hv.w};
  float xa[4] = {xv.x, xv.y, xv.z, xv.w};
  float ra[4];
#pragma unroll
  for (int j = 0; j < 4; ++j) {
    int d = d0 + j;
    float sub = ha[j] - ms[d] * mean[g * D + d];
    float v = w[d] * sub * rstd[g * D + d] + b[d];
    ra[j] = fmaxf(v, 0.f) + xa[j];
  }
  ((float4*)x)[idx] = make_float4(ra[0], ra[1], ra[2], ra[3]);
  ushort4 o;
  o.x = bf16u(ra[0]); o.y = bf16u(ra[1]); o.z = bf16u(ra[2]); o.w = bf16u(ra[3]);
  ((ushort4*)xb)[idx] = o;
}

// ======================= Hub scores (MFMA) =======================
__global__ __launch_bounds__(256) void hub_mfma_k(const unsigned short* __restrict__ Xb,
                                                  const unsigned short* __restrict__ W1p,
                                                  const float* __restrict__ nb1, const float* __restrict__ nw2,
                                                  const float* __restrict__ nb2, float* __restrict__ out, int n) {
  __shared__ unsigned short Bs[8192];
  int t = threadIdx.x;
  for (int i = t; i < 1024; i += 256) ((uint4*)Bs)[i] = ((const uint4*)W1p)[i];
  __syncthreads();
  int w = t >> 6, lane = t & 63;
  int row0 = blockIdx.x * 64 + w * 16;
  int arow = row0 + (lane & 15);
  f32x4 acc[4];
#pragma unroll
  for (int c = 0; c < 4; ++c) acc[c] = {0.f, 0.f, 0.f, 0.f};
#pragma unroll
  for (int kc = 0; kc < 4; ++kc) {
    bf16x8 a = {0, 0, 0, 0, 0, 0, 0, 0};
    if (arow < n) a = *(const bf16x8*)&Xb[(size_t)arow * 128 + kc * 32 + (lane >> 4) * 8];
#pragma unroll
    for (int c = 0; c < 4; ++c) {
      bf16x8 b = *(const bf16x8*)&Bs[((c * 4 + kc) * 64 + lane) * 8];
      acc[c] = __builtin_amdgcn_mfma_f32_16x16x32_bf16(a, b, acc[c], 0, 0, 0);
    }
  }
  float b2 = nb2[0];
  float s[4] = {0.f, 0.f, 0.f, 0.f};
#pragma unroll
  for (int c = 0; c < 4; ++c) {
    int colq = c * 16 + (lane & 15);
    float b1 = nb1[colq];
    float w2 = nw2[colq];
#pragma unroll
    for (int r = 0; r < 4; ++r) s[r] += fmaxf(acc[c][r] + b1, 0.f) * w2;
  }
#pragma unroll
  for (int off = 1; off < 16; off <<= 1) {
#pragma unroll
    for (int r = 0; r < 4; ++r) s[r] += __shfl_xor(s[r], off, 64);
  }
  if ((lane & 15) == 0) {
    int rbase = row0 + (lane >> 4) * 4;
#pragma unroll
    for (int r = 0; r < 4; ++r) {
      int row = rbase + r;
      if (row < n) out[row] = 1.0f / (1.0f + __expf(-(s[r] + b2)));
    }
  }
}

// ======================= Pooling =======================
__global__ void init_maxu_k(unsigned* __restrict__ p, int n) {
  int i = blockIdx.x * blockDim.x + threadIdx.x;
  if (i < n) p[i] = 0x007FFFFFu;
}

__global__ __launch_bounds__(256) void pool_stats_k(const float* __restrict__ x, const int* __restrict__ gstart,
                                                    const int* __restrict__ gcnt, float* __restrict__ gsum,
                                                    unsigned* __restrict__ gmaxu) {
  int g = blockIdx.x / SLICES, sl = blockIdx.x % SLICES;
  int st = gstart[g], cn = gcnt[g];
  int d = threadIdx.x & 127, half = threadIdx.x >> 7;
  float s = 0.f, mx = __uint_as_float(0xFF800000u);
  for (int r = sl * 2 + half; r < cn; r += 2 * SLICES) {
    float v = x[(size_t)(st + r) * D + d];
    s += v; mx = fmaxf(mx, v);
  }
  __shared__ float l1[128], l2[128];
  if (half) { l1[d] = s; l2[d] = mx; }
  __syncthreads();
  if (!half) {
    s += l1[d];
    mx = fmaxf(mx, l2[d]);
    atomicAdd(&gsum[g * D + d], s);
    unsigned u = __float_as_uint(mx);
    u = (u & 0x80000000u) ? ~u : (u | 0x80000000u);
    atomicMax(&gmaxu[g * D + d], u);
  }
}

__global__ void pool_fin_k(const float* __restrict__ gsum, const unsigned* __restrict__ gmaxu,
                           const int* __restrict__ gcnt, float* __restrict__ gf) {
  int g = blockIdx.x, d = threadIdx.x;
  float cnt = fmaxf((float)gcnt[g], 1.0f);
  gf[g * 256 + d] = gsum[g * D + d] / cnt;
  unsigned u = gmaxu[g * D + d];
  unsigned bits = (u & 0x80000000u) ? (u ^ 0x80000000u) : ~u;
  gf[g * 256 + 128 + d] = __uint_as_float(bits);
}

// ======================= Graph MLP =======================
__global__ __launch_bounds__(128) void mlp_k(const float* __restrict__ gf, const float* __restrict__ hw1,
                                             const float* __restrict__ hb1, const float* __restrict__ hw2,
                                             const float* __restrict__ hb2, const float* __restrict__ hw3,
                                             const float* __restrict__ hb3, float* __restrict__ logits) {
  __shared__ float sg[256], z1[128], z2[64];
  int g = blockIdx.x, t = threadIdx.x;
  sg[t] = gf[g * 256 + t];
  sg[t + 128] = gf[g * 256 + 128 + t];
  __syncthreads();
  float a = hb1[t];
  for (int k = 0; k < 256; ++k) a += sg[k] * hw1[k * 128 + t];
  z1[t] = fmaxf(a, 0.f);
  __syncthreads();
  if (t < 64) {
    float a2 = hb2[t];
    for (int k = 0; k < 128; ++k) a2 += z1[k] * hw2[k * 64 + t];
    z2[t] = fmaxf(a2, 0.f);
  }
  __syncthreads();
  if (t < 2) {
    float a3 = hb3[t];
    for (int k = 0; k < 64; ++k) a3 += z2[k] * hw3[k * 2 + t];
    logits[g * 2 + t] = a3;
  }
}

// ======================= Host =======================
extern "C" void kernel_launch(void* const* d_in, const int* in_sizes, int n_in,
                              void* d_out, int out_size, void* d_ws, size_t ws_size,
                              hipStream_t stream) {
  const float* x_in  = (const float*)d_in[0];
  const int*   eidx  = (const int*)d_in[1];
  const int*   batch = (const int*)d_in[2];
  const float* Wp  = (const float*)d_in[3];
  const float* bp  = (const float*)d_in[4];
  const float* Wg  = (const float*)d_in[5];
  const float* bg  = (const float*)d_in[6];
  const float* Wa1 = (const float*)d_in[7];
  const float* as1 = (const float*)d_in[8];
  const float* ad1 = (const float*)d_in[9];
  const float* ba1 = (const float*)d_in[10];
  const float* Wa2 = (const float*)d_in[11];
  const float* as2 = (const float*)d_in[12];
  const float* ad2 = (const float*)d_in[13];
  const float* ba2 = (const float*)d_in[14];
  const float* gnw[3] = {(const float*)d_in[15], (const float*)d_in[18], (const float*)d_in[21]};
  const float* gnb[3] = {(const float*)d_in[16], (const float*)d_in[19], (const float*)d_in[22]};
  const float* gns[3] = {(const float*)d_in[17], (const float*)d_in[20], (const float*)d_in[23]};
  const float* hw1 = (const float*)d_in[24];
  const float* hb1 = (const float*)d_in[25];
  const float* hw2 = (const float*)d_in[26];
  const float* hb2 = (const float*)d_in[27];
  const float* hw3 = (const float*)d_in[28];
  const float* hb3 = (const float*)d_in[29];
  const float* nw1 = (const float*)d_in[30];
  const float* nb1 = (const float*)d_in[31];
  const float* nw2 = (const float*)d_in[32];
  const float* nb2 = (const float*)d_in[33];

  const int N = in_sizes[0] / D;
  const int E = in_sizes[1] / 2;
  const int* src = eidx;
  const int* dst = eidx + E;

  float* out    = (float*)d_out;
  float* logits = out;
  float* hub    = out + GG * 2;
  float* gf     = out + GG * 2 + N;
  float* X      = out + GG * 2 + N + GG * 256;

  char* wp = (char*)d_ws;
  auto alloc = [&](size_t bytes) { char* p = wp; wp += (bytes + 255) & ~(size_t)255; return p; };
  float*    B1    = (float*)alloc((size_t)N * D * 4);
  float*    B2    = (float*)alloc((size_t)N * D * 4);
  unsigned* B1h   = (unsigned*)alloc((size_t)N * (D / 2) * 4);
  unsigned short* Xb = (unsigned short*)alloc((size_t)N * D * 2);
  int*   col     = (int*)alloc((size_t)E * 4);
  int*   cnt     = (int*)alloc((size_t)N * 4);
  int*   rowp    = (int*)alloc((size_t)(N + 1) * 4);
  int*   cur     = (int*)alloc((size_t)N * 4);
  float* dinv    = (float*)alloc((size_t)N * 4);
  float* es      = (float*)alloc((size_t)N * 4 * 4);
  float* ed      = (float*)alloc((size_t)N * 4 * 4);
  float* aself   = (float*)alloc((size_t)N * 4 * 4);
  float* winv    = (float*)alloc((size_t)N * 4 * 4);
  float* gsum    = (float*)alloc((size_t)GG * D * 4);
  float* gsq     = (float*)alloc((size_t)GG * D * 4);
  unsigned* gmaxu = (unsigned*)alloc((size_t)GG * D * 4);
  float* mean    = (float*)alloc((size_t)GG * D * 4);
  float* rstd    = (float*)alloc((size_t)GG * D * 4);
  int*   gcnt    = (int*)alloc((size_t)GG * 4);
  int*   gstart  = (int*)alloc((size_t)GG * 4);
  int*   gend    = (int*)alloc((size_t)GG * 4);
  int*   bsum    = (int*)alloc((size_t)256 * 4);
  unsigned short* Wpp  = (unsigned short*)alloc(16384 * 2);
  unsigned short* Wgp  = (unsigned short*)alloc(16384 * 2);
  unsigned short* Wa1p = (unsigned short*)alloc(16384 * 2);
  unsigned short* Wa2p = (unsigned short*)alloc(16384 * 2);
  unsigned short* W1p  = (unsigned short*)alloc(8192 * 2);
  float* alpha = B1;
  unsigned short* xinb = (unsigned short*)B2;
  if ((size_t)(wp - (char*)d_ws) > ws_size) return;

  const int nb = (N + 255) / 256;

  // ---- CSR + graph ranges ----
  hipMemsetAsync(cnt, 0, (size_t)N * 4, stream);
  count_edges_k<<<(E + 255) / 256, 256, 0, stream>>>(dst, cnt, E);
  bounds_init_k<<<1, GG, 0, stream>>>(gstart, gend);
  graph_bounds_k<<<nb, 256, 0, stream>>>(batch, gstart, gend, N);
  gcnt_k<<<1, GG, 0, stream>>>(gstart, gend, gcnt);
  scan1_k<<<nb, 256, 0, stream>>>(cnt, rowp, bsum, N);
  scan2_k<<<1, 256, 0, stream>>>(bsum, nb);
  scan3_k<<<nb, 256, 0, stream>>>(rowp, bsum, cur, N, E);
  dinv_k<<<nb, 256, 0, stream>>>(cnt, dinv, N);
  {
    int chunks = (E + 255) / 256;
    int slice = (N + NPASS - 1) / NPASS;
    fill_csr_mp_k<<<chunks * NPASS, 256, 0, stream>>>(src, dst, cur, col, E, slice, chunks);
  }

  // ---- weight packs + input cast ----
  packB_k<<<8, 256, 0, stream>>>(Wp, Wpp, 128, 8);
  packB_k<<<8, 256, 0, stream>>>(Wg, Wgp, 128, 8);
  packB_k<<<8, 256, 0, stream>>>(Wa1, Wa1p, 128, 8);
  packB_k<<<8, 256, 0, stream>>>(Wa2, Wa2p, 128, 8);
  packB_k<<<4, 256, 0, stream>>>(nw1, W1p, 64, 4);
  cast_bf16_k<<<(N * 32 + 255) / 256, 256, 0, stream>>>(x_in, xinb, N * 32);

  const int gemmGrid = (N + 63) / 64;
  const int aggGrid  = (N + 3) / 4;

  auto graphnorm = [&](int layer) {
    hipMemsetAsync(gsum, 0, 2 * (size_t)GG * D * 4, stream);
    gn_stats_k<<<GG * SLICES, 256, 0, stream>>>(B2, gstart, gcnt, gsum, gsq);
    gn_finalize_k<<<GG, D, 0, stream>>>(gsum, gsq, gcnt, gns[layer], mean, rstd);
    gn_apply_k<<<(N * 32 + 255) / 256, 256, 0, stream>>>(B2, X, Xb, batch, mean, rstd,
                                                         gnw[layer], gnb[layer], gns[layer], N);
  };

  // ---- projection ----
  gemm_mfma_k<<<gemmGrid, 256, 0, stream>>>(xinb, Wpp, bp, X, Xb, N);

  // ---- GCN layer ----
  gemm_mfma_k<<<gemmGrid, 256, 0, stream>>>(Xb, Wgp, nullptr, nullptr, (unsigned short*)B1h, N);
  gcn_gather_k<<<aggGrid, 256, 0, stream>>>(B1h, rowp, col, dinv, bg, B2, N);
  graphnorm(0);

  // ---- GAT layer 1 ----
  gemm_mfma_k<<<gemmGrid, 256, 0, stream>>>(Xb, Wa1p, nullptr, nullptr, (unsigned short*)B1h, N);
  attn_coef_k<<<(N * 4 + 255) / 256, 256, 0, stream>>>((const unsigned short*)B1h, as1, ad1, es, ed, N);
  alpha_k<<<aggGrid, 256, 0, stream>>>(es, ed, rowp, col, alpha, aself, winv, N);
  gat_gather_k<<<aggGrid, 256, 0, stream>>>(B1h, rowp, col, alpha, aself, winv, ba1, B2, N);
  graphnorm(1);

  // ---- GAT layer 2 ----
  gemm_mfma_k<<<gemmGrid, 256, 0, stream>>>(Xb, Wa2p, nullptr, nullptr, (unsigned short*)B1h, N);
  attn_coef_k<<<(N * 4 + 255) / 256, 256, 0, stream>>>((const unsigned short*)B1h, as2, ad2, es, ed, N);
  alpha_k<<<aggGrid, 256, 0, stream>>>(es, ed, rowp, col, alpha, aself, winv, N);
  gat_gather_k<<<aggGrid, 256, 0, stream>>>(B1h, rowp, col, alpha, aself, winv, ba2, B2, N);
  graphnorm(2);

  // ---- hub scores (MFMA) ----
  hub_mfma_k<<<gemmGrid, 256, 0, stream>>>(Xb, W1p, nb1, nw2, nb2, hub, N);

  // ---- pooling + graph MLP ----
  hipMemsetAsync(gsum, 0, (size_t)GG * D * 4, stream);
  init_maxu_k<<<(GG * D + 255) / 256, 256, 0, stream>>>(gmaxu, GG * D);
  pool_stats_k<<<GG * SLICES, 256, 0, stream>>>(X, gstart, gcnt, gsum, gmaxu);
  pool_fin_k<<<GG, D, 0, stream>>>(gsum, gmaxu, gcnt, gf);
  mlp_k<<<GG, 128, 0, stream>>>(gf, hw1, hb1, hw2, hb2, hw3, hb3, logits);
}

// Round 6
// 458.207 us; speedup vs baseline: 1.0286x; 1.0286x over previous
//
#include <hip/hip_runtime.h>
#include <cstdint>

#define D 128
#define GG 64
#define SLICES 16
#define NPASS 4

typedef short bf16x8 __attribute__((ext_vector_type(8)));
typedef float f32x4 __attribute__((ext_vector_type(4)));

// ---------- bf16 helpers ----------
__device__ inline unsigned short bf16u(float f) {
  unsigned u = __float_as_uint(f);
  u = (u + 0x7FFFu + ((u >> 16) & 1u)) >> 16;
  return (unsigned short)u;
}
__device__ inline float2 unpackbf2(unsigned u) {
  return make_float2(__uint_as_float(u << 16), __uint_as_float(u & 0xFFFF0000u));
}
__device__ inline void accum8(float* acc, uint4 v, float w) {
  float2 p0 = unpackbf2(v.x), p1 = unpackbf2(v.y), p2 = unpackbf2(v.z), p3 = unpackbf2(v.w);
  acc[0] += p0.x * w; acc[1] += p0.y * w; acc[2] += p1.x * w; acc[3] += p1.y * w;
  acc[4] += p2.x * w; acc[5] += p2.y * w; acc[6] += p3.x * w; acc[7] += p3.y * w;
}

// ======================= CSR build =======================
__global__ void count_edges_k(const int* __restrict__ dst, int* __restrict__ cnt, int E) {
  int e = blockIdx.x * blockDim.x + threadIdx.x;
  if (e < E) atomicAdd(&cnt[dst[e]], 1);
}

__global__ void bounds_init_k(int* __restrict__ gstart, int* __restrict__ gend) {
  int g = threadIdx.x;
  gstart[g] = 0;
  gend[g] = 0;
}

__global__ void graph_bounds_k(const int* __restrict__ batch, int* __restrict__ gstart,
                               int* __restrict__ gend, int n) {
  int i = blockIdx.x * blockDim.x + threadIdx.x;
  if (i >= n) return;
  int b = batch[i];
  if (i == 0) {
    gstart[b] = 0;
  } else {
    int pb = batch[i - 1];
    if (pb != b) { gstart[b] = i; gend[pb] = i; }
  }
  if (i == n - 1) gend[b] = n;
}

__global__ void gcnt_k(const int* __restrict__ gstart, const int* __restrict__ gend,
                       int* __restrict__ gcnt) {
  int g = threadIdx.x;
  gcnt[g] = gend[g] - gstart[g];
}

__global__ __launch_bounds__(256) void scan1_k(const int* __restrict__ cnt, int* __restrict__ rp,
                                               int* __restrict__ bsum, int n) {
  __shared__ int sd[256];
  int t = threadIdx.x;
  int i = blockIdx.x * 256 + t;
  int v = (i < n) ? cnt[i] : 0;
  sd[t] = v;
  __syncthreads();
#pragma unroll
  for (int off = 1; off < 256; off <<= 1) {
    int u = (t >= off) ? sd[t - off] : 0;
    __syncthreads();
    sd[t] += u;
    __syncthreads();
  }
  if (i < n) rp[i] = sd[t] - v;
  if (t == 255) bsum[blockIdx.x] = sd[255];
}

__global__ __launch_bounds__(256) void scan2_k(int* __restrict__ bsum, int nb) {
  __shared__ int sd[256];
  int t = threadIdx.x;
  int v = (t < nb) ? bsum[t] : 0;
  sd[t] = v;
  __syncthreads();
#pragma unroll
  for (int off = 1; off < 256; off <<= 1) {
    int u = (t >= off) ? sd[t - off] : 0;
    __syncthreads();
    sd[t] += u;
    __syncthreads();
  }
  if (t < nb) bsum[t] = sd[t] - v;
}

__global__ __launch_bounds__(256) void scan3_k(int* __restrict__ rp, const int* __restrict__ bsum,
                                               int* __restrict__ cur, int n, int E) {
  int i = blockIdx.x * 256 + threadIdx.x;
  if (i < n) {
    int r = rp[i] + bsum[blockIdx.x];
    rp[i] = r;
    cur[i] = r;
  }
  if (i == 0) rp[n] = E;
}

__global__ __launch_bounds__(256) void fill_csr_mp_k(const int* __restrict__ src,
                                                     const int* __restrict__ dst,
                                                     int* __restrict__ cur, int* __restrict__ col,
                                                     int E, int slice, int chunks) {
  int pass = blockIdx.x / chunks;
  int e = (blockIdx.x % chunks) * 256 + threadIdx.x;
  if (e >= E) return;
  int d = dst[e];
  if (d >= pass * slice && d < (pass + 1) * slice) {
    int p = atomicAdd(&cur[d], 1);
    col[p] = src[e];
  }
}

__global__ void dinv_k(const int* __restrict__ cnt, float* __restrict__ dinv, int n) {
  int i = blockIdx.x * blockDim.x + threadIdx.x;
  if (i < n) dinv[i] = rsqrtf((float)cnt[i] + 1.0f);
}

// ======================= bf16 cast =======================
__global__ void cast_bf16_k(const float* __restrict__ in, unsigned short* __restrict__ outp, int n4) {
  int i = blockIdx.x * blockDim.x + threadIdx.x;
  if (i >= n4) return;
  float4 v = ((const float4*)in)[i];
  ushort4 o;
  o.x = bf16u(v.x); o.y = bf16u(v.y); o.z = bf16u(v.z); o.w = bf16u(v.w);
  ((ushort4*)outp)[i] = o;
}

// ======================= Weight pack into MFMA B-fragment order =======================
__global__ void packB_k(const float* __restrict__ B, unsigned short* __restrict__ Bp, int ldb, int ct) {
  int idx = blockIdx.x * 256 + threadIdx.x;
  if (idx >= ct * 256) return;
  int lane = idx & 63;
  int kc = (idx >> 6) & 3;
  int c = idx >> 8;
  int kb = kc * 32 + (lane >> 4) * 8;
  int colq = c * 16 + (lane & 15);
  unsigned short o[8];
#pragma unroll
  for (int j = 0; j < 8; ++j) o[j] = bf16u(B[(size_t)(kb + j) * ldb + colq]);
  uint4 p;
  p.x = (unsigned)o[0] | ((unsigned)o[1] << 16);
  p.y = (unsigned)o[2] | ((unsigned)o[3] << 16);
  p.z = (unsigned)o[4] | ((unsigned)o[5] << 16);
  p.w = (unsigned)o[6] | ((unsigned)o[7] << 16);
  *(uint4*)&Bp[(size_t)idx * 8] = p;
}

// ======================= MFMA GEMM: [M,128]x[128,128] =======================
__global__ __launch_bounds__(256) void gemm_mfma_k(const unsigned short* __restrict__ Ab,
                                                   const unsigned short* __restrict__ Bp,
                                                   const float* __restrict__ bias,
                                                   float* __restrict__ Cf,
                                                   unsigned short* __restrict__ Cb, int M) {
  __shared__ unsigned short Bs[16384];
  int t = threadIdx.x;
  for (int i = t; i < 2048; i += 256) ((uint4*)Bs)[i] = ((const uint4*)Bp)[i];
  __syncthreads();
  int w = t >> 6, lane = t & 63;
  int row0 = blockIdx.x * 64 + w * 16;
  int arow = row0 + (lane & 15);
  f32x4 acc[8];
#pragma unroll
  for (int c = 0; c < 8; ++c) acc[c] = {0.f, 0.f, 0.f, 0.f};
#pragma unroll
  for (int kc = 0; kc < 4; ++kc) {
    bf16x8 a = {0, 0, 0, 0, 0, 0, 0, 0};
    if (arow < M) a = *(const bf16x8*)&Ab[(size_t)arow * 128 + kc * 32 + (lane >> 4) * 8];
#pragma unroll
    for (int c = 0; c < 8; ++c) {
      bf16x8 b = *(const bf16x8*)&Bs[((c * 4 + kc) * 64 + lane) * 8];
      acc[c] = __builtin_amdgcn_mfma_f32_16x16x32_bf16(a, b, acc[c], 0, 0, 0);
    }
  }
  int rbase = row0 + (lane >> 4) * 4;
#pragma unroll
  for (int c = 0; c < 8; ++c) {
    int colq = c * 16 + (lane & 15);
    float bb = bias ? bias[colq] : 0.f;
#pragma unroll
    for (int r = 0; r < 4; ++r) {
      int row = rbase + r;
      if (row < M) {
        float v = acc[c][r] + bb;
        if (Cf) Cf[(size_t)row * 128 + colq] = v;
        if (Cb) Cb[(size_t)row * 128 + colq] = bf16u(v);
      }
    }
  }
}

// ======================= GCN aggregation (16B/lane, 4 edges per instruction) ============
__global__ __launch_bounds__(256) void gcn_gather_k(const uint4* __restrict__ xw16,
                                                    const int* __restrict__ rp, const int* __restrict__ col,
                                                    const float* __restrict__ dinv, const float* __restrict__ bias,
                                                    float* __restrict__ out, int n) {
  int i = blockIdx.x * 4 + (threadIdx.x >> 6);
  if (i >= n) return;
  int lane = threadIdx.x & 63;
  int g = lane >> 4, sub = lane & 15;
  int e0 = __builtin_amdgcn_readfirstlane(rp[i]);
  int e1 = __builtin_amdgcn_readfirstlane(rp[i + 1]);
  float di = dinv[i];
  float acc[8] = {0.f, 0.f, 0.f, 0.f, 0.f, 0.f, 0.f, 0.f};
  if (g == 0) {
    uint4 v = xw16[(size_t)i * 16 + sub];
    accum8(acc, v, di * di);
  }
  int e = e0;
  for (; e + 15 < e1; e += 16) {           // 16 edges: 4 gather instrs in flight
    int s0 = col[e + g];
    int s1 = col[e + 4 + g];
    int s2 = col[e + 8 + g];
    int s3 = col[e + 12 + g];
    float w0 = dinv[s0] * di, w1 = dinv[s1] * di, w2 = dinv[s2] * di, w3 = dinv[s3] * di;
    uint4 v0 = xw16[(size_t)s0 * 16 + sub];
    uint4 v1 = xw16[(size_t)s1 * 16 + sub];
    uint4 v2 = xw16[(size_t)s2 * 16 + sub];
    uint4 v3 = xw16[(size_t)s3 * 16 + sub];
    accum8(acc, v0, w0); accum8(acc, v1, w1); accum8(acc, v2, w2); accum8(acc, v3, w3);
  }
  for (; e < e1; e += 4) {                  // tail: <=3 dummy edges (self row, L1-hot)
    bool ok = (e + g) < e1;
    int s0 = ok ? col[e + g] : i;
    float w0 = ok ? dinv[s0] * di : 0.f;
    uint4 v0 = xw16[(size_t)s0 * 16 + sub];
    accum8(acc, v0, w0);
  }
#pragma unroll
  for (int k = 0; k < 8; ++k) {
    acc[k] += __shfl_xor(acc[k], 16, 64);
    acc[k] += __shfl_xor(acc[k], 32, 64);
  }
  if (g == 0) {
    float4 b0 = ((const float4*)bias)[sub * 2], b1 = ((const float4*)bias)[sub * 2 + 1];
    *(float4*)&out[(size_t)i * 128 + sub * 8] =
        make_float4(acc[0] + b0.x, acc[1] + b0.y, acc[2] + b0.z, acc[3] + b0.w);
    *(float4*)&out[(size_t)i * 128 + sub * 8 + 4] =
        make_float4(acc[4] + b1.x, acc[5] + b1.y, acc[6] + b1.z, acc[7] + b1.w);
  }
}

// ======================= GAT attention coefficients (bf16 input) =======================
__global__ void attn_coef_k(const unsigned short* __restrict__ hb, const float* __restrict__ a_s,
                            const float* __restrict__ a_d, float* __restrict__ es,
                            float* __restrict__ ed, int n) {
  int idx = blockIdx.x * blockDim.x + threadIdx.x;
  if (idx >= n * 4) return;
  int node = idx >> 2, hh = idx & 3;
  const uint4* hr = (const uint4*)(hb + (size_t)node * 128 + hh * 32);
  const float4* av = (const float4*)(a_s + hh * 32);
  const float4* dv = (const float4*)(a_d + hh * 32);
  float s = 0.f, d2 = 0.f;
#pragma unroll
  for (int q = 0; q < 4; ++q) {
    uint4 u = hr[q];
    float2 p0 = unpackbf2(u.x), p1 = unpackbf2(u.y), p2 = unpackbf2(u.z), p3 = unpackbf2(u.w);
    float4 a0 = av[q * 2], a1 = av[q * 2 + 1];
    float4 d0 = dv[q * 2], d1 = dv[q * 2 + 1];
    s  += p0.x * a0.x + p0.y * a0.y + p1.x * a0.z + p1.y * a0.w
        + p2.x * a1.x + p2.y * a1.y + p3.x * a1.z + p3.y * a1.w;
    d2 += p0.x * d0.x + p0.y * d0.y + p1.x * d0.z + p1.y * d0.w
        + p2.x * d1.x + p2.y * d1.y + p3.x * d1.z + p3.y * d1.w;
  }
  es[idx] = s;
  ed[idx] = d2;
}

// ======================= GAT alpha precompute (unnormalized; winv factored out) ==============
__global__ __launch_bounds__(256) void alpha_k(const float* __restrict__ es, const float* __restrict__ ed,
                                               const int* __restrict__ rp, const int* __restrict__ col,
                                               float* __restrict__ alpha, float* __restrict__ aself,
                                               float* __restrict__ winv, int n) {
  int i = blockIdx.x * 4 + (threadIdx.x >> 6);
  if (i >= n) return;
  int lane = threadIdx.x & 63;
  int hh = lane >> 4, slot = lane & 15;
  int e0 = __builtin_amdgcn_readfirstlane(rp[i]);
  int e1 = __builtin_amdgcn_readfirstlane(rp[i + 1]);
  float edi = ed[i * 4 + hh];
  float esf = es[i * 4 + hh] + edi;
  esf = esf >= 0.f ? esf : 0.2f * esf;
  float m = esf;
  for (int e = e0 + slot; e < e1; e += 16) {
    int sj = col[e];
    float ev = es[sj * 4 + hh] + edi;
    ev = ev >= 0.f ? ev : 0.2f * ev;
    alpha[(size_t)e * 4 + hh] = ev;
    m = fmaxf(m, ev);
  }
#pragma unroll
  for (int off = 1; off < 16; off <<= 1) m = fmaxf(m, __shfl_xor(m, off, 64));
  float s = (slot == 0) ? __expf(esf - m) : 0.f;
  for (int e = e0 + slot; e < e1; e += 16) {
    float w = __expf(alpha[(size_t)e * 4 + hh] - m);
    alpha[(size_t)e * 4 + hh] = w;
    s += w;
  }
#pragma unroll
  for (int off = 1; off < 16; off <<= 1) s += __shfl_xor(s, off, 64);
  if (slot == 0) {
    aself[i * 4 + hh] = __expf(esf - m);
    winv[i * 4 + hh] = 1.0f / (s + 1e-16f);
  }
}

// ======================= GAT gather (16B/lane, 4 edges per instruction) ================
__global__ __launch_bounds__(256) void gat_gather_k(const uint4* __restrict__ hf16,
                                                    const int* __restrict__ rp, const int* __restrict__ col,
                                                    const float* __restrict__ alpha, const float* __restrict__ aself,
                                                    const float* __restrict__ winv,
                                                    const float* __restrict__ bias, float* __restrict__ out, int n) {
  int i = blockIdx.x * 4 + (threadIdx.x >> 6);
  if (i >= n) return;
  int lane = threadIdx.x & 63;
  int g = lane >> 4, sub = lane & 15;
  int hh = sub >> 2;                      // head owning dims [8*sub, 8*sub+8)
  int e0 = __builtin_amdgcn_readfirstlane(rp[i]);
  int e1 = __builtin_amdgcn_readfirstlane(rp[i + 1]);
  float acc[8] = {0.f, 0.f, 0.f, 0.f, 0.f, 0.f, 0.f, 0.f};
  if (g == 0) {
    uint4 v = hf16[(size_t)i * 16 + sub];
    accum8(acc, v, aself[i * 4 + hh]);
  }
  int e = e0;
  for (; e + 15 < e1; e += 16) {
    int s0 = col[e + g];
    int s1 = col[e + 4 + g];
    int s2 = col[e + 8 + g];
    int s3 = col[e + 12 + g];
    float a0 = alpha[(size_t)(e + g) * 4 + hh];
    float a1 = alpha[(size_t)(e + 4 + g) * 4 + hh];
    float a2 = alpha[(size_t)(e + 8 + g) * 4 + hh];
    float a3 = alpha[(size_t)(e + 12 + g) * 4 + hh];
    uint4 v0 = hf16[(size_t)s0 * 16 + sub];
    uint4 v1 = hf16[(size_t)s1 * 16 + sub];
    uint4 v2 = hf16[(size_t)s2 * 16 + sub];
    uint4 v3 = hf16[(size_t)s3 * 16 + sub];
    accum8(acc, v0, a0); accum8(acc, v1, a1); accum8(acc, v2, a2); accum8(acc, v3, a3);
  }
  for (; e < e1; e += 4) {
    bool ok = (e + g) < e1;
    int s0 = ok ? col[e + g] : i;
    float a0 = ok ? alpha[(size_t)(e + g) * 4 + hh] : 0.f;
    uint4 v0 = hf16[(size_t)s0 * 16 + sub];
    accum8(acc, v0, a0);
  }
#pragma unroll
  for (int k = 0; k < 8; ++k) {
    acc[k] += __shfl_xor(acc[k], 16, 64);
    acc[k] += __shfl_xor(acc[k], 32, 64);
  }
  if (g == 0) {
    float wi = winv[i * 4 + hh];
    float4 b0 = ((const float4*)bias)[sub * 2], b1 = ((const float4*)bias)[sub * 2 + 1];
    *(float4*)&out[(size_t)i * 128 + sub * 8] =
        make_float4(acc[0] * wi + b0.x, acc[1] * wi + b0.y, acc[2] * wi + b0.z, acc[3] * wi + b0.w);
    *(float4*)&out[(size_t)i * 128 + sub * 8 + 4] =
        make_float4(acc[4] * wi + b1.x, acc[5] * wi + b1.y, acc[6] * wi + b1.z, acc[7] * wi + b1.w);
  }
}

// ======================= GraphNorm =======================
__global__ __launch_bounds__(256) void gn_stats_k(const float* __restrict__ h, const int* __restrict__ gstart,
                                                  const int* __restrict__ gcnt, float* __restrict__ gsum,
                                                  float* __restrict__ gsq) {
  int g = blockIdx.x / SLICES, sl = blockIdx.x % SLICES;
  int st = gstart[g], cn = gcnt[g];
  int d = threadIdx.x & 127, half = threadIdx.x >> 7;
  float s = 0.f, ss = 0.f;
  for (int r = sl * 2 + half; r < cn; r += 2 * SLICES) {
    float v = h[(size_t)(st + r) * D + d];
    s += v; ss += v * v;
  }
  __shared__ float l1[128], l2[128];
  if (half) { l1[d] = s; l2[d] = ss; }
  __syncthreads();
  if (!half) {
    atomicAdd(&gsum[g * D + d], s + l1[d]);
    atomicAdd(&gsq[g * D + d], ss + l2[d]);
  }
}

__global__ void gn_finalize_k(const float* __restrict__ gsum, const float* __restrict__ gsq,
                              const int* __restrict__ gcnt, const float* __restrict__ ms,
                              float* __restrict__ mean, float* __restrict__ rstd) {
  int g = blockIdx.x, d = threadIdx.x;
  float cnt = fmaxf((float)gcnt[g], 1.0f);
  float mu = gsum[g * D + d] / cnt;
  float m2 = gsq[g * D + d] / cnt;
  float s = ms[d];
  float var = m2 - (2.0f * s - s * s) * mu * mu;
  mean[g * D + d] = mu;
  rstd[g * D + d] = rsqrtf(fmaxf(var, 0.0f) + 1e-5f);
}

__global__ void gn_apply_k(const float* __restrict__ h, float* __restrict__ x,
                           unsigned short* __restrict__ xb,
                           const int* __restrict__ batch, const float* __restrict__ mean,
                           const float* __restrict__ rstd, const float* __restrict__ w,
                           const float* __restrict__ b, const float* __restrict__ ms, int n) {
  int idx = blockIdx.x * blockDim.x + threadIdx.x;
  if (idx >= n * 32) return;
  int node = idx >> 5, q = idx & 31;
  int g = batch[node];
  int d0 = q * 4;
  float4 hv = ((const float4*)h)[idx];
  float4 xv = ((const float4*)x)[idx];
  float ha[4] = {hv.x, hv.y, hv.z, hv.w};
  float xa[4] = {xv.x, xv.y, xv.z, xv.w};
  float ra[4];
#pragma unroll
  for (int j = 0; j < 4; ++j) {
    int d = d0 + j;
    float sub = ha[j] - ms[d] * mean[g * D + d];
    float v = w[d] * sub * rstd[g * D + d] + b[d];
    ra[j] = fmaxf(v, 0.f) + xa[j];
  }
  ((float4*)x)[idx] = make_float4(ra[0], ra[1], ra[2], ra[3]);
  ushort4 o;
  o.x = bf16u(ra[0]); o.y = bf16u(ra[1]); o.z = bf16u(ra[2]); o.w = bf16u(ra[3]);
  ((ushort4*)xb)[idx] = o;
}

// ======================= Hub scores (MFMA) =======================
__global__ __launch_bounds__(256) void hub_mfma_k(const unsigned short* __restrict__ Xb,
                                                  const unsigned short* __restrict__ W1p,
                                                  const float* __restrict__ nb1, const float* __restrict__ nw2,
                                                  const float* __restrict__ nb2, float* __restrict__ out, int n) {
  __shared__ unsigned short Bs[8192];
  int t = threadIdx.x;
  for (int i = t; i < 1024; i += 256) ((uint4*)Bs)[i] = ((const uint4*)W1p)[i];
  __syncthreads();
  int w = t >> 6, lane = t & 63;
  int row0 = blockIdx.x * 64 + w * 16;
  int arow = row0 + (lane & 15);
  f32x4 acc[4];
#pragma unroll
  for (int c = 0; c < 4; ++c) acc[c] = {0.f, 0.f, 0.f, 0.f};
#pragma unroll
  for (int kc = 0; kc < 4; ++kc) {
    bf16x8 a = {0, 0, 0, 0, 0, 0, 0, 0};
    if (arow < n) a = *(const bf16x8*)&Xb[(size_t)arow * 128 + kc * 32 + (lane >> 4) * 8];
#pragma unroll
    for (int c = 0; c < 4; ++c) {
      bf16x8 b = *(const bf16x8*)&Bs[((c * 4 + kc) * 64 + lane) * 8];
      acc[c] = __builtin_amdgcn_mfma_f32_16x16x32_bf16(a, b, acc[c], 0, 0, 0);
    }
  }
  float b2 = nb2[0];
  float s[4] = {0.f, 0.f, 0.f, 0.f};
#pragma unroll
  for (int c = 0; c < 4; ++c) {
    int colq = c * 16 + (lane & 15);
    float b1 = nb1[colq];
    float w2 = nw2[colq];
#pragma unroll
    for (int r = 0; r < 4; ++r) s[r] += fmaxf(acc[c][r] + b1, 0.f) * w2;
  }
#pragma unroll
  for (int off = 1; off < 16; off <<= 1) {
#pragma unroll
    for (int r = 0; r < 4; ++r) s[r] += __shfl_xor(s[r], off, 64);
  }
  if ((lane & 15) == 0) {
    int rbase = row0 + (lane >> 4) * 4;
#pragma unroll
    for (int r = 0; r < 4; ++r) {
      int row = rbase + r;
      if (row < n) out[row] = 1.0f / (1.0f + __expf(-(s[r] + b2)));
    }
  }
}

// ======================= Pooling =======================
__global__ void init_maxu_k(unsigned* __restrict__ p, int n) {
  int i = blockIdx.x * blockDim.x + threadIdx.x;
  if (i < n) p[i] = 0x007FFFFFu;
}

__global__ __launch_bounds__(256) void pool_stats_k(const float* __restrict__ x, const int* __restrict__ gstart,
                                                    const int* __restrict__ gcnt, float* __restrict__ gsum,
                                                    unsigned* __restrict__ gmaxu) {
  int g = blockIdx.x / SLICES, sl = blockIdx.x % SLICES;
  int st = gstart[g], cn = gcnt[g];
  int d = threadIdx.x & 127, half = threadIdx.x >> 7;
  float s = 0.f, mx = __uint_as_float(0xFF800000u);
  for (int r = sl * 2 + half; r < cn; r += 2 * SLICES) {
    float v = x[(size_t)(st + r) * D + d];
    s += v; mx = fmaxf(mx, v);
  }
  __shared__ float l1[128], l2[128];
  if (half) { l1[d] = s; l2[d] = mx; }
  __syncthreads();
  if (!half) {
    s += l1[d];
    mx = fmaxf(mx, l2[d]);
    atomicAdd(&gsum[g * D + d], s);
    unsigned u = __float_as_uint(mx);
    u = (u & 0x80000000u) ? ~u : (u | 0x80000000u);
    atomicMax(&gmaxu[g * D + d], u);
  }
}

__global__ void pool_fin_k(const float* __restrict__ gsum, const unsigned* __restrict__ gmaxu,
                           const int* __restrict__ gcnt, float* __restrict__ gf) {
  int g = blockIdx.x, d = threadIdx.x;
  float cnt = fmaxf((float)gcnt[g], 1.0f);
  gf[g * 256 + d] = gsum[g * D + d] / cnt;
  unsigned u = gmaxu[g * D + d];
  unsigned bits = (u & 0x80000000u) ? (u ^ 0x80000000u) : ~u;
  gf[g * 256 + 128 + d] = __uint_as_float(bits);
}

// ======================= Graph MLP =======================
__global__ __launch_bounds__(128) void mlp_k(const float* __restrict__ gf, const float* __restrict__ hw1,
                                             const float* __restrict__ hb1, const float* __restrict__ hw2,
                                             const float* __restrict__ hb2, const float* __restrict__ hw3,
                                             const float* __restrict__ hb3, float* __restrict__ logits) {
  __shared__ float sg[256], z1[128], z2[64];
  int g = blockIdx.x, t = threadIdx.x;
  sg[t] = gf[g * 256 + t];
  sg[t + 128] = gf[g * 256 + 128 + t];
  __syncthreads();
  float a = hb1[t];
  for (int k = 0; k < 256; ++k) a += sg[k] * hw1[k * 128 + t];
  z1[t] = fmaxf(a, 0.f);
  __syncthreads();
  if (t < 64) {
    float a2 = hb2[t];
    for (int k = 0; k < 128; ++k) a2 += z1[k] * hw2[k * 64 + t];
    z2[t] = fmaxf(a2, 0.f);
  }
  __syncthreads();
  if (t < 2) {
    float a3 = hb3[t];
    for (int k = 0; k < 64; ++k) a3 += z2[k] * hw3[k * 2 + t];
    logits[g * 2 + t] = a3;
  }
}

// ======================= Host =======================
extern "C" void kernel_launch(void* const* d_in, const int* in_sizes, int n_in,
                              void* d_out, int out_size, void* d_ws, size_t ws_size,
                              hipStream_t stream) {
  const float* x_in  = (const float*)d_in[0];
  const int*   eidx  = (const int*)d_in[1];
  const int*   batch = (const int*)d_in[2];
  const float* Wp  = (const float*)d_in[3];
  const float* bp  = (const float*)d_in[4];
  const float* Wg  = (const float*)d_in[5];
  const float* bg  = (const float*)d_in[6];
  const float* Wa1 = (const float*)d_in[7];
  const float* as1 = (const float*)d_in[8];
  const float* ad1 = (const float*)d_in[9];
  const float* ba1 = (const float*)d_in[10];
  const float* Wa2 = (const float*)d_in[11];
  const float* as2 = (const float*)d_in[12];
  const float* ad2 = (const float*)d_in[13];
  const float* ba2 = (const float*)d_in[14];
  const float* gnw[3] = {(const float*)d_in[15], (const float*)d_in[18], (const float*)d_in[21]};
  const float* gnb[3] = {(const float*)d_in[16], (const float*)d_in[19], (const float*)d_in[22]};
  const float* gns[3] = {(const float*)d_in[17], (const float*)d_in[20], (const float*)d_in[23]};
  const float* hw1 = (const float*)d_in[24];
  const float* hb1 = (const float*)d_in[25];
  const float* hw2 = (const float*)d_in[26];
  const float* hb2 = (const float*)d_in[27];
  const float* hw3 = (const float*)d_in[28];
  const float* hb3 = (const float*)d_in[29];
  const float* nw1 = (const float*)d_in[30];
  const float* nb1 = (const float*)d_in[31];
  const float* nw2 = (const float*)d_in[32];
  const float* nb2 = (const float*)d_in[33];

  const int N = in_sizes[0] / D;
  const int E = in_sizes[1] / 2;
  const int* src = eidx;
  const int* dst = eidx + E;

  float* out    = (float*)d_out;
  float* logits = out;
  float* hub    = out + GG * 2;
  float* gf     = out + GG * 2 + N;
  float* X      = out + GG * 2 + N + GG * 256;

  char* wp = (char*)d_ws;
  auto alloc = [&](size_t bytes) { char* p = wp; wp += (bytes + 255) & ~(size_t)255; return p; };
  float*    B1    = (float*)alloc((size_t)N * D * 4);
  float*    B2    = (float*)alloc((size_t)N * D * 4);
  unsigned* B1h   = (unsigned*)alloc((size_t)N * (D / 2) * 4);
  unsigned short* Xb = (unsigned short*)alloc((size_t)N * D * 2);
  int*   col     = (int*)alloc((size_t)E * 4);
  int*   cnt     = (int*)alloc((size_t)N * 4);
  int*   rowp    = (int*)alloc((size_t)(N + 1) * 4);
  int*   cur     = (int*)alloc((size_t)N * 4);
  float* dinv    = (float*)alloc((size_t)N * 4);
  float* es      = (float*)alloc((size_t)N * 4 * 4);
  float* ed      = (float*)alloc((size_t)N * 4 * 4);
  float* aself   = (float*)alloc((size_t)N * 4 * 4);
  float* winv    = (float*)alloc((size_t)N * 4 * 4);
  float* gsum    = (float*)alloc((size_t)GG * D * 4);
  float* gsq     = (float*)alloc((size_t)GG * D * 4);
  unsigned* gmaxu = (unsigned*)alloc((size_t)GG * D * 4);
  float* mean    = (float*)alloc((size_t)GG * D * 4);
  float* rstd    = (float*)alloc((size_t)GG * D * 4);
  int*   gcnt    = (int*)alloc((size_t)GG * 4);
  int*   gstart  = (int*)alloc((size_t)GG * 4);
  int*   gend    = (int*)alloc((size_t)GG * 4);
  int*   bsum    = (int*)alloc((size_t)256 * 4);
  unsigned short* Wpp  = (unsigned short*)alloc(16384 * 2);
  unsigned short* Wgp  = (unsigned short*)alloc(16384 * 2);
  unsigned short* Wa1p = (unsigned short*)alloc(16384 * 2);
  unsigned short* Wa2p = (unsigned short*)alloc(16384 * 2);
  unsigned short* W1p  = (unsigned short*)alloc(8192 * 2);
  float* alpha = B1;
  unsigned short* xinb = (unsigned short*)B2;
  if ((size_t)(wp - (char*)d_ws) > ws_size) return;

  const int nb = (N + 255) / 256;

  // ---- CSR + graph ranges ----
  hipMemsetAsync(cnt, 0, (size_t)N * 4, stream);
  count_edges_k<<<(E + 255) / 256, 256, 0, stream>>>(dst, cnt, E);
  bounds_init_k<<<1, GG, 0, stream>>>(gstart, gend);
  graph_bounds_k<<<nb, 256, 0, stream>>>(batch, gstart, gend, N);
  gcnt_k<<<1, GG, 0, stream>>>(gstart, gend, gcnt);
  scan1_k<<<nb, 256, 0, stream>>>(cnt, rowp, bsum, N);
  scan2_k<<<1, 256, 0, stream>>>(bsum, nb);
  scan3_k<<<nb, 256, 0, stream>>>(rowp, bsum, cur, N, E);
  dinv_k<<<nb, 256, 0, stream>>>(cnt, dinv, N);
  {
    int chunks = (E + 255) / 256;
    int slice = (N + NPASS - 1) / NPASS;
    fill_csr_mp_k<<<chunks * NPASS, 256, 0, stream>>>(src, dst, cur, col, E, slice, chunks);
  }

  // ---- weight packs + input cast ----
  packB_k<<<8, 256, 0, stream>>>(Wp, Wpp, 128, 8);
  packB_k<<<8, 256, 0, stream>>>(Wg, Wgp, 128, 8);
  packB_k<<<8, 256, 0, stream>>>(Wa1, Wa1p, 128, 8);
  packB_k<<<8, 256, 0, stream>>>(Wa2, Wa2p, 128, 8);
  packB_k<<<4, 256, 0, stream>>>(nw1, W1p, 64, 4);
  cast_bf16_k<<<(N * 32 + 255) / 256, 256, 0, stream>>>(x_in, xinb, N * 32);

  const int gemmGrid = (N + 63) / 64;
  const int aggGrid  = (N + 3) / 4;

  auto graphnorm = [&](int layer) {
    hipMemsetAsync(gsum, 0, 2 * (size_t)GG * D * 4, stream);
    gn_stats_k<<<GG * SLICES, 256, 0, stream>>>(B2, gstart, gcnt, gsum, gsq);
    gn_finalize_k<<<GG, D, 0, stream>>>(gsum, gsq, gcnt, gns[layer], mean, rstd);
    gn_apply_k<<<(N * 32 + 255) / 256, 256, 0, stream>>>(B2, X, Xb, batch, mean, rstd,
                                                         gnw[layer], gnb[layer], gns[layer], N);
  };

  // ---- projection ----
  gemm_mfma_k<<<gemmGrid, 256, 0, stream>>>(xinb, Wpp, bp, X, Xb, N);

  // ---- GCN layer ----
  gemm_mfma_k<<<gemmGrid, 256, 0, stream>>>(Xb, Wgp, nullptr, nullptr, (unsigned short*)B1h, N);
  gcn_gather_k<<<aggGrid, 256, 0, stream>>>((const uint4*)B1h, rowp, col, dinv, bg, B2, N);
  graphnorm(0);

  // ---- GAT layer 1 ----
  gemm_mfma_k<<<gemmGrid, 256, 0, stream>>>(Xb, Wa1p, nullptr, nullptr, (unsigned short*)B1h, N);
  attn_coef_k<<<(N * 4 + 255) / 256, 256, 0, stream>>>((const unsigned short*)B1h, as1, ad1, es, ed, N);
  alpha_k<<<aggGrid, 256, 0, stream>>>(es, ed, rowp, col, alpha, aself, winv, N);
  gat_gather_k<<<aggGrid, 256, 0, stream>>>((const uint4*)B1h, rowp, col, alpha, aself, winv, ba1, B2, N);
  graphnorm(1);

  // ---- GAT layer 2 ----
  gemm_mfma_k<<<gemmGrid, 256, 0, stream>>>(Xb, Wa2p, nullptr, nullptr, (unsigned short*)B1h, N);
  attn_coef_k<<<(N * 4 + 255) / 256, 256, 0, stream>>>((const unsigned short*)B1h, as2, ad2, es, ed, N);
  alpha_k<<<aggGrid, 256, 0, stream>>>(es, ed, rowp, col, alpha, aself, winv, N);
  gat_gather_k<<<aggGrid, 256, 0, stream>>>((const uint4*)B1h, rowp, col, alpha, aself, winv, ba2, B2, N);
  graphnorm(2);

  // ---- hub scores (MFMA) ----
  hub_mfma_k<<<gemmGrid, 256, 0, stream>>>(Xb, W1p, nb1, nw2, nb2, hub, N);

  // ---- pooling + graph MLP ----
  hipMemsetAsync(gsum, 0, (size_t)GG * D * 4, stream);
  init_maxu_k<<<(GG * D + 255) / 256, 256, 0, stream>>>(gmaxu, GG * D);
  pool_stats_k<<<GG * SLICES, 256, 0, stream>>>(X, gstart, gcnt, gsum, gmaxu);
  pool_fin_k<<<GG, D, 0, stream>>>(gsum, gmaxu, gcnt, gf);
  mlp_k<<<GG, 128, 0, stream>>>(gf, hw1, hb1, hw2, hb2, hw3, hb3, logits);
}

// Round 7
// 454.145 us; speedup vs baseline: 1.0379x; 1.0089x over previous
//
#include <hip/hip_runtime.h>
#include <cstdint>

#define D 128
#define GG 64
#define SLICES 16
#define NXCD 8

typedef short bf16x8 __attribute__((ext_vector_type(8)));
typedef float f32x4 __attribute__((ext_vector_type(4)));

// ---------- bf16 helpers ----------
__device__ inline unsigned short bf16u(float f) {
  unsigned u = __float_as_uint(f);
  u = (u + 0x7FFFu + ((u >> 16) & 1u)) >> 16;
  return (unsigned short)u;
}
__device__ inline float2 unpackbf2(unsigned u) {
  return make_float2(__uint_as_float(u << 16), __uint_as_float(u & 0xFFFF0000u));
}
__device__ inline void accum8(float* acc, uint4 v, float w) {
  float2 p0 = unpackbf2(v.x), p1 = unpackbf2(v.y), p2 = unpackbf2(v.z), p3 = unpackbf2(v.w);
  acc[0] += p0.x * w; acc[1] += p0.y * w; acc[2] += p1.x * w; acc[3] += p1.y * w;
  acc[4] += p2.x * w; acc[5] += p2.y * w; acc[6] += p3.x * w; acc[7] += p3.y * w;
}

// ======================= CSR build =======================
__global__ void count_edges_k(const int* __restrict__ dst, int* __restrict__ cnt, int E) {
  int e = blockIdx.x * blockDim.x + threadIdx.x;
  if (e < E) atomicAdd(&cnt[dst[e]], 1);
}

__global__ void bounds_init_k(int* __restrict__ gstart, int* __restrict__ gend) {
  int g = threadIdx.x;
  gstart[g] = 0;
  gend[g] = 0;
}

__global__ void graph_bounds_k(const int* __restrict__ batch, int* __restrict__ gstart,
                               int* __restrict__ gend, int n) {
  int i = blockIdx.x * blockDim.x + threadIdx.x;
  if (i >= n) return;
  int b = batch[i];
  if (i == 0) {
    gstart[b] = 0;
  } else {
    int pb = batch[i - 1];
    if (pb != b) { gstart[b] = i; gend[pb] = i; }
  }
  if (i == n - 1) gend[b] = n;
}

__global__ void gcnt_k(const int* __restrict__ gstart, const int* __restrict__ gend,
                       int* __restrict__ gcnt) {
  int g = threadIdx.x;
  gcnt[g] = gend[g] - gstart[g];
}

__global__ __launch_bounds__(256) void scan1_k(const int* __restrict__ cnt, int* __restrict__ rp,
                                               int* __restrict__ bsum, int n) {
  __shared__ int sd[256];
  int t = threadIdx.x;
  int i = blockIdx.x * 256 + t;
  int v = (i < n) ? cnt[i] : 0;
  sd[t] = v;
  __syncthreads();
#pragma unroll
  for (int off = 1; off < 256; off <<= 1) {
    int u = (t >= off) ? sd[t - off] : 0;
    __syncthreads();
    sd[t] += u;
    __syncthreads();
  }
  if (i < n) rp[i] = sd[t] - v;
  if (t == 255) bsum[blockIdx.x] = sd[255];
}

__global__ __launch_bounds__(256) void scan2_k(int* __restrict__ bsum, int nb) {
  __shared__ int sd[256];
  int t = threadIdx.x;
  int v = (t < nb) ? bsum[t] : 0;
  sd[t] = v;
  __syncthreads();
#pragma unroll
  for (int off = 1; off < 256; off <<= 1) {
    int u = (t >= off) ? sd[t - off] : 0;
    __syncthreads();
    sd[t] += u;
    __syncthreads();
  }
  if (t < nb) bsum[t] = sd[t] - v;
}

// scan3 + dinv fused
__global__ __launch_bounds__(256) void scan3_k(int* __restrict__ rp, const int* __restrict__ bsum,
                                               int* __restrict__ cur, const int* __restrict__ cnt,
                                               float* __restrict__ dinv, int n, int E) {
  int i = blockIdx.x * 256 + threadIdx.x;
  if (i < n) {
    int r = rp[i] + bsum[blockIdx.x];
    rp[i] = r;
    cur[i] = r;
    dinv[i] = rsqrtf((float)cnt[i] + 1.0f);
  }
  if (i == 0) rp[n] = E;
}

// XCD-sliced fill: pass = blockIdx&7 -> (round-robin mapping) all writers of a
// given col slice live on ONE XCD, so its L2 assembles each line once.
__global__ __launch_bounds__(256) void fill_csr_xcd_k(const int* __restrict__ src,
                                                      const int* __restrict__ dst,
                                                      int* __restrict__ cur,
                                                      unsigned short* __restrict__ col,
                                                      int E, int slice) {
  int pass = blockIdx.x & (NXCD - 1);
  int e = (blockIdx.x >> 3) * 256 + threadIdx.x;
  if (e >= E) return;
  int d = dst[e];
  if ((unsigned)(d - pass * slice) < (unsigned)slice) {
    int p = atomicAdd(&cur[d], 1);
    col[p] = (unsigned short)src[e];
  }
}

// ======================= bf16 cast =======================
__global__ void cast_bf16_k(const float* __restrict__ in, unsigned short* __restrict__ outp, int n4) {
  int i = blockIdx.x * blockDim.x + threadIdx.x;
  if (i >= n4) return;
  float4 v = ((const float4*)in)[i];
  ushort4 o;
  o.x = bf16u(v.x); o.y = bf16u(v.y); o.z = bf16u(v.z); o.w = bf16u(v.w);
  ((ushort4*)outp)[i] = o;
}

// ======================= Weight pack into MFMA B-fragment order =======================
__global__ void packB_k(const float* __restrict__ B, unsigned short* __restrict__ Bp, int ldb, int ct) {
  int idx = blockIdx.x * 256 + threadIdx.x;
  if (idx >= ct * 256) return;
  int lane = idx & 63;
  int kc = (idx >> 6) & 3;
  int c = idx >> 8;
  int kb = kc * 32 + (lane >> 4) * 8;
  int colq = c * 16 + (lane & 15);
  unsigned short o[8];
#pragma unroll
  for (int j = 0; j < 8; ++j) o[j] = bf16u(B[(size_t)(kb + j) * ldb + colq]);
  uint4 p;
  p.x = (unsigned)o[0] | ((unsigned)o[1] << 16);
  p.y = (unsigned)o[2] | ((unsigned)o[3] << 16);
  p.z = (unsigned)o[4] | ((unsigned)o[5] << 16);
  p.w = (unsigned)o[6] | ((unsigned)o[7] << 16);
  *(uint4*)&Bp[(size_t)idx * 8] = p;
}

// ======================= MFMA GEMM: [M,128]x[128,128] =======================
__global__ __launch_bounds__(256) void gemm_mfma_k(const unsigned short* __restrict__ Ab,
                                                   const unsigned short* __restrict__ Bp,
                                                   const float* __restrict__ bias,
                                                   float* __restrict__ Cf,
                                                   unsigned short* __restrict__ Cb, int M) {
  __shared__ unsigned short Bs[16384];
  int t = threadIdx.x;
  for (int i = t; i < 2048; i += 256) ((uint4*)Bs)[i] = ((const uint4*)Bp)[i];
  __syncthreads();
  int w = t >> 6, lane = t & 63;
  int row0 = blockIdx.x * 64 + w * 16;
  int arow = row0 + (lane & 15);
  f32x4 acc[8];
#pragma unroll
  for (int c = 0; c < 8; ++c) acc[c] = {0.f, 0.f, 0.f, 0.f};
#pragma unroll
  for (int kc = 0; kc < 4; ++kc) {
    bf16x8 a = {0, 0, 0, 0, 0, 0, 0, 0};
    if (arow < M) a = *(const bf16x8*)&Ab[(size_t)arow * 128 + kc * 32 + (lane >> 4) * 8];
#pragma unroll
    for (int c = 0; c < 8; ++c) {
      bf16x8 b = *(const bf16x8*)&Bs[((c * 4 + kc) * 64 + lane) * 8];
      acc[c] = __builtin_amdgcn_mfma_f32_16x16x32_bf16(a, b, acc[c], 0, 0, 0);
    }
  }
  int rbase = row0 + (lane >> 4) * 4;
#pragma unroll
  for (int c = 0; c < 8; ++c) {
    int colq = c * 16 + (lane & 15);
    float bb = bias ? bias[colq] : 0.f;
#pragma unroll
    for (int r = 0; r < 4; ++r) {
      int row = rbase + r;
      if (row < M) {
        float v = acc[c][r] + bb;
        if (Cf) Cf[(size_t)row * 128 + colq] = v;
        if (Cb) Cb[(size_t)row * 128 + colq] = bf16u(v);
      }
    }
  }
}

// ======================= GCN aggregation (16B/lane, 4 edges per instruction) ============
__global__ __launch_bounds__(256) void gcn_gather_k(const uint4* __restrict__ xw16,
                                                    const int* __restrict__ rp,
                                                    const unsigned short* __restrict__ col,
                                                    const float* __restrict__ dinv, const float* __restrict__ bias,
                                                    float* __restrict__ out, int n) {
  int i = blockIdx.x * 4 + (threadIdx.x >> 6);
  if (i >= n) return;
  int lane = threadIdx.x & 63;
  int g = lane >> 4, sub = lane & 15;
  int e0 = __builtin_amdgcn_readfirstlane(rp[i]);
  int e1 = __builtin_amdgcn_readfirstlane(rp[i + 1]);
  float di = dinv[i];
  float acc[8] = {0.f, 0.f, 0.f, 0.f, 0.f, 0.f, 0.f, 0.f};
  if (g == 0) {
    uint4 v = xw16[(size_t)i * 16 + sub];
    accum8(acc, v, di * di);
  }
  int e = e0;
  for (; e + 15 < e1; e += 16) {
    int s0 = col[e + g];
    int s1 = col[e + 4 + g];
    int s2 = col[e + 8 + g];
    int s3 = col[e + 12 + g];
    float w0 = dinv[s0] * di, w1 = dinv[s1] * di, w2 = dinv[s2] * di, w3 = dinv[s3] * di;
    uint4 v0 = xw16[(size_t)s0 * 16 + sub];
    uint4 v1 = xw16[(size_t)s1 * 16 + sub];
    uint4 v2 = xw16[(size_t)s2 * 16 + sub];
    uint4 v3 = xw16[(size_t)s3 * 16 + sub];
    accum8(acc, v0, w0); accum8(acc, v1, w1); accum8(acc, v2, w2); accum8(acc, v3, w3);
  }
  for (; e < e1; e += 4) {
    bool ok = (e + g) < e1;
    int s0 = ok ? (int)col[e + g] : i;
    float w0 = ok ? dinv[s0] * di : 0.f;
    uint4 v0 = xw16[(size_t)s0 * 16 + sub];
    accum8(acc, v0, w0);
  }
#pragma unroll
  for (int k = 0; k < 8; ++k) {
    acc[k] += __shfl_xor(acc[k], 16, 64);
    acc[k] += __shfl_xor(acc[k], 32, 64);
  }
  if (g == 0) {
    float4 b0 = ((const float4*)bias)[sub * 2], b1 = ((const float4*)bias)[sub * 2 + 1];
    *(float4*)&out[(size_t)i * 128 + sub * 8] =
        make_float4(acc[0] + b0.x, acc[1] + b0.y, acc[2] + b0.z, acc[3] + b0.w);
    *(float4*)&out[(size_t)i * 128 + sub * 8 + 4] =
        make_float4(acc[4] + b1.x, acc[5] + b1.y, acc[6] + b1.z, acc[7] + b1.w);
  }
}

// ======================= GAT attention coefficients (bf16 input) =======================
__global__ void attn_coef_k(const unsigned short* __restrict__ hb, const float* __restrict__ a_s,
                            const float* __restrict__ a_d, float* __restrict__ es,
                            float* __restrict__ ed, int n) {
  int idx = blockIdx.x * blockDim.x + threadIdx.x;
  if (idx >= n * 4) return;
  int node = idx >> 2, hh = idx & 3;
  const uint4* hr = (const uint4*)(hb + (size_t)node * 128 + hh * 32);
  const float4* av = (const float4*)(a_s + hh * 32);
  const float4* dv = (const float4*)(a_d + hh * 32);
  float s = 0.f, d2 = 0.f;
#pragma unroll
  for (int q = 0; q < 4; ++q) {
    uint4 u = hr[q];
    float2 p0 = unpackbf2(u.x), p1 = unpackbf2(u.y), p2 = unpackbf2(u.z), p3 = unpackbf2(u.w);
    float4 a0 = av[q * 2], a1 = av[q * 2 + 1];
    float4 d0 = dv[q * 2], d1 = dv[q * 2 + 1];
    s  += p0.x * a0.x + p0.y * a0.y + p1.x * a0.z + p1.y * a0.w
        + p2.x * a1.x + p2.y * a1.y + p3.x * a1.z + p3.y * a1.w;
    d2 += p0.x * d0.x + p0.y * d0.y + p1.x * d0.z + p1.y * d0.w
        + p2.x * d1.x + p2.y * d1.y + p3.x * d1.z + p3.y * d1.w;
  }
  es[idx] = s;
  ed[idx] = d2;
}

// ======================= GAT alpha precompute (unnormalized; winv factored out) ==============
__global__ __launch_bounds__(256) void alpha_k(const float* __restrict__ es, const float* __restrict__ ed,
                                               const int* __restrict__ rp,
                                               const unsigned short* __restrict__ col,
                                               float* __restrict__ alpha, float* __restrict__ aself,
                                               float* __restrict__ winv, int n) {
  int i = blockIdx.x * 4 + (threadIdx.x >> 6);
  if (i >= n) return;
  int lane = threadIdx.x & 63;
  int hh = lane >> 4, slot = lane & 15;
  int e0 = __builtin_amdgcn_readfirstlane(rp[i]);
  int e1 = __builtin_amdgcn_readfirstlane(rp[i + 1]);
  float edi = ed[i * 4 + hh];
  float esf = es[i * 4 + hh] + edi;
  esf = esf >= 0.f ? esf : 0.2f * esf;
  float m = esf;
  for (int e = e0 + slot; e < e1; e += 16) {
    int sj = col[e];
    float ev = es[sj * 4 + hh] + edi;
    ev = ev >= 0.f ? ev : 0.2f * ev;
    alpha[(size_t)e * 4 + hh] = ev;
    m = fmaxf(m, ev);
  }
#pragma unroll
  for (int off = 1; off < 16; off <<= 1) m = fmaxf(m, __shfl_xor(m, off, 64));
  float s = (slot == 0) ? __expf(esf - m) : 0.f;
  for (int e = e0 + slot; e < e1; e += 16) {
    float w = __expf(alpha[(size_t)e * 4 + hh] - m);
    alpha[(size_t)e * 4 + hh] = w;
    s += w;
  }
#pragma unroll
  for (int off = 1; off < 16; off <<= 1) s += __shfl_xor(s, off, 64);
  if (slot == 0) {
    aself[i * 4 + hh] = __expf(esf - m);
    winv[i * 4 + hh] = 1.0f / (s + 1e-16f);
  }
}

// ======================= GAT gather (16B/lane, 4 edges per instruction) ================
__global__ __launch_bounds__(256) void gat_gather_k(const uint4* __restrict__ hf16,
                                                    const int* __restrict__ rp,
                                                    const unsigned short* __restrict__ col,
                                                    const float* __restrict__ alpha, const float* __restrict__ aself,
                                                    const float* __restrict__ winv,
                                                    const float* __restrict__ bias, float* __restrict__ out, int n) {
  int i = blockIdx.x * 4 + (threadIdx.x >> 6);
  if (i >= n) return;
  int lane = threadIdx.x & 63;
  int g = lane >> 4, sub = lane & 15;
  int hh = sub >> 2;
  int e0 = __builtin_amdgcn_readfirstlane(rp[i]);
  int e1 = __builtin_amdgcn_readfirstlane(rp[i + 1]);
  float acc[8] = {0.f, 0.f, 0.f, 0.f, 0.f, 0.f, 0.f, 0.f};
  if (g == 0) {
    uint4 v = hf16[(size_t)i * 16 + sub];
    accum8(acc, v, aself[i * 4 + hh]);
  }
  int e = e0;
  for (; e + 15 < e1; e += 16) {
    int s0 = col[e + g];
    int s1 = col[e + 4 + g];
    int s2 = col[e + 8 + g];
    int s3 = col[e + 12 + g];
    float a0 = alpha[(size_t)(e + g) * 4 + hh];
    float a1 = alpha[(size_t)(e + 4 + g) * 4 + hh];
    float a2 = alpha[(size_t)(e + 8 + g) * 4 + hh];
    float a3 = alpha[(size_t)(e + 12 + g) * 4 + hh];
    uint4 v0 = hf16[(size_t)s0 * 16 + sub];
    uint4 v1 = hf16[(size_t)s1 * 16 + sub];
    uint4 v2 = hf16[(size_t)s2 * 16 + sub];
    uint4 v3 = hf16[(size_t)s3 * 16 + sub];
    accum8(acc, v0, a0); accum8(acc, v1, a1); accum8(acc, v2, a2); accum8(acc, v3, a3);
  }
  for (; e < e1; e += 4) {
    bool ok = (e + g) < e1;
    int s0 = ok ? (int)col[e + g] : i;
    float a0 = ok ? alpha[(size_t)(e + g) * 4 + hh] : 0.f;
    uint4 v0 = hf16[(size_t)s0 * 16 + sub];
    accum8(acc, v0, a0);
  }
#pragma unroll
  for (int k = 0; k < 8; ++k) {
    acc[k] += __shfl_xor(acc[k], 16, 64);
    acc[k] += __shfl_xor(acc[k], 32, 64);
  }
  if (g == 0) {
    float wi = winv[i * 4 + hh];
    float4 b0 = ((const float4*)bias)[sub * 2], b1 = ((const float4*)bias)[sub * 2 + 1];
    *(float4*)&out[(size_t)i * 128 + sub * 8] =
        make_float4(acc[0] * wi + b0.x, acc[1] * wi + b0.y, acc[2] * wi + b0.z, acc[3] * wi + b0.w);
    *(float4*)&out[(size_t)i * 128 + sub * 8 + 4] =
        make_float4(acc[4] * wi + b1.x, acc[5] * wi + b1.y, acc[6] * wi + b1.z, acc[7] * wi + b1.w);
  }
}

// ======================= GraphNorm =======================
__global__ __launch_bounds__(256) void gn_stats_k(const float* __restrict__ h, const int* __restrict__ gstart,
                                                  const int* __restrict__ gcnt, float* __restrict__ gsum,
                                                  float* __restrict__ gsq) {
  int g = blockIdx.x / SLICES, sl = blockIdx.x % SLICES;
  int st = gstart[g], cn = gcnt[g];
  int d = threadIdx.x & 127, half = threadIdx.x >> 7;
  float s = 0.f, ss = 0.f;
  for (int r = sl * 2 + half; r < cn; r += 2 * SLICES) {
    float v = h[(size_t)(st + r) * D + d];
    s += v; ss += v * v;
  }
  __shared__ float l1[128], l2[128];
  if (half) { l1[d] = s; l2[d] = ss; }
  __syncthreads();
  if (!half) {
    atomicAdd(&gsum[g * D + d], s + l1[d]);
    atomicAdd(&gsq[g * D + d], ss + l2[d]);
  }
}

__global__ void gn_finalize_k(const float* __restrict__ gsum, const float* __restrict__ gsq,
                              const int* __restrict__ gcnt, const float* __restrict__ ms,
                              float* __restrict__ mean, float* __restrict__ rstd) {
  int g = blockIdx.x, d = threadIdx.x;
  float cnt = fmaxf((float)gcnt[g], 1.0f);
  float mu = gsum[g * D + d] / cnt;
  float m2 = gsq[g * D + d] / cnt;
  float s = ms[d];
  float var = m2 - (2.0f * s - s * s) * mu * mu;
  mean[g * D + d] = mu;
  rstd[g * D + d] = rsqrtf(fmaxf(var, 0.0f) + 1e-5f);
}

__global__ void gn_apply_k(const float* __restrict__ h, float* __restrict__ x,
                           unsigned short* __restrict__ xb,
                           const int* __restrict__ batch, const float* __restrict__ mean,
                           const float* __restrict__ rstd, const float* __restrict__ w,
                           const float* __restrict__ b, const float* __restrict__ ms, int n) {
  int idx = blockIdx.x * blockDim.x + threadIdx.x;
  if (idx >= n * 32) return;
  int node = idx >> 5, q = idx & 31;
  int g = batch[node];
  int d0 = q * 4;
  float4 hv = ((const float4*)h)[idx];
  float4 xv = ((const float4*)x)[idx];
  float ha[4] = {hv.x, hv.y, hv.z, hv.w};
  float xa[4] = {xv.x, xv.y, xv.z, xv.w};
  float ra[4];
#pragma unroll
  for (int j = 0; j < 4; ++j) {
    int d = d0 + j;
    float sub = ha[j] - ms[d] * mean[g * D + d];
    float v = w[d] * sub * rstd[g * D + d] + b[d];
    ra[j] = fmaxf(v, 0.f) + xa[j];
  }
  ((float4*)x)[idx] = make_float4(ra[0], ra[1], ra[2], ra[3]);
  ushort4 o;
  o.x = bf16u(ra[0]); o.y = bf16u(ra[1]); o.z = bf16u(ra[2]); o.w = bf16u(ra[3]);
  ((ushort4*)xb)[idx] = o;
}

// ======================= Hub scores (MFMA) =======================
__global__ __launch_bounds__(256) void hub_mfma_k(const unsigned short* __restrict__ Xb,
                                                  const unsigned short* __restrict__ W1p,
                                                  const float* __restrict__ nb1, const float* __restrict__ nw2,
                                                  const float* __restrict__ nb2, float* __restrict__ out, int n) {
  __shared__ unsigned short Bs[8192];
  int t = threadIdx.x;
  for (int i = t; i < 1024; i += 256) ((uint4*)Bs)[i] = ((const uint4*)W1p)[i];
  __syncthreads();
  int w = t >> 6, lane = t & 63;
  int row0 = blockIdx.x * 64 + w * 16;
  int arow = row0 + (lane & 15);
  f32x4 acc[4];
#pragma unroll
  for (int c = 0; c < 4; ++c) acc[c] = {0.f, 0.f, 0.f, 0.f};
#pragma unroll
  for (int kc = 0; kc < 4; ++kc) {
    bf16x8 a = {0, 0, 0, 0, 0, 0, 0, 0};
    if (arow < n) a = *(const bf16x8*)&Xb[(size_t)arow * 128 + kc * 32 + (lane >> 4) * 8];
#pragma unroll
    for (int c = 0; c < 4; ++c) {
      bf16x8 b = *(const bf16x8*)&Bs[((c * 4 + kc) * 64 + lane) * 8];
      acc[c] = __builtin_amdgcn_mfma_f32_16x16x32_bf16(a, b, acc[c], 0, 0, 0);
    }
  }
  float b2 = nb2[0];
  float s[4] = {0.f, 0.f, 0.f, 0.f};
#pragma unroll
  for (int c = 0; c < 4; ++c) {
    int colq = c * 16 + (lane & 15);
    float b1 = nb1[colq];
    float w2 = nw2[colq];
#pragma unroll
    for (int r = 0; r < 4; ++r) s[r] += fmaxf(acc[c][r] + b1, 0.f) * w2;
  }
#pragma unroll
  for (int off = 1; off < 16; off <<= 1) {
#pragma unroll
    for (int r = 0; r < 4; ++r) s[r] += __shfl_xor(s[r], off, 64);
  }
  if ((lane & 15) == 0) {
    int rbase = row0 + (lane >> 4) * 4;
#pragma unroll
    for (int r = 0; r < 4; ++r) {
      int row = rbase + r;
      if (row < n) out[row] = 1.0f / (1.0f + __expf(-(s[r] + b2)));
    }
  }
}

// ======================= Pooling =======================
__global__ void init_maxu_k(unsigned* __restrict__ p, int n) {
  int i = blockIdx.x * blockDim.x + threadIdx.x;
  if (i < n) p[i] = 0x007FFFFFu;
}

__global__ __launch_bounds__(256) void pool_stats_k(const float* __restrict__ x, const int* __restrict__ gstart,
                                                    const int* __restrict__ gcnt, float* __restrict__ gsum,
                                                    unsigned* __restrict__ gmaxu) {
  int g = blockIdx.x / SLICES, sl = blockIdx.x % SLICES;
  int st = gstart[g], cn = gcnt[g];
  int d = threadIdx.x & 127, half = threadIdx.x >> 7;
  float s = 0.f, mx = __uint_as_float(0xFF800000u);
  for (int r = sl * 2 + half; r < cn; r += 2 * SLICES) {
    float v = x[(size_t)(st + r) * D + d];
    s += v; mx = fmaxf(mx, v);
  }
  __shared__ float l1[128], l2[128];
  if (half) { l1[d] = s; l2[d] = mx; }
  __syncthreads();
  if (!half) {
    s += l1[d];
    mx = fmaxf(mx, l2[d]);
    atomicAdd(&gsum[g * D + d], s);
    unsigned u = __float_as_uint(mx);
    u = (u & 0x80000000u) ? ~u : (u | 0x80000000u);
    atomicMax(&gmaxu[g * D + d], u);
  }
}

__global__ void pool_fin_k(const float* __restrict__ gsum, const unsigned* __restrict__ gmaxu,
                           const int* __restrict__ gcnt, float* __restrict__ gf) {
  int g = blockIdx.x, d = threadIdx.x;
  float cnt = fmaxf((float)gcnt[g], 1.0f);
  gf[g * 256 + d] = gsum[g * D + d] / cnt;
  unsigned u = gmaxu[g * D + d];
  unsigned bits = (u & 0x80000000u) ? (u ^ 0x80000000u) : ~u;
  gf[g * 256 + 128 + d] = __uint_as_float(bits);
}

// ======================= Graph MLP =======================
__global__ __launch_bounds__(128) void mlp_k(const float* __restrict__ gf, const float* __restrict__ hw1,
                                             const float* __restrict__ hb1, const float* __restrict__ hw2,
                                             const float* __restrict__ hb2, const float* __restrict__ hw3,
                                             const float* __restrict__ hb3, float* __restrict__ logits) {
  __shared__ float sg[256], z1[128], z2[64];
  int g = blockIdx.x, t = threadIdx.x;
  sg[t] = gf[g * 256 + t];
  sg[t + 128] = gf[g * 256 + 128 + t];
  __syncthreads();
  float a = hb1[t];
  for (int k = 0; k < 256; ++k) a += sg[k] * hw1[k * 128 + t];
  z1[t] = fmaxf(a, 0.f);
  __syncthreads();
  if (t < 64) {
    float a2 = hb2[t];
    for (int k = 0; k < 128; ++k) a2 += z1[k] * hw2[k * 64 + t];
    z2[t] = fmaxf(a2, 0.f);
  }
  __syncthreads();
  if (t < 2) {
    float a3 = hb3[t];
    for (int k = 0; k < 64; ++k) a3 += z2[k] * hw3[k * 2 + t];
    logits[g * 2 + t] = a3;
  }
}

// ======================= Host =======================
extern "C" void kernel_launch(void* const* d_in, const int* in_sizes, int n_in,
                              void* d_out, int out_size, void* d_ws, size_t ws_size,
                              hipStream_t stream) {
  const float* x_in  = (const float*)d_in[0];
  const int*   eidx  = (const int*)d_in[1];
  const int*   batch = (const int*)d_in[2];
  const float* Wp  = (const float*)d_in[3];
  const float* bp  = (const float*)d_in[4];
  const float* Wg  = (const float*)d_in[5];
  const float* bg  = (const float*)d_in[6];
  const float* Wa1 = (const float*)d_in[7];
  const float* as1 = (const float*)d_in[8];
  const float* ad1 = (const float*)d_in[9];
  const float* ba1 = (const float*)d_in[10];
  const float* Wa2 = (const float*)d_in[11];
  const float* as2 = (const float*)d_in[12];
  const float* ad2 = (const float*)d_in[13];
  const float* ba2 = (const float*)d_in[14];
  const float* gnw[3] = {(const float*)d_in[15], (const float*)d_in[18], (const float*)d_in[21]};
  const float* gnb[3] = {(const float*)d_in[16], (const float*)d_in[19], (const float*)d_in[22]};
  const float* gns[3] = {(const float*)d_in[17], (const float*)d_in[20], (const float*)d_in[23]};
  const float* hw1 = (const float*)d_in[24];
  const float* hb1 = (const float*)d_in[25];
  const float* hw2 = (const float*)d_in[26];
  const float* hb2 = (const float*)d_in[27];
  const float* hw3 = (const float*)d_in[28];
  const float* hb3 = (const float*)d_in[29];
  const float* nw1 = (const float*)d_in[30];
  const float* nb1 = (const float*)d_in[31];
  const float* nw2 = (const float*)d_in[32];
  const float* nb2 = (const float*)d_in[33];

  const int N = in_sizes[0] / D;
  const int E = in_sizes[1] / 2;
  const int* src = eidx;
  const int* dst = eidx + E;

  float* out    = (float*)d_out;
  float* logits = out;
  float* hub    = out + GG * 2;
  float* gf     = out + GG * 2 + N;
  float* X      = out + GG * 2 + N + GG * 256;

  char* wp = (char*)d_ws;
  auto alloc = [&](size_t bytes) { char* p = wp; wp += (bytes + 255) & ~(size_t)255; return p; };
  float*    B1    = (float*)alloc((size_t)N * D * 4);
  float*    B2    = (float*)alloc((size_t)N * D * 4);
  unsigned* B1h   = (unsigned*)alloc((size_t)N * (D / 2) * 4);
  unsigned short* Xb = (unsigned short*)alloc((size_t)N * D * 2);
  unsigned short* col = (unsigned short*)alloc((size_t)E * 2);
  int*   cnt     = (int*)alloc((size_t)N * 4);
  int*   rowp    = (int*)alloc((size_t)(N + 1) * 4);
  int*   cur     = (int*)alloc((size_t)N * 4);
  float* dinv    = (float*)alloc((size_t)N * 4);
  float* es      = (float*)alloc((size_t)N * 4 * 4);
  float* ed      = (float*)alloc((size_t)N * 4 * 4);
  float* aself   = (float*)alloc((size_t)N * 4 * 4);
  float* winv    = (float*)alloc((size_t)N * 4 * 4);
  float* gsum    = (float*)alloc((size_t)GG * D * 4);
  float* gsq     = (float*)alloc((size_t)GG * D * 4);
  unsigned* gmaxu = (unsigned*)alloc((size_t)GG * D * 4);
  float* mean    = (float*)alloc((size_t)GG * D * 4);
  float* rstd    = (float*)alloc((size_t)GG * D * 4);
  int*   gcnt    = (int*)alloc((size_t)GG * 4);
  int*   gstart  = (int*)alloc((size_t)GG * 4);
  int*   gend    = (int*)alloc((size_t)GG * 4);
  int*   bsum    = (int*)alloc((size_t)256 * 4);
  unsigned short* Wpp  = (unsigned short*)alloc(16384 * 2);
  unsigned short* Wgp  = (unsigned short*)alloc(16384 * 2);
  unsigned short* Wa1p = (unsigned short*)alloc(16384 * 2);
  unsigned short* Wa2p = (unsigned short*)alloc(16384 * 2);
  unsigned short* W1p  = (unsigned short*)alloc(8192 * 2);
  float* alpha = B1;
  unsigned short* xinb = (unsigned short*)B2;
  if ((size_t)(wp - (char*)d_ws) > ws_size) return;

  const int nb = (N + 255) / 256;

  // ---- CSR + graph ranges ----
  hipMemsetAsync(cnt, 0, (size_t)N * 4, stream);
  count_edges_k<<<(E + 255) / 256, 256, 0, stream>>>(dst, cnt, E);
  bounds_init_k<<<1, GG, 0, stream>>>(gstart, gend);
  graph_bounds_k<<<nb, 256, 0, stream>>>(batch, gstart, gend, N);
  gcnt_k<<<1, GG, 0, stream>>>(gstart, gend, gcnt);
  scan1_k<<<nb, 256, 0, stream>>>(cnt, rowp, bsum, N);
  scan2_k<<<1, 256, 0, stream>>>(bsum, nb);
  scan3_k<<<nb, 256, 0, stream>>>(rowp, bsum, cur, cnt, dinv, N, E);
  {
    int chunks = (E + 255) / 256;
    int slice = (N + NXCD - 1) / NXCD;
    fill_csr_xcd_k<<<chunks * NXCD, 256, 0, stream>>>(src, dst, cur, col, E, slice);
  }

  // ---- weight packs + input cast ----
  packB_k<<<8, 256, 0, stream>>>(Wp, Wpp, 128, 8);
  packB_k<<<8, 256, 0, stream>>>(Wg, Wgp, 128, 8);
  packB_k<<<8, 256, 0, stream>>>(Wa1, Wa1p, 128, 8);
  packB_k<<<8, 256, 0, stream>>>(Wa2, Wa2p, 128, 8);
  packB_k<<<4, 256, 0, stream>>>(nw1, W1p, 64, 4);
  cast_bf16_k<<<(N * 32 + 255) / 256, 256, 0, stream>>>(x_in, xinb, N * 32);

  const int gemmGrid = (N + 63) / 64;
  const int aggGrid  = (N + 3) / 4;

  auto graphnorm = [&](int layer) {
    hipMemsetAsync(gsum, 0, 2 * (size_t)GG * D * 4, stream);
    gn_stats_k<<<GG * SLICES, 256, 0, stream>>>(B2, gstart, gcnt, gsum, gsq);
    gn_finalize_k<<<GG, D, 0, stream>>>(gsum, gsq, gcnt, gns[layer], mean, rstd);
    gn_apply_k<<<(N * 32 + 255) / 256, 256, 0, stream>>>(B2, X, Xb, batch, mean, rstd,
                                                         gnw[layer], gnb[layer], gns[layer], N);
  };

  // ---- projection ----
  gemm_mfma_k<<<gemmGrid, 256, 0, stream>>>(xinb, Wpp, bp, X, Xb, N);

  // ---- GCN layer ----
  gemm_mfma_k<<<gemmGrid, 256, 0, stream>>>(Xb, Wgp, nullptr, nullptr, (unsigned short*)B1h, N);
  gcn_gather_k<<<aggGrid, 256, 0, stream>>>((const uint4*)B1h, rowp, col, dinv, bg, B2, N);
  graphnorm(0);

  // ---- GAT layer 1 ----
  gemm_mfma_k<<<gemmGrid, 256, 0, stream>>>(Xb, Wa1p, nullptr, nullptr, (unsigned short*)B1h, N);
  attn_coef_k<<<(N * 4 + 255) / 256, 256, 0, stream>>>((const unsigned short*)B1h, as1, ad1, es, ed, N);
  alpha_k<<<aggGrid, 256, 0, stream>>>(es, ed, rowp, col, alpha, aself, winv, N);
  gat_gather_k<<<aggGrid, 256, 0, stream>>>((const uint4*)B1h, rowp, col, alpha, aself, winv, ba1, B2, N);
  graphnorm(1);

  // ---- GAT layer 2 ----
  gemm_mfma_k<<<gemmGrid, 256, 0, stream>>>(Xb, Wa2p, nullptr, nullptr, (unsigned short*)B1h, N);
  attn_coef_k<<<(N * 4 + 255) / 256, 256, 0, stream>>>((const unsigned short*)B1h, as2, ad2, es, ed, N);
  alpha_k<<<aggGrid, 256, 0, stream>>>(es, ed, rowp, col, alpha, aself, winv, N);
  gat_gather_k<<<aggGrid, 256, 0, stream>>>((const uint4*)B1h, rowp, col, alpha, aself, winv, ba2, B2, N);
  graphnorm(2);

  // ---- hub scores (MFMA) ----
  hub_mfma_k<<<gemmGrid, 256, 0, stream>>>(Xb, W1p, nb1, nw2, nb2, hub, N);

  // ---- pooling + graph MLP ----
  hipMemsetAsync(gsum, 0, (size_t)GG * D * 4, stream);
  init_maxu_k<<<(GG * D + 255) / 256, 256, 0, stream>>>(gmaxu, GG * D);
  pool_stats_k<<<GG * SLICES, 256, 0, stream>>>(X, gstart, gcnt, gsum, gmaxu);
  pool_fin_k<<<GG, D, 0, stream>>>(gsum, gmaxu, gcnt, gf);
  mlp_k<<<GG, 128, 0, stream>>>(gf, hw1, hb1, hw2, hb2, hw3, hb3, logits);
}

// Round 8
// 414.528 us; speedup vs baseline: 1.1370x; 1.0956x over previous
//
#include <hip/hip_runtime.h>
#include <cstdint>

#define D 128
#define GG 64
#define SLICES 16
#define NXCD 8

typedef short bf16x8 __attribute__((ext_vector_type(8)));
typedef float f32x4 __attribute__((ext_vector_type(4)));

// ---------- bf16 helpers ----------
__device__ inline unsigned short bf16u(float f) {
  unsigned u = __float_as_uint(f);
  u = (u + 0x7FFFu + ((u >> 16) & 1u)) >> 16;
  return (unsigned short)u;
}
__device__ inline float2 unpackbf2(unsigned u) {
  return make_float2(__uint_as_float(u << 16), __uint_as_float(u & 0xFFFF0000u));
}
__device__ inline void accum8(float* acc, uint4 v, float w) {
  float2 p0 = unpackbf2(v.x), p1 = unpackbf2(v.y), p2 = unpackbf2(v.z), p3 = unpackbf2(v.w);
  acc[0] += p0.x * w; acc[1] += p0.y * w; acc[2] += p1.x * w; acc[3] += p1.y * w;
  acc[4] += p2.x * w; acc[5] += p2.y * w; acc[6] += p3.x * w; acc[7] += p3.y * w;
}

// ======================= CSR build =======================
__global__ void count_edges_k(const int* __restrict__ dst, int* __restrict__ cnt, int E) {
  int e = blockIdx.x * blockDim.x + threadIdx.x;
  if (e < E) atomicAdd(&cnt[dst[e]], 1);
}

__global__ void bounds_init_k(int* __restrict__ gstart, int* __restrict__ gend) {
  int g = threadIdx.x;
  gstart[g] = 0;
  gend[g] = 0;
}

__global__ void graph_bounds_k(const int* __restrict__ batch, int* __restrict__ gstart,
                               int* __restrict__ gend, int n) {
  int i = blockIdx.x * blockDim.x + threadIdx.x;
  if (i >= n) return;
  int b = batch[i];
  if (i == 0) {
    gstart[b] = 0;
  } else {
    int pb = batch[i - 1];
    if (pb != b) { gstart[b] = i; gend[pb] = i; }
  }
  if (i == n - 1) gend[b] = n;
}

__global__ void gcnt_k(const int* __restrict__ gstart, const int* __restrict__ gend,
                       int* __restrict__ gcnt) {
  int g = threadIdx.x;
  gcnt[g] = gend[g] - gstart[g];
}

__global__ __launch_bounds__(256) void scan1_k(const int* __restrict__ cnt, int* __restrict__ rp,
                                               int* __restrict__ bsum, int n) {
  __shared__ int sd[256];
  int t = threadIdx.x;
  int i = blockIdx.x * 256 + t;
  int v = (i < n) ? cnt[i] : 0;
  sd[t] = v;
  __syncthreads();
#pragma unroll
  for (int off = 1; off < 256; off <<= 1) {
    int u = (t >= off) ? sd[t - off] : 0;
    __syncthreads();
    sd[t] += u;
    __syncthreads();
  }
  if (i < n) rp[i] = sd[t] - v;
  if (t == 255) bsum[blockIdx.x] = sd[255];
}

__global__ __launch_bounds__(256) void scan2_k(int* __restrict__ bsum, int nb) {
  __shared__ int sd[256];
  int t = threadIdx.x;
  int v = (t < nb) ? bsum[t] : 0;
  sd[t] = v;
  __syncthreads();
#pragma unroll
  for (int off = 1; off < 256; off <<= 1) {
    int u = (t >= off) ? sd[t - off] : 0;
    __syncthreads();
    sd[t] += u;
    __syncthreads();
  }
  if (t < nb) bsum[t] = sd[t] - v;
}

// scan3 + dinv fused
__global__ __launch_bounds__(256) void scan3_k(int* __restrict__ rp, const int* __restrict__ bsum,
                                               int* __restrict__ cur, const int* __restrict__ cnt,
                                               float* __restrict__ dinv, int n, int E) {
  int i = blockIdx.x * 256 + threadIdx.x;
  if (i < n) {
    int r = rp[i] + bsum[blockIdx.x];
    rp[i] = r;
    cur[i] = r;
    dinv[i] = rsqrtf((float)cnt[i] + 1.0f);
  }
  if (i == 0) rp[n] = E;
}

__global__ __launch_bounds__(256) void fill_csr_xcd_k(const int* __restrict__ src,
                                                      const int* __restrict__ dst,
                                                      int* __restrict__ cur,
                                                      unsigned short* __restrict__ col,
                                                      int E, int slice) {
  int pass = blockIdx.x & (NXCD - 1);
  int e = (blockIdx.x >> 3) * 256 + threadIdx.x;
  if (e >= E) return;
  int d = dst[e];
  if ((unsigned)(d - pass * slice) < (unsigned)slice) {
    int p = atomicAdd(&cur[d], 1);
    col[p] = (unsigned short)src[e];
  }
}

// ======================= bf16 cast =======================
__global__ void cast_bf16_k(const float* __restrict__ in, unsigned short* __restrict__ outp, int n4) {
  int i = blockIdx.x * blockDim.x + threadIdx.x;
  if (i >= n4) return;
  float4 v = ((const float4*)in)[i];
  ushort4 o;
  o.x = bf16u(v.x); o.y = bf16u(v.y); o.z = bf16u(v.z); o.w = bf16u(v.w);
  ((ushort4*)outp)[i] = o;
}

// ======================= Weight pack into MFMA B-fragment order =======================
__global__ void packB_k(const float* __restrict__ B, unsigned short* __restrict__ Bp, int ldb, int ct) {
  int idx = blockIdx.x * 256 + threadIdx.x;
  if (idx >= ct * 256) return;
  int lane = idx & 63;
  int kc = (idx >> 6) & 3;
  int c = idx >> 8;
  int kb = kc * 32 + (lane >> 4) * 8;
  int colq = c * 16 + (lane & 15);
  unsigned short o[8];
#pragma unroll
  for (int j = 0; j < 8; ++j) o[j] = bf16u(B[(size_t)(kb + j) * ldb + colq]);
  uint4 p;
  p.x = (unsigned)o[0] | ((unsigned)o[1] << 16);
  p.y = (unsigned)o[2] | ((unsigned)o[3] << 16);
  p.z = (unsigned)o[4] | ((unsigned)o[5] << 16);
  p.w = (unsigned)o[6] | ((unsigned)o[7] << 16);
  *(uint4*)&Bp[(size_t)idx * 8] = p;
}

// ======================= MFMA GEMM: [M,128]x[128,128] + fused extras ==================
// rowscale: optional per-row scale applied to bf16 output (GCN dinv fold)
// as_flat/ad_flat: optional GAT attention vectors -> es/ed per (node, head)
__global__ __launch_bounds__(256) void gemm_mfma_k(const unsigned short* __restrict__ Ab,
                                                   const unsigned short* __restrict__ Bp,
                                                   const float* __restrict__ bias,
                                                   float* __restrict__ Cf,
                                                   unsigned short* __restrict__ Cb,
                                                   const float* __restrict__ rowscale,
                                                   const float* __restrict__ as_flat,
                                                   const float* __restrict__ ad_flat,
                                                   float* __restrict__ es, float* __restrict__ ed,
                                                   int M) {
  __shared__ unsigned short Bs[16384];
  int t = threadIdx.x;
  for (int i = t; i < 2048; i += 256) ((uint4*)Bs)[i] = ((const uint4*)Bp)[i];
  __syncthreads();
  int w = t >> 6, lane = t & 63;
  int row0 = blockIdx.x * 64 + w * 16;
  int arow = row0 + (lane & 15);
  f32x4 acc[8];
#pragma unroll
  for (int c = 0; c < 8; ++c) acc[c] = {0.f, 0.f, 0.f, 0.f};
#pragma unroll
  for (int kc = 0; kc < 4; ++kc) {
    bf16x8 a = {0, 0, 0, 0, 0, 0, 0, 0};
    if (arow < M) a = *(const bf16x8*)&Ab[(size_t)arow * 128 + kc * 32 + (lane >> 4) * 8];
#pragma unroll
    for (int c = 0; c < 8; ++c) {
      bf16x8 b = *(const bf16x8*)&Bs[((c * 4 + kc) * 64 + lane) * 8];
      acc[c] = __builtin_amdgcn_mfma_f32_16x16x32_bf16(a, b, acc[c], 0, 0, 0);
    }
  }
  int l15 = lane & 15;
  int rbase = row0 + (lane >> 4) * 4;
#pragma unroll
  for (int c = 0; c < 8; ++c) {
    int colq = c * 16 + l15;
    float bb = bias ? bias[colq] : 0.f;
#pragma unroll
    for (int r = 0; r < 4; ++r) {
      int row = rbase + r;
      if (row < M) {
        float v = acc[c][r] + bb;
        if (Cf) Cf[(size_t)row * 128 + colq] = v;
        if (Cb) {
          float rs = rowscale ? rowscale[row] : 1.f;
          Cb[(size_t)row * 128 + colq] = bf16u(v * rs);
        }
      }
    }
  }
  if (as_flat) {
    // es[n,h] = sum_c H[n, h*32+c] * a_s[h,c]; ed likewise (H = acc, bias==null here)
    float pe[4][4], pd[4][4];
#pragma unroll
    for (int h = 0; h < 4; ++h) {
      float a0 = as_flat[h * 32 + l15], a1 = as_flat[h * 32 + 16 + l15];
      float d0 = ad_flat[h * 32 + l15], d1 = ad_flat[h * 32 + 16 + l15];
#pragma unroll
      for (int r = 0; r < 4; ++r) {
        pe[h][r] = acc[2 * h][r] * a0 + acc[2 * h + 1][r] * a1;
        pd[h][r] = acc[2 * h][r] * d0 + acc[2 * h + 1][r] * d1;
      }
    }
#pragma unroll
    for (int off = 1; off < 16; off <<= 1) {
#pragma unroll
      for (int h = 0; h < 4; ++h)
#pragma unroll
        for (int r = 0; r < 4; ++r) {
          pe[h][r] += __shfl_xor(pe[h][r], off, 64);
          pd[h][r] += __shfl_xor(pd[h][r], off, 64);
        }
    }
    int hh = l15 & 3, rr = l15 >> 2;
    int row = rbase + rr;
    if (row < M) {
      es[row * 4 + hh] = pe[hh][rr];
      ed[row * 4 + hh] = pd[hh][rr];
    }
  }
}

// ======================= GCN aggregation (prescaled rows: pure adds) ============
__global__ __launch_bounds__(256) void gcn_gather_k(const uint4* __restrict__ xw16,
                                                    const int* __restrict__ rp,
                                                    const unsigned short* __restrict__ col,
                                                    const float* __restrict__ dinv, const float* __restrict__ bias,
                                                    float* __restrict__ out, int n) {
  int i = blockIdx.x * 4 + (threadIdx.x >> 6);
  if (i >= n) return;
  int lane = threadIdx.x & 63;
  int g = lane >> 4, sub = lane & 15;
  int e0 = __builtin_amdgcn_readfirstlane(rp[i]);
  int e1 = __builtin_amdgcn_readfirstlane(rp[i + 1]);
  float acc[8] = {0.f, 0.f, 0.f, 0.f, 0.f, 0.f, 0.f, 0.f};
  if (g == 0) {
    uint4 v = xw16[(size_t)i * 16 + sub];   // row already scaled by dinv[i]
    accum8(acc, v, 1.f);
  }
  int e = e0;
  for (; e + 15 < e1; e += 16) {
    int s0 = col[e + g];
    int s1 = col[e + 4 + g];
    int s2 = col[e + 8 + g];
    int s3 = col[e + 12 + g];
    uint4 v0 = xw16[(size_t)s0 * 16 + sub];
    uint4 v1 = xw16[(size_t)s1 * 16 + sub];
    uint4 v2 = xw16[(size_t)s2 * 16 + sub];
    uint4 v3 = xw16[(size_t)s3 * 16 + sub];
    accum8(acc, v0, 1.f); accum8(acc, v1, 1.f); accum8(acc, v2, 1.f); accum8(acc, v3, 1.f);
  }
  for (; e < e1; e += 4) {
    bool ok = (e + g) < e1;
    int s0 = ok ? (int)col[e + g] : i;
    float w0 = ok ? 1.f : 0.f;
    uint4 v0 = xw16[(size_t)s0 * 16 + sub];
    accum8(acc, v0, w0);
  }
#pragma unroll
  for (int k = 0; k < 8; ++k) {
    acc[k] += __shfl_xor(acc[k], 16, 64);
    acc[k] += __shfl_xor(acc[k], 32, 64);
  }
  if (g == 0) {
    float di = dinv[i];
    float4 b0 = ((const float4*)bias)[sub * 2], b1 = ((const float4*)bias)[sub * 2 + 1];
    *(float4*)&out[(size_t)i * 128 + sub * 8] =
        make_float4(acc[0] * di + b0.x, acc[1] * di + b0.y, acc[2] * di + b0.z, acc[3] * di + b0.w);
    *(float4*)&out[(size_t)i * 128 + sub * 8 + 4] =
        make_float4(acc[4] * di + b1.x, acc[5] * di + b1.y, acc[6] * di + b1.z, acc[7] * di + b1.w);
  }
}

// ======================= GAT gather (fused direct-exp softmax) ================
// softmax shift-invariance: w = exp(lrelu(e)) directly (|e| << 80), normalize by 1/sum.
__global__ __launch_bounds__(256) void gat_gather_k(const uint4* __restrict__ hf16,
                                                    const int* __restrict__ rp,
                                                    const unsigned short* __restrict__ col,
                                                    const float* __restrict__ es, const float* __restrict__ ed,
                                                    const float* __restrict__ bias, float* __restrict__ out, int n) {
  int i = blockIdx.x * 4 + (threadIdx.x >> 6);
  if (i >= n) return;
  int lane = threadIdx.x & 63;
  int g = lane >> 4, sub = lane & 15;
  int hh = sub >> 2;
  int e0 = __builtin_amdgcn_readfirstlane(rp[i]);
  int e1 = __builtin_amdgcn_readfirstlane(rp[i + 1]);
  float edi = ed[i * 4 + hh];
  float acc[8] = {0.f, 0.f, 0.f, 0.f, 0.f, 0.f, 0.f, 0.f};
  float s = 0.f;
  if (g == 0) {
    float esf = es[i * 4 + hh] + edi;
    esf = esf >= 0.f ? esf : 0.2f * esf;
    float wself = __expf(fminf(esf, 80.f));
    uint4 v = hf16[(size_t)i * 16 + sub];
    accum8(acc, v, wself);
    s = wself;
  }
  int e = e0;
  for (; e + 15 < e1; e += 16) {
    int s0 = col[e + g];
    int s1 = col[e + 4 + g];
    int s2 = col[e + 8 + g];
    int s3 = col[e + 12 + g];
    float t0 = es[s0 * 4 + hh] + edi;
    float t1 = es[s1 * 4 + hh] + edi;
    float t2 = es[s2 * 4 + hh] + edi;
    float t3 = es[s3 * 4 + hh] + edi;
    t0 = t0 >= 0.f ? t0 : 0.2f * t0;
    t1 = t1 >= 0.f ? t1 : 0.2f * t1;
    t2 = t2 >= 0.f ? t2 : 0.2f * t2;
    t3 = t3 >= 0.f ? t3 : 0.2f * t3;
    float w0 = __expf(fminf(t0, 80.f));
    float w1 = __expf(fminf(t1, 80.f));
    float w2 = __expf(fminf(t2, 80.f));
    float w3 = __expf(fminf(t3, 80.f));
    uint4 v0 = hf16[(size_t)s0 * 16 + sub];
    uint4 v1 = hf16[(size_t)s1 * 16 + sub];
    uint4 v2 = hf16[(size_t)s2 * 16 + sub];
    uint4 v3 = hf16[(size_t)s3 * 16 + sub];
    accum8(acc, v0, w0); accum8(acc, v1, w1); accum8(acc, v2, w2); accum8(acc, v3, w3);
    s += w0 + w1 + w2 + w3;
  }
  for (; e < e1; e += 4) {
    bool ok = (e + g) < e1;
    int s0 = ok ? (int)col[e + g] : i;
    float t0 = es[s0 * 4 + hh] + edi;
    t0 = t0 >= 0.f ? t0 : 0.2f * t0;
    float w0 = ok ? __expf(fminf(t0, 80.f)) : 0.f;
    uint4 v0 = hf16[(size_t)s0 * 16 + sub];
    accum8(acc, v0, w0);
    s += w0;
  }
#pragma unroll
  for (int k = 0; k < 8; ++k) {
    acc[k] += __shfl_xor(acc[k], 16, 64);
    acc[k] += __shfl_xor(acc[k], 32, 64);
  }
  s += __shfl_xor(s, 16, 64);
  s += __shfl_xor(s, 32, 64);
  if (g == 0) {
    float wi = 1.0f / s;
    float4 b0 = ((const float4*)bias)[sub * 2], b1 = ((const float4*)bias)[sub * 2 + 1];
    *(float4*)&out[(size_t)i * 128 + sub * 8] =
        make_float4(acc[0] * wi + b0.x, acc[1] * wi + b0.y, acc[2] * wi + b0.z, acc[3] * wi + b0.w);
    *(float4*)&out[(size_t)i * 128 + sub * 8 + 4] =
        make_float4(acc[4] * wi + b1.x, acc[5] * wi + b1.y, acc[6] * wi + b1.z, acc[7] * wi + b1.w);
  }
}

// ======================= GraphNorm =======================
__global__ __launch_bounds__(256) void gn_stats_k(const float* __restrict__ h, const int* __restrict__ gstart,
                                                  const int* __restrict__ gcnt, float* __restrict__ gsum,
                                                  float* __restrict__ gsq) {
  int g = blockIdx.x / SLICES, sl = blockIdx.x % SLICES;
  int st = gstart[g], cn = gcnt[g];
  int d = threadIdx.x & 127, half = threadIdx.x >> 7;
  float s = 0.f, ss = 0.f;
  for (int r = sl * 2 + half; r < cn; r += 2 * SLICES) {
    float v = h[(size_t)(st + r) * D + d];
    s += v; ss += v * v;
  }
  __shared__ float l1[128], l2[128];
  if (half) { l1[d] = s; l2[d] = ss; }
  __syncthreads();
  if (!half) {
    atomicAdd(&gsum[g * D + d], s + l1[d]);
    atomicAdd(&gsq[g * D + d], ss + l2[d]);
  }
}

__global__ void gn_finalize_k(const float* __restrict__ gsum, const float* __restrict__ gsq,
                              const int* __restrict__ gcnt, const float* __restrict__ ms,
                              float* __restrict__ mean, float* __restrict__ rstd) {
  int g = blockIdx.x, d = threadIdx.x;
  float cnt = fmaxf((float)gcnt[g], 1.0f);
  float mu = gsum[g * D + d] / cnt;
  float m2 = gsq[g * D + d] / cnt;
  float s = ms[d];
  float var = m2 - (2.0f * s - s * s) * mu * mu;
  mean[g * D + d] = mu;
  rstd[g * D + d] = rsqrtf(fmaxf(var, 0.0f) + 1e-5f);
}

__global__ void gn_apply_k(const float* __restrict__ h, float* __restrict__ x,
                           unsigned short* __restrict__ xb,
                           const int* __restrict__ batch, const float* __restrict__ mean,
                           const float* __restrict__ rstd, const float* __restrict__ w,
                           const float* __restrict__ b, const float* __restrict__ ms, int n) {
  int idx = blockIdx.x * blockDim.x + threadIdx.x;
  if (idx >= n * 32) return;
  int node = idx >> 5, q = idx & 31;
  int g = batch[node];
  int d0 = q * 4;
  float4 hv = ((const float4*)h)[idx];
  float4 xv = ((const float4*)x)[idx];
  float ha[4] = {hv.x, hv.y, hv.z, hv.w};
  float xa[4] = {xv.x, xv.y, xv.z, xv.w};
  float ra[4];
#pragma unroll
  for (int j = 0; j < 4; ++j) {
    int d = d0 + j;
    float sub = ha[j] - ms[d] * mean[g * D + d];
    float v = w[d] * sub * rstd[g * D + d] + b[d];
    ra[j] = fmaxf(v, 0.f) + xa[j];
  }
  ((float4*)x)[idx] = make_float4(ra[0], ra[1], ra[2], ra[3]);
  ushort4 o;
  o.x = bf16u(ra[0]); o.y = bf16u(ra[1]); o.z = bf16u(ra[2]); o.w = bf16u(ra[3]);
  ((ushort4*)xb)[idx] = o;
}

// ======================= Hub scores (MFMA) =======================
__global__ __launch_bounds__(256) void hub_mfma_k(const unsigned short* __restrict__ Xb,
                                                  const unsigned short* __restrict__ W1p,
                                                  const float* __restrict__ nb1, const float* __restrict__ nw2,
                                                  const float* __restrict__ nb2, float* __restrict__ out, int n) {
  __shared__ unsigned short Bs[8192];
  int t = threadIdx.x;
  for (int i = t; i < 1024; i += 256) ((uint4*)Bs)[i] = ((const uint4*)W1p)[i];
  __syncthreads();
  int w = t >> 6, lane = t & 63;
  int row0 = blockIdx.x * 64 + w * 16;
  int arow = row0 + (lane & 15);
  f32x4 acc[4];
#pragma unroll
  for (int c = 0; c < 4; ++c) acc[c] = {0.f, 0.f, 0.f, 0.f};
#pragma unroll
  for (int kc = 0; kc < 4; ++kc) {
    bf16x8 a = {0, 0, 0, 0, 0, 0, 0, 0};
    if (arow < n) a = *(const bf16x8*)&Xb[(size_t)arow * 128 + kc * 32 + (lane >> 4) * 8];
#pragma unroll
    for (int c = 0; c < 4; ++c) {
      bf16x8 b = *(const bf16x8*)&Bs[((c * 4 + kc) * 64 + lane) * 8];
      acc[c] = __builtin_amdgcn_mfma_f32_16x16x32_bf16(a, b, acc[c], 0, 0, 0);
    }
  }
  float b2 = nb2[0];
  float s[4] = {0.f, 0.f, 0.f, 0.f};
#pragma unroll
  for (int c = 0; c < 4; ++c) {
    int colq = c * 16 + (lane & 15);
    float b1 = nb1[colq];
    float w2 = nw2[colq];
#pragma unroll
    for (int r = 0; r < 4; ++r) s[r] += fmaxf(acc[c][r] + b1, 0.f) * w2;
  }
#pragma unroll
  for (int off = 1; off < 16; off <<= 1) {
#pragma unroll
    for (int r = 0; r < 4; ++r) s[r] += __shfl_xor(s[r], off, 64);
  }
  if ((lane & 15) == 0) {
    int rbase = row0 + (lane >> 4) * 4;
#pragma unroll
    for (int r = 0; r < 4; ++r) {
      int row = rbase + r;
      if (row < n) out[row] = 1.0f / (1.0f + __expf(-(s[r] + b2)));
    }
  }
}

// ======================= Pooling =======================
__global__ void init_maxu_k(unsigned* __restrict__ p, int n) {
  int i = blockIdx.x * blockDim.x + threadIdx.x;
  if (i < n) p[i] = 0x007FFFFFu;
}

__global__ __launch_bounds__(256) void pool_stats_k(const float* __restrict__ x, const int* __restrict__ gstart,
                                                    const int* __restrict__ gcnt, float* __restrict__ gsum,
                                                    unsigned* __restrict__ gmaxu) {
  int g = blockIdx.x / SLICES, sl = blockIdx.x % SLICES;
  int st = gstart[g], cn = gcnt[g];
  int d = threadIdx.x & 127, half = threadIdx.x >> 7;
  float s = 0.f, mx = __uint_as_float(0xFF800000u);
  for (int r = sl * 2 + half; r < cn; r += 2 * SLICES) {
    float v = x[(size_t)(st + r) * D + d];
    s += v; mx = fmaxf(mx, v);
  }
  __shared__ float l1[128], l2[128];
  if (half) { l1[d] = s; l2[d] = mx; }
  __syncthreads();
  if (!half) {
    s += l1[d];
    mx = fmaxf(mx, l2[d]);
    atomicAdd(&gsum[g * D + d], s);
    unsigned u = __float_as_uint(mx);
    u = (u & 0x80000000u) ? ~u : (u | 0x80000000u);
    atomicMax(&gmaxu[g * D + d], u);
  }
}

__global__ void pool_fin_k(const float* __restrict__ gsum, const unsigned* __restrict__ gmaxu,
                           const int* __restrict__ gcnt, float* __restrict__ gf) {
  int g = blockIdx.x, d = threadIdx.x;
  float cnt = fmaxf((float)gcnt[g], 1.0f);
  gf[g * 256 + d] = gsum[g * D + d] / cnt;
  unsigned u = gmaxu[g * D + d];
  unsigned bits = (u & 0x80000000u) ? (u ^ 0x80000000u) : ~u;
  gf[g * 256 + 128 + d] = __uint_as_float(bits);
}

// ======================= Graph MLP =======================
__global__ __launch_bounds__(128) void mlp_k(const float* __restrict__ gf, const float* __restrict__ hw1,
                                             const float* __restrict__ hb1, const float* __restrict__ hw2,
                                             const float* __restrict__ hb2, const float* __restrict__ hw3,
                                             const float* __restrict__ hb3, float* __restrict__ logits) {
  __shared__ float sg[256], z1[128], z2[64];
  int g = blockIdx.x, t = threadIdx.x;
  sg[t] = gf[g * 256 + t];
  sg[t + 128] = gf[g * 256 + 128 + t];
  __syncthreads();
  float a = hb1[t];
  for (int k = 0; k < 256; ++k) a += sg[k] * hw1[k * 128 + t];
  z1[t] = fmaxf(a, 0.f);
  __syncthreads();
  if (t < 64) {
    float a2 = hb2[t];
    for (int k = 0; k < 128; ++k) a2 += z1[k] * hw2[k * 64 + t];
    z2[t] = fmaxf(a2, 0.f);
  }
  __syncthreads();
  if (t < 2) {
    float a3 = hb3[t];
    for (int k = 0; k < 64; ++k) a3 += z2[k] * hw3[k * 2 + t];
    logits[g * 2 + t] = a3;
  }
}

// ======================= Host =======================
extern "C" void kernel_launch(void* const* d_in, const int* in_sizes, int n_in,
                              void* d_out, int out_size, void* d_ws, size_t ws_size,
                              hipStream_t stream) {
  const float* x_in  = (const float*)d_in[0];
  const int*   eidx  = (const int*)d_in[1];
  const int*   batch = (const int*)d_in[2];
  const float* Wp  = (const float*)d_in[3];
  const float* bp  = (const float*)d_in[4];
  const float* Wg  = (const float*)d_in[5];
  const float* bg  = (const float*)d_in[6];
  const float* Wa1 = (const float*)d_in[7];
  const float* as1 = (const float*)d_in[8];
  const float* ad1 = (const float*)d_in[9];
  const float* ba1 = (const float*)d_in[10];
  const float* Wa2 = (const float*)d_in[11];
  const float* as2 = (const float*)d_in[12];
  const float* ad2 = (const float*)d_in[13];
  const float* ba2 = (const float*)d_in[14];
  const float* gnw[3] = {(const float*)d_in[15], (const float*)d_in[18], (const float*)d_in[21]};
  const float* gnb[3] = {(const float*)d_in[16], (const float*)d_in[19], (const float*)d_in[22]};
  const float* gns[3] = {(const float*)d_in[17], (const float*)d_in[20], (const float*)d_in[23]};
  const float* hw1 = (const float*)d_in[24];
  const float* hb1 = (const float*)d_in[25];
  const float* hw2 = (const float*)d_in[26];
  const float* hb2 = (const float*)d_in[27];
  const float* hw3 = (const float*)d_in[28];
  const float* hb3 = (const float*)d_in[29];
  const float* nw1 = (const float*)d_in[30];
  const float* nb1 = (const float*)d_in[31];
  const float* nw2 = (const float*)d_in[32];
  const float* nb2 = (const float*)d_in[33];

  const int N = in_sizes[0] / D;
  const int E = in_sizes[1] / 2;
  const int* src = eidx;
  const int* dst = eidx + E;

  float* out    = (float*)d_out;
  float* logits = out;
  float* hub    = out + GG * 2;
  float* gf     = out + GG * 2 + N;
  float* X      = out + GG * 2 + N + GG * 256;

  char* wp = (char*)d_ws;
  auto alloc = [&](size_t bytes) { char* p = wp; wp += (bytes + 255) & ~(size_t)255; return p; };
  float*    B2    = (float*)alloc((size_t)N * D * 4);
  unsigned* B1h   = (unsigned*)alloc((size_t)N * (D / 2) * 4);
  unsigned short* Xb = (unsigned short*)alloc((size_t)N * D * 2);
  unsigned short* col = (unsigned short*)alloc((size_t)E * 2);
  int*   cnt     = (int*)alloc((size_t)N * 4);
  int*   rowp    = (int*)alloc((size_t)(N + 1) * 4);
  int*   cur     = (int*)alloc((size_t)N * 4);
  float* dinv    = (float*)alloc((size_t)N * 4);
  float* es      = (float*)alloc((size_t)N * 4 * 4);
  float* ed      = (float*)alloc((size_t)N * 4 * 4);
  float* gsum    = (float*)alloc((size_t)GG * D * 4);
  float* gsq     = (float*)alloc((size_t)GG * D * 4);
  unsigned* gmaxu = (unsigned*)alloc((size_t)GG * D * 4);
  float* mean    = (float*)alloc((size_t)GG * D * 4);
  float* rstd    = (float*)alloc((size_t)GG * D * 4);
  int*   gcnt    = (int*)alloc((size_t)GG * 4);
  int*   gstart  = (int*)alloc((size_t)GG * 4);
  int*   gend    = (int*)alloc((size_t)GG * 4);
  int*   bsum    = (int*)alloc((size_t)256 * 4);
  unsigned short* Wpp  = (unsigned short*)alloc(16384 * 2);
  unsigned short* Wgp  = (unsigned short*)alloc(16384 * 2);
  unsigned short* Wa1p = (unsigned short*)alloc(16384 * 2);
  unsigned short* Wa2p = (unsigned short*)alloc(16384 * 2);
  unsigned short* W1p  = (unsigned short*)alloc(8192 * 2);
  unsigned short* xinb = (unsigned short*)B2;  // alias: consumed before B2 first written
  if ((size_t)(wp - (char*)d_ws) > ws_size) return;

  const int nb = (N + 255) / 256;

  // ---- CSR + graph ranges ----
  hipMemsetAsync(cnt, 0, (size_t)N * 4, stream);
  count_edges_k<<<(E + 255) / 256, 256, 0, stream>>>(dst, cnt, E);
  bounds_init_k<<<1, GG, 0, stream>>>(gstart, gend);
  graph_bounds_k<<<nb, 256, 0, stream>>>(batch, gstart, gend, N);
  gcnt_k<<<1, GG, 0, stream>>>(gstart, gend, gcnt);
  scan1_k<<<nb, 256, 0, stream>>>(cnt, rowp, bsum, N);
  scan2_k<<<1, 256, 0, stream>>>(bsum, nb);
  scan3_k<<<nb, 256, 0, stream>>>(rowp, bsum, cur, cnt, dinv, N, E);
  {
    int chunks = (E + 255) / 256;
    int slice = (N + NXCD - 1) / NXCD;
    fill_csr_xcd_k<<<chunks * NXCD, 256, 0, stream>>>(src, dst, cur, col, E, slice);
  }

  // ---- weight packs + input cast ----
  packB_k<<<8, 256, 0, stream>>>(Wp, Wpp, 128, 8);
  packB_k<<<8, 256, 0, stream>>>(Wg, Wgp, 128, 8);
  packB_k<<<8, 256, 0, stream>>>(Wa1, Wa1p, 128, 8);
  packB_k<<<8, 256, 0, stream>>>(Wa2, Wa2p, 128, 8);
  packB_k<<<4, 256, 0, stream>>>(nw1, W1p, 64, 4);
  cast_bf16_k<<<(N * 32 + 255) / 256, 256, 0, stream>>>(x_in, xinb, N * 32);

  const int gemmGrid = (N + 63) / 64;
  const int aggGrid  = (N + 3) / 4;

  auto graphnorm = [&](int layer) {
    hipMemsetAsync(gsum, 0, 2 * (size_t)GG * D * 4, stream);
    gn_stats_k<<<GG * SLICES, 256, 0, stream>>>(B2, gstart, gcnt, gsum, gsq);
    gn_finalize_k<<<GG, D, 0, stream>>>(gsum, gsq, gcnt, gns[layer], mean, rstd);
    gn_apply_k<<<(N * 32 + 255) / 256, 256, 0, stream>>>(B2, X, Xb, batch, mean, rstd,
                                                         gnw[layer], gnb[layer], gns[layer], N);
  };

  // ---- projection: X = x@Wp + bp (f32 + bf16) ----
  gemm_mfma_k<<<gemmGrid, 256, 0, stream>>>(xinb, Wpp, bp, X, Xb,
                                            nullptr, nullptr, nullptr, nullptr, nullptr, N);

  // ---- GCN layer: bf16 out pre-scaled by dinv[row] ----
  gemm_mfma_k<<<gemmGrid, 256, 0, stream>>>(Xb, Wgp, nullptr, nullptr, (unsigned short*)B1h,
                                            dinv, nullptr, nullptr, nullptr, nullptr, N);
  gcn_gather_k<<<aggGrid, 256, 0, stream>>>((const uint4*)B1h, rowp, col, dinv, bg, B2, N);
  graphnorm(0);

  // ---- GAT layer 1: es/ed fused into GEMM epilogue ----
  gemm_mfma_k<<<gemmGrid, 256, 0, stream>>>(Xb, Wa1p, nullptr, nullptr, (unsigned short*)B1h,
                                            nullptr, as1, ad1, es, ed, N);
  gat_gather_k<<<aggGrid, 256, 0, stream>>>((const uint4*)B1h, rowp, col, es, ed, ba1, B2, N);
  graphnorm(1);

  // ---- GAT layer 2 ----
  gemm_mfma_k<<<gemmGrid, 256, 0, stream>>>(Xb, Wa2p, nullptr, nullptr, (unsigned short*)B1h,
                                            nullptr, as2, ad2, es, ed, N);
  gat_gather_k<<<aggGrid, 256, 0, stream>>>((const uint4*)B1h, rowp, col, es, ed, ba2, B2, N);
  graphnorm(2);

  // ---- hub scores (MFMA) ----
  hub_mfma_k<<<gemmGrid, 256, 0, stream>>>(Xb, W1p, nb1, nw2, nb2, hub, N);

  // ---- pooling + graph MLP ----
  hipMemsetAsync(gsum, 0, (size_t)GG * D * 4, stream);
  init_maxu_k<<<(GG * D + 255) / 256, 256, 0, stream>>>(gmaxu, GG * D);
  pool_stats_k<<<GG * SLICES, 256, 0, stream>>>(X, gstart, gcnt, gsum, gmaxu);
  pool_fin_k<<<GG, D, 0, stream>>>(gsum, gmaxu, gcnt, gf);
  mlp_k<<<GG, 128, 0, stream>>>(gf, hw1, hb1, hw2, hb2, hw3, hb3, logits);
}

// Round 9
// 404.606 us; speedup vs baseline: 1.1649x; 1.0245x over previous
//
#include <hip/hip_runtime.h>
#include <cstdint>

#define D 128
#define GG 64
#define SLICES 16
#define NXCD 8

typedef short bf16x8 __attribute__((ext_vector_type(8)));
typedef float f32x4 __attribute__((ext_vector_type(4)));

// ---------- bf16 helpers ----------
__device__ inline unsigned short bf16u(float f) {
  unsigned u = __float_as_uint(f);
  u = (u + 0x7FFFu + ((u >> 16) & 1u)) >> 16;
  return (unsigned short)u;
}
__device__ inline unsigned packbf2(float a, float b) {
  return (unsigned)bf16u(a) | ((unsigned)bf16u(b) << 16);
}
__device__ inline float bfu(unsigned short u) { return __uint_as_float((unsigned)u << 16); }
__device__ inline float2 unpackbf2(unsigned u) {
  return make_float2(__uint_as_float(u << 16), __uint_as_float(u & 0xFFFF0000u));
}
__device__ inline void accum8(float* acc, uint4 v, float w) {
  float2 p0 = unpackbf2(v.x), p1 = unpackbf2(v.y), p2 = unpackbf2(v.z), p3 = unpackbf2(v.w);
  acc[0] += p0.x * w; acc[1] += p0.y * w; acc[2] += p1.x * w; acc[3] += p1.y * w;
  acc[4] += p2.x * w; acc[5] += p2.y * w; acc[6] += p3.x * w; acc[7] += p3.y * w;
}

// ======================= CSR build =======================
__global__ void count_edges_k(const int* __restrict__ dst, int* __restrict__ cnt, int E) {
  int e = blockIdx.x * blockDim.x + threadIdx.x;
  if (e < E) atomicAdd(&cnt[dst[e]], 1);
}

__global__ void bounds_init_k(int* __restrict__ gstart, int* __restrict__ gend) {
  int g = threadIdx.x;
  gstart[g] = 0;
  gend[g] = 0;
}

__global__ void graph_bounds_k(const int* __restrict__ batch, int* __restrict__ gstart,
                               int* __restrict__ gend, int n) {
  int i = blockIdx.x * blockDim.x + threadIdx.x;
  if (i >= n) return;
  int b = batch[i];
  if (i == 0) {
    gstart[b] = 0;
  } else {
    int pb = batch[i - 1];
    if (pb != b) { gstart[b] = i; gend[pb] = i; }
  }
  if (i == n - 1) gend[b] = n;
}

__global__ void gcnt_k(const int* __restrict__ gstart, const int* __restrict__ gend,
                       int* __restrict__ gcnt) {
  int g = threadIdx.x;
  gcnt[g] = gend[g] - gstart[g];
}

__global__ __launch_bounds__(256) void scan1_k(const int* __restrict__ cnt, int* __restrict__ rp,
                                               int* __restrict__ bsum, int n) {
  __shared__ int sd[256];
  int t = threadIdx.x;
  int i = blockIdx.x * 256 + t;
  int v = (i < n) ? cnt[i] : 0;
  sd[t] = v;
  __syncthreads();
#pragma unroll
  for (int off = 1; off < 256; off <<= 1) {
    int u = (t >= off) ? sd[t - off] : 0;
    __syncthreads();
    sd[t] += u;
    __syncthreads();
  }
  if (i < n) rp[i] = sd[t] - v;
  if (t == 255) bsum[blockIdx.x] = sd[255];
}

__global__ __launch_bounds__(256) void scan2_k(int* __restrict__ bsum, int nb) {
  __shared__ int sd[256];
  int t = threadIdx.x;
  int v = (t < nb) ? bsum[t] : 0;
  sd[t] = v;
  __syncthreads();
#pragma unroll
  for (int off = 1; off < 256; off <<= 1) {
    int u = (t >= off) ? sd[t - off] : 0;
    __syncthreads();
    sd[t] += u;
    __syncthreads();
  }
  if (t < nb) bsum[t] = sd[t] - v;
}

__global__ __launch_bounds__(256) void scan3_k(int* __restrict__ rp, const int* __restrict__ bsum,
                                               int* __restrict__ cur, const int* __restrict__ cnt,
                                               float* __restrict__ dinv, int n, int E) {
  int i = blockIdx.x * 256 + threadIdx.x;
  if (i < n) {
    int r = rp[i] + bsum[blockIdx.x];
    rp[i] = r;
    cur[i] = r;
    dinv[i] = rsqrtf((float)cnt[i] + 1.0f);
  }
  if (i == 0) rp[n] = E;
}

__global__ __launch_bounds__(256) void fill_csr_xcd_k(const int* __restrict__ src,
                                                      const int* __restrict__ dst,
                                                      int* __restrict__ cur,
                                                      unsigned short* __restrict__ col,
                                                      int E, int slice) {
  int pass = blockIdx.x & (NXCD - 1);
  int e = (blockIdx.x >> 3) * 256 + threadIdx.x;
  if (e >= E) return;
  int d = dst[e];
  if ((unsigned)(d - pass * slice) < (unsigned)slice) {
    int p = atomicAdd(&cur[d], 1);
    col[p] = (unsigned short)src[e];
  }
}

// ======================= bf16 cast =======================
__global__ void cast_bf16_k(const float* __restrict__ in, unsigned short* __restrict__ outp, int n4) {
  int i = blockIdx.x * blockDim.x + threadIdx.x;
  if (i >= n4) return;
  float4 v = ((const float4*)in)[i];
  ushort4 o;
  o.x = bf16u(v.x); o.y = bf16u(v.y); o.z = bf16u(v.z); o.w = bf16u(v.w);
  ((ushort4*)outp)[i] = o;
}

// ======================= Weight pack into MFMA B-fragment order =======================
__global__ void packB_k(const float* __restrict__ B, unsigned short* __restrict__ Bp, int ldb, int ct) {
  int idx = blockIdx.x * 256 + threadIdx.x;
  if (idx >= ct * 256) return;
  int lane = idx & 63;
  int kc = (idx >> 6) & 3;
  int c = idx >> 8;
  int kb = kc * 32 + (lane >> 4) * 8;
  int colq = c * 16 + (lane & 15);
  unsigned short o[8];
#pragma unroll
  for (int j = 0; j < 8; ++j) o[j] = bf16u(B[(size_t)(kb + j) * ldb + colq]);
  uint4 p;
  p.x = (unsigned)o[0] | ((unsigned)o[1] << 16);
  p.y = (unsigned)o[2] | ((unsigned)o[3] << 16);
  p.z = (unsigned)o[4] | ((unsigned)o[5] << 16);
  p.w = (unsigned)o[6] | ((unsigned)o[7] << 16);
  *(uint4*)&Bp[(size_t)idx * 8] = p;
}

// ======================= MFMA GEMM: [M,128]x[128,128] + fused extras ==================
__global__ __launch_bounds__(256) void gemm_mfma_k(const unsigned short* __restrict__ Ab,
                                                   const unsigned short* __restrict__ Bp,
                                                   const float* __restrict__ bias,
                                                   float* __restrict__ Cf,
                                                   unsigned short* __restrict__ Cb,
                                                   const float* __restrict__ rowscale,
                                                   const float* __restrict__ as_flat,
                                                   const float* __restrict__ ad_flat,
                                                   float* __restrict__ es, float* __restrict__ ed,
                                                   int M) {
  __shared__ unsigned short Bs[16384];
  int t = threadIdx.x;
  for (int i = t; i < 2048; i += 256) ((uint4*)Bs)[i] = ((const uint4*)Bp)[i];
  __syncthreads();
  int w = t >> 6, lane = t & 63;
  int row0 = blockIdx.x * 64 + w * 16;
  int arow = row0 + (lane & 15);
  f32x4 acc[8];
#pragma unroll
  for (int c = 0; c < 8; ++c) acc[c] = {0.f, 0.f, 0.f, 0.f};
#pragma unroll
  for (int kc = 0; kc < 4; ++kc) {
    bf16x8 a = {0, 0, 0, 0, 0, 0, 0, 0};
    if (arow < M) a = *(const bf16x8*)&Ab[(size_t)arow * 128 + kc * 32 + (lane >> 4) * 8];
#pragma unroll
    for (int c = 0; c < 8; ++c) {
      bf16x8 b = *(const bf16x8*)&Bs[((c * 4 + kc) * 64 + lane) * 8];
      acc[c] = __builtin_amdgcn_mfma_f32_16x16x32_bf16(a, b, acc[c], 0, 0, 0);
    }
  }
  int l15 = lane & 15;
  int rbase = row0 + (lane >> 4) * 4;
#pragma unroll
  for (int c = 0; c < 8; ++c) {
    int colq = c * 16 + l15;
    float bb = bias ? bias[colq] : 0.f;
#pragma unroll
    for (int r = 0; r < 4; ++r) {
      int row = rbase + r;
      if (row < M) {
        float v = acc[c][r] + bb;
        if (Cf) Cf[(size_t)row * 128 + colq] = v;
        if (Cb) {
          float rs = rowscale ? rowscale[row] : 1.f;
          Cb[(size_t)row * 128 + colq] = bf16u(v * rs);
        }
      }
    }
  }
  if (as_flat) {
    float pe[4][4], pd[4][4];
#pragma unroll
    for (int h = 0; h < 4; ++h) {
      float a0 = as_flat[h * 32 + l15], a1 = as_flat[h * 32 + 16 + l15];
      float d0 = ad_flat[h * 32 + l15], d1 = ad_flat[h * 32 + 16 + l15];
#pragma unroll
      for (int r = 0; r < 4; ++r) {
        pe[h][r] = acc[2 * h][r] * a0 + acc[2 * h + 1][r] * a1;
        pd[h][r] = acc[2 * h][r] * d0 + acc[2 * h + 1][r] * d1;
      }
    }
#pragma unroll
    for (int off = 1; off < 16; off <<= 1) {
#pragma unroll
      for (int h = 0; h < 4; ++h)
#pragma unroll
        for (int r = 0; r < 4; ++r) {
          pe[h][r] += __shfl_xor(pe[h][r], off, 64);
          pd[h][r] += __shfl_xor(pd[h][r], off, 64);
        }
    }
    int hh = l15 & 3, rr = l15 >> 2;
    int row = rbase + rr;
    if (row < M) {
      es[row * 4 + hh] = pe[hh][rr];
      ed[row * 4 + hh] = pd[hh][rr];
    }
  }
}

// ======================= GCN aggregation (predicated 16-edge loop, bf16 out) ============
__global__ __launch_bounds__(256) void gcn_gather_k(const uint4* __restrict__ xw16,
                                                    const int* __restrict__ rp,
                                                    const unsigned short* __restrict__ col,
                                                    const float* __restrict__ dinv, const float* __restrict__ bias,
                                                    unsigned short* __restrict__ outb, int n) {
  int i = blockIdx.x * 4 + (threadIdx.x >> 6);
  if (i >= n) return;
  int lane = threadIdx.x & 63;
  int g = lane >> 4, sub = lane & 15;
  int e0 = __builtin_amdgcn_readfirstlane(rp[i]);
  int e1 = __builtin_amdgcn_readfirstlane(rp[i + 1]);
  float acc[8] = {0.f, 0.f, 0.f, 0.f, 0.f, 0.f, 0.f, 0.f};
  if (g == 0) {
    uint4 v = xw16[(size_t)i * 16 + sub];   // row prescaled by dinv[i]
    accum8(acc, v, 1.f);
  }
  for (int e = e0; e < e1; e += 16) {
    int i0 = e + g, i1 = e + 4 + g, i2 = e + 8 + g, i3 = e + 12 + g;
    int s0 = i0 < e1 ? (int)col[i0] : i;
    int s1 = i1 < e1 ? (int)col[i1] : i;
    int s2 = i2 < e1 ? (int)col[i2] : i;
    int s3 = i3 < e1 ? (int)col[i3] : i;
    float w0 = i0 < e1 ? 1.f : 0.f;
    float w1 = i1 < e1 ? 1.f : 0.f;
    float w2 = i2 < e1 ? 1.f : 0.f;
    float w3 = i3 < e1 ? 1.f : 0.f;
    uint4 v0 = xw16[(size_t)s0 * 16 + sub];
    uint4 v1 = xw16[(size_t)s1 * 16 + sub];
    uint4 v2 = xw16[(size_t)s2 * 16 + sub];
    uint4 v3 = xw16[(size_t)s3 * 16 + sub];
    accum8(acc, v0, w0); accum8(acc, v1, w1); accum8(acc, v2, w2); accum8(acc, v3, w3);
  }
#pragma unroll
  for (int k = 0; k < 8; ++k) {
    acc[k] += __shfl_xor(acc[k], 16, 64);
    acc[k] += __shfl_xor(acc[k], 32, 64);
  }
  if (g == 0) {
    float di = dinv[i];
    float4 b0 = ((const float4*)bias)[sub * 2], b1 = ((const float4*)bias)[sub * 2 + 1];
    uint4 p;
    p.x = packbf2(acc[0] * di + b0.x, acc[1] * di + b0.y);
    p.y = packbf2(acc[2] * di + b0.z, acc[3] * di + b0.w);
    p.z = packbf2(acc[4] * di + b1.x, acc[5] * di + b1.y);
    p.w = packbf2(acc[6] * di + b1.z, acc[7] * di + b1.w);
    ((uint4*)outb)[(size_t)i * 16 + sub] = p;
  }
}

// ======================= GAT gather (predicated loop, exp dedup via shfl, bf16 out) =====
// lane (g,sub): gathers edges e+4j+g for head hh=sub>>2; computes exp for (edge e+sub, head g).
__global__ __launch_bounds__(256) void gat_gather_k(const uint4* __restrict__ hf16,
                                                    const int* __restrict__ rp,
                                                    const unsigned short* __restrict__ col,
                                                    const float* __restrict__ es, const float* __restrict__ ed,
                                                    const float* __restrict__ bias,
                                                    unsigned short* __restrict__ outb, int n) {
  int i = blockIdx.x * 4 + (threadIdx.x >> 6);
  if (i >= n) return;
  int lane = threadIdx.x & 63;
  int g = lane >> 4, sub = lane & 15;
  int hh = sub >> 2;
  int e0 = __builtin_amdgcn_readfirstlane(rp[i]);
  int e1 = __builtin_amdgcn_readfirstlane(rp[i + 1]);
  float edi_g = ed[i * 4 + g];   // head for this lane's exp duty
  float acc[8] = {0.f, 0.f, 0.f, 0.f, 0.f, 0.f, 0.f, 0.f};
  float s = 0.f;
  if (g == 0) {
    float esf = es[i * 4 + hh] + ed[i * 4 + hh];
    esf = esf >= 0.f ? esf : 0.2f * esf;
    float wself = __expf(fminf(esf, 80.f));
    uint4 v = hf16[(size_t)i * 16 + sub];
    accum8(acc, v, wself);
    s = wself;
  }
  for (int e = e0; e < e1; e += 16) {
    // exp duty: edge e+sub, head g (64 distinct (edge,head) pairs per wave)
    int el = e + sub;
    bool okl = el < e1;
    int sl = okl ? (int)col[el] : i;
    float tl = es[sl * 4 + g] + edi_g;
    tl = tl >= 0.f ? tl : 0.2f * tl;
    float wl = okl ? __expf(fminf(tl, 80.f)) : 0.f;
    int base = hh << 4;
    float w0 = __shfl(wl, base | g, 64);
    float w1 = __shfl(wl, base | (g + 4), 64);
    float w2 = __shfl(wl, base | (g + 8), 64);
    float w3 = __shfl(wl, base | (g + 12), 64);
    // gather duty
    int i0 = e + g, i1 = e + 4 + g, i2 = e + 8 + g, i3 = e + 12 + g;
    int s0 = i0 < e1 ? (int)col[i0] : i;
    int s1 = i1 < e1 ? (int)col[i1] : i;
    int s2 = i2 < e1 ? (int)col[i2] : i;
    int s3 = i3 < e1 ? (int)col[i3] : i;
    uint4 v0 = hf16[(size_t)s0 * 16 + sub];
    uint4 v1 = hf16[(size_t)s1 * 16 + sub];
    uint4 v2 = hf16[(size_t)s2 * 16 + sub];
    uint4 v3 = hf16[(size_t)s3 * 16 + sub];
    accum8(acc, v0, w0); accum8(acc, v1, w1); accum8(acc, v2, w2); accum8(acc, v3, w3);
    s += w0 + w1 + w2 + w3;
  }
#pragma unroll
  for (int k = 0; k < 8; ++k) {
    acc[k] += __shfl_xor(acc[k], 16, 64);
    acc[k] += __shfl_xor(acc[k], 32, 64);
  }
  s += __shfl_xor(s, 16, 64);
  s += __shfl_xor(s, 32, 64);
  if (g == 0) {
    float wi = 1.0f / s;
    float4 b0 = ((const float4*)bias)[sub * 2], b1 = ((const float4*)bias)[sub * 2 + 1];
    uint4 p;
    p.x = packbf2(acc[0] * wi + b0.x, acc[1] * wi + b0.y);
    p.y = packbf2(acc[2] * wi + b0.z, acc[3] * wi + b0.w);
    p.z = packbf2(acc[4] * wi + b1.x, acc[5] * wi + b1.y);
    p.w = packbf2(acc[6] * wi + b1.z, acc[7] * wi + b1.w);
    ((uint4*)outb)[(size_t)i * 16 + sub] = p;
  }
}

// ======================= GraphNorm (bf16 h) =======================
__global__ __launch_bounds__(256) void gn_stats_k(const unsigned short* __restrict__ h,
                                                  const int* __restrict__ gstart,
                                                  const int* __restrict__ gcnt, float* __restrict__ gsum,
                                                  float* __restrict__ gsq) {
  int g = blockIdx.x / SLICES, sl = blockIdx.x % SLICES;
  int st = gstart[g], cn = gcnt[g];
  int d = threadIdx.x & 127, half = threadIdx.x >> 7;
  float s = 0.f, ss = 0.f;
  for (int r = sl * 2 + half; r < cn; r += 2 * SLICES) {
    float v = bfu(h[(size_t)(st + r) * D + d]);
    s += v; ss += v * v;
  }
  __shared__ float l1[128], l2[128];
  if (half) { l1[d] = s; l2[d] = ss; }
  __syncthreads();
  if (!half) {
    atomicAdd(&gsum[g * D + d], s + l1[d]);
    atomicAdd(&gsq[g * D + d], ss + l2[d]);
  }
}

__global__ void gn_finalize_k(const float* __restrict__ gsum, const float* __restrict__ gsq,
                              const int* __restrict__ gcnt, const float* __restrict__ ms,
                              float* __restrict__ mean, float* __restrict__ rstd) {
  int g = blockIdx.x, d = threadIdx.x;
  float cnt = fmaxf((float)gcnt[g], 1.0f);
  float mu = gsum[g * D + d] / cnt;
  float m2 = gsq[g * D + d] / cnt;
  float s = ms[d];
  float var = m2 - (2.0f * s - s * s) * mu * mu;
  mean[g * D + d] = mu;
  rstd[g * D + d] = rsqrtf(fmaxf(var, 0.0f) + 1e-5f);
}

__global__ void gn_apply_k(const unsigned short* __restrict__ h, float* __restrict__ x,
                           unsigned short* __restrict__ xb,
                           const int* __restrict__ batch, const float* __restrict__ mean,
                           const float* __restrict__ rstd, const float* __restrict__ w,
                           const float* __restrict__ b, const float* __restrict__ ms, int n) {
  int idx = blockIdx.x * blockDim.x + threadIdx.x;
  if (idx >= n * 32) return;
  int node = idx >> 5, q = idx & 31;
  int g = batch[node];
  int d0 = q * 4;
  ushort4 hv = ((const ushort4*)h)[idx];
  float4 xv = ((const float4*)x)[idx];
  float ha[4] = {bfu(hv.x), bfu(hv.y), bfu(hv.z), bfu(hv.w)};
  float xa[4] = {xv.x, xv.y, xv.z, xv.w};
  float ra[4];
#pragma unroll
  for (int j = 0; j < 4; ++j) {
    int d = d0 + j;
    float sub = ha[j] - ms[d] * mean[g * D + d];
    float v = w[d] * sub * rstd[g * D + d] + b[d];
    ra[j] = fmaxf(v, 0.f) + xa[j];
  }
  ((float4*)x)[idx] = make_float4(ra[0], ra[1], ra[2], ra[3]);
  ushort4 o;
  o.x = bf16u(ra[0]); o.y = bf16u(ra[1]); o.z = bf16u(ra[2]); o.w = bf16u(ra[3]);
  ((ushort4*)xb)[idx] = o;
}

// ======================= Hub scores (MFMA) =======================
__global__ __launch_bounds__(256) void hub_mfma_k(const unsigned short* __restrict__ Xb,
                                                  const unsigned short* __restrict__ W1p,
                                                  const float* __restrict__ nb1, const float* __restrict__ nw2,
                                                  const float* __restrict__ nb2, float* __restrict__ out, int n) {
  __shared__ unsigned short Bs[8192];
  int t = threadIdx.x;
  for (int i = t; i < 1024; i += 256) ((uint4*)Bs)[i] = ((const uint4*)W1p)[i];
  __syncthreads();
  int w = t >> 6, lane = t & 63;
  int row0 = blockIdx.x * 64 + w * 16;
  int arow = row0 + (lane & 15);
  f32x4 acc[4];
#pragma unroll
  for (int c = 0; c < 4; ++c) acc[c] = {0.f, 0.f, 0.f, 0.f};
#pragma unroll
  for (int kc = 0; kc < 4; ++kc) {
    bf16x8 a = {0, 0, 0, 0, 0, 0, 0, 0};
    if (arow < n) a = *(const bf16x8*)&Xb[(size_t)arow * 128 + kc * 32 + (lane >> 4) * 8];
#pragma unroll
    for (int c = 0; c < 4; ++c) {
      bf16x8 b = *(const bf16x8*)&Bs[((c * 4 + kc) * 64 + lane) * 8];
      acc[c] = __builtin_amdgcn_mfma_f32_16x16x32_bf16(a, b, acc[c], 0, 0, 0);
    }
  }
  float b2 = nb2[0];
  float s[4] = {0.f, 0.f, 0.f, 0.f};
#pragma unroll
  for (int c = 0; c < 4; ++c) {
    int colq = c * 16 + (lane & 15);
    float b1 = nb1[colq];
    float w2 = nw2[colq];
#pragma unroll
    for (int r = 0; r < 4; ++r) s[r] += fmaxf(acc[c][r] + b1, 0.f) * w2;
  }
#pragma unroll
  for (int off = 1; off < 16; off <<= 1) {
#pragma unroll
    for (int r = 0; r < 4; ++r) s[r] += __shfl_xor(s[r], off, 64);
  }
  if ((lane & 15) == 0) {
    int rbase = row0 + (lane >> 4) * 4;
#pragma unroll
    for (int r = 0; r < 4; ++r) {
      int row = rbase + r;
      if (row < n) out[row] = 1.0f / (1.0f + __expf(-(s[r] + b2)));
    }
  }
}

// ======================= Pooling =======================
__global__ void init_maxu_k(unsigned* __restrict__ p, int n) {
  int i = blockIdx.x * blockDim.x + threadIdx.x;
  if (i < n) p[i] = 0x007FFFFFu;
}

__global__ __launch_bounds__(256) void pool_stats_k(const float* __restrict__ x, const int* __restrict__ gstart,
                                                    const int* __restrict__ gcnt, float* __restrict__ gsum,
                                                    unsigned* __restrict__ gmaxu) {
  int g = blockIdx.x / SLICES, sl = blockIdx.x % SLICES;
  int st = gstart[g], cn = gcnt[g];
  int d = threadIdx.x & 127, half = threadIdx.x >> 7;
  float s = 0.f, mx = __uint_as_float(0xFF800000u);
  for (int r = sl * 2 + half; r < cn; r += 2 * SLICES) {
    float v = x[(size_t)(st + r) * D + d];
    s += v; mx = fmaxf(mx, v);
  }
  __shared__ float l1[128], l2[128];
  if (half) { l1[d] = s; l2[d] = mx; }
  __syncthreads();
  if (!half) {
    s += l1[d];
    mx = fmaxf(mx, l2[d]);
    atomicAdd(&gsum[g * D + d], s);
    unsigned u = __float_as_uint(mx);
    u = (u & 0x80000000u) ? ~u : (u | 0x80000000u);
    atomicMax(&gmaxu[g * D + d], u);
  }
}

__global__ void pool_fin_k(const float* __restrict__ gsum, const unsigned* __restrict__ gmaxu,
                           const int* __restrict__ gcnt, float* __restrict__ gf) {
  int g = blockIdx.x, d = threadIdx.x;
  float cnt = fmaxf((float)gcnt[g], 1.0f);
  gf[g * 256 + d] = gsum[g * D + d] / cnt;
  unsigned u = gmaxu[g * D + d];
  unsigned bits = (u & 0x80000000u) ? (u ^ 0x80000000u) : ~u;
  gf[g * 256 + 128 + d] = __uint_as_float(bits);
}

// ======================= Graph MLP =======================
__global__ __launch_bounds__(128) void mlp_k(const float* __restrict__ gf, const float* __restrict__ hw1,
                                             const float* __restrict__ hb1, const float* __restrict__ hw2,
                                             const float* __restrict__ hb2, const float* __restrict__ hw3,
                                             const float* __restrict__ hb3, float* __restrict__ logits) {
  __shared__ float sg[256], z1[128], z2[64];
  int g = blockIdx.x, t = threadIdx.x;
  sg[t] = gf[g * 256 + t];
  sg[t + 128] = gf[g * 256 + 128 + t];
  __syncthreads();
  float a = hb1[t];
  for (int k = 0; k < 256; ++k) a += sg[k] * hw1[k * 128 + t];
  z1[t] = fmaxf(a, 0.f);
  __syncthreads();
  if (t < 64) {
    float a2 = hb2[t];
    for (int k = 0; k < 128; ++k) a2 += z1[k] * hw2[k * 64 + t];
    z2[t] = fmaxf(a2, 0.f);
  }
  __syncthreads();
  if (t < 2) {
    float a3 = hb3[t];
    for (int k = 0; k < 64; ++k) a3 += z2[k] * hw3[k * 2 + t];
    logits[g * 2 + t] = a3;
  }
}

// ======================= Host =======================
extern "C" void kernel_launch(void* const* d_in, const int* in_sizes, int n_in,
                              void* d_out, int out_size, void* d_ws, size_t ws_size,
                              hipStream_t stream) {
  const float* x_in  = (const float*)d_in[0];
  const int*   eidx  = (const int*)d_in[1];
  const int*   batch = (const int*)d_in[2];
  const float* Wp  = (const float*)d_in[3];
  const float* bp  = (const float*)d_in[4];
  const float* Wg  = (const float*)d_in[5];
  const float* bg  = (const float*)d_in[6];
  const float* Wa1 = (const float*)d_in[7];
  const float* as1 = (const float*)d_in[8];
  const float* ad1 = (const float*)d_in[9];
  const float* ba1 = (const float*)d_in[10];
  const float* Wa2 = (const float*)d_in[11];
  const float* as2 = (const float*)d_in[12];
  const float* ad2 = (const float*)d_in[13];
  const float* ba2 = (const float*)d_in[14];
  const float* gnw[3] = {(const float*)d_in[15], (const float*)d_in[18], (const float*)d_in[21]};
  const float* gnb[3] = {(const float*)d_in[16], (const float*)d_in[19], (const float*)d_in[22]};
  const float* gns[3] = {(const float*)d_in[17], (const float*)d_in[20], (const float*)d_in[23]};
  const float* hw1 = (const float*)d_in[24];
  const float* hb1 = (const float*)d_in[25];
  const float* hw2 = (const float*)d_in[26];
  const float* hb2 = (const float*)d_in[27];
  const float* hw3 = (const float*)d_in[28];
  const float* hb3 = (const float*)d_in[29];
  const float* nw1 = (const float*)d_in[30];
  const float* nb1 = (const float*)d_in[31];
  const float* nw2 = (const float*)d_in[32];
  const float* nb2 = (const float*)d_in[33];

  const int N = in_sizes[0] / D;
  const int E = in_sizes[1] / 2;
  const int* src = eidx;
  const int* dst = eidx + E;

  float* out    = (float*)d_out;
  float* logits = out;
  float* hub    = out + GG * 2;
  float* gf     = out + GG * 2 + N;
  float* X      = out + GG * 2 + N + GG * 256;

  char* wp = (char*)d_ws;
  auto alloc = [&](size_t bytes) { char* p = wp; wp += (bytes + 255) & ~(size_t)255; return p; };
  unsigned short* B2 = (unsigned short*)alloc((size_t)N * D * 2);   // bf16 agg output / xin alias
  unsigned* B1h   = (unsigned*)alloc((size_t)N * (D / 2) * 4);
  unsigned short* Xb = (unsigned short*)alloc((size_t)N * D * 2);
  unsigned short* col = (unsigned short*)alloc((size_t)E * 2);
  int*   cnt     = (int*)alloc((size_t)N * 4);
  int*   rowp    = (int*)alloc((size_t)(N + 1) * 4);
  int*   cur     = (int*)alloc((size_t)N * 4);
  float* dinv    = (float*)alloc((size_t)N * 4);
  float* es      = (float*)alloc((size_t)N * 4 * 4);
  float* ed      = (float*)alloc((size_t)N * 4 * 4);
  float* gsum    = (float*)alloc((size_t)GG * D * 4);
  float* gsq     = (float*)alloc((size_t)GG * D * 4);
  unsigned* gmaxu = (unsigned*)alloc((size_t)GG * D * 4);
  float* mean    = (float*)alloc((size_t)GG * D * 4);
  float* rstd    = (float*)alloc((size_t)GG * D * 4);
  int*   gcnt    = (int*)alloc((size_t)GG * 4);
  int*   gstart  = (int*)alloc((size_t)GG * 4);
  int*   gend    = (int*)alloc((size_t)GG * 4);
  int*   bsum    = (int*)alloc((size_t)256 * 4);
  unsigned short* Wpp  = (unsigned short*)alloc(16384 * 2);
  unsigned short* Wgp  = (unsigned short*)alloc(16384 * 2);
  unsigned short* Wa1p = (unsigned short*)alloc(16384 * 2);
  unsigned short* Wa2p = (unsigned short*)alloc(16384 * 2);
  unsigned short* W1p  = (unsigned short*)alloc(8192 * 2);
  unsigned short* xinb = B2;  // alias: consumed by projection GEMM before B2 first written
  if ((size_t)(wp - (char*)d_ws) > ws_size) return;

  const int nb = (N + 255) / 256;

  // ---- CSR + graph ranges ----
  hipMemsetAsync(cnt, 0, (size_t)N * 4, stream);
  count_edges_k<<<(E + 255) / 256, 256, 0, stream>>>(dst, cnt, E);
  bounds_init_k<<<1, GG, 0, stream>>>(gstart, gend);
  graph_bounds_k<<<nb, 256, 0, stream>>>(batch, gstart, gend, N);
  gcnt_k<<<1, GG, 0, stream>>>(gstart, gend, gcnt);
  scan1_k<<<nb, 256, 0, stream>>>(cnt, rowp, bsum, N);
  scan2_k<<<1, 256, 0, stream>>>(bsum, nb);
  scan3_k<<<nb, 256, 0, stream>>>(rowp, bsum, cur, cnt, dinv, N, E);
  {
    int chunks = (E + 255) / 256;
    int slice = (N + NXCD - 1) / NXCD;
    fill_csr_xcd_k<<<chunks * NXCD, 256, 0, stream>>>(src, dst, cur, col, E, slice);
  }

  // ---- weight packs + input cast ----
  packB_k<<<8, 256, 0, stream>>>(Wp, Wpp, 128, 8);
  packB_k<<<8, 256, 0, stream>>>(Wg, Wgp, 128, 8);
  packB_k<<<8, 256, 0, stream>>>(Wa1, Wa1p, 128, 8);
  packB_k<<<8, 256, 0, stream>>>(Wa2, Wa2p, 128, 8);
  packB_k<<<4, 256, 0, stream>>>(nw1, W1p, 64, 4);
  cast_bf16_k<<<(N * 32 + 255) / 256, 256, 0, stream>>>(x_in, xinb, N * 32);

  const int gemmGrid = (N + 63) / 64;
  const int aggGrid  = (N + 3) / 4;

  auto graphnorm = [&](int layer) {
    hipMemsetAsync(gsum, 0, 2 * (size_t)GG * D * 4, stream);
    gn_stats_k<<<GG * SLICES, 256, 0, stream>>>(B2, gstart, gcnt, gsum, gsq);
    gn_finalize_k<<<GG, D, 0, stream>>>(gsum, gsq, gcnt, gns[layer], mean, rstd);
    gn_apply_k<<<(N * 32 + 255) / 256, 256, 0, stream>>>(B2, X, Xb, batch, mean, rstd,
                                                         gnw[layer], gnb[layer], gns[layer], N);
  };

  // ---- projection: X = x@Wp + bp (f32 + bf16) ----
  gemm_mfma_k<<<gemmGrid, 256, 0, stream>>>(xinb, Wpp, bp, X, Xb,
                                            nullptr, nullptr, nullptr, nullptr, nullptr, N);

  // ---- GCN layer ----
  gemm_mfma_k<<<gemmGrid, 256, 0, stream>>>(Xb, Wgp, nullptr, nullptr, (unsigned short*)B1h,
                                            dinv, nullptr, nullptr, nullptr, nullptr, N);
  gcn_gather_k<<<aggGrid, 256, 0, stream>>>((const uint4*)B1h, rowp, col, dinv, bg, B2, N);
  graphnorm(0);

  // ---- GAT layer 1 ----
  gemm_mfma_k<<<gemmGrid, 256, 0, stream>>>(Xb, Wa1p, nullptr, nullptr, (unsigned short*)B1h,
                                            nullptr, as1, ad1, es, ed, N);
  gat_gather_k<<<aggGrid, 256, 0, stream>>>((const uint4*)B1h, rowp, col, es, ed, ba1, B2, N);
  graphnorm(1);

  // ---- GAT layer 2 ----
  gemm_mfma_k<<<gemmGrid, 256, 0, stream>>>(Xb, Wa2p, nullptr, nullptr, (unsigned short*)B1h,
                                            nullptr, as2, ad2, es, ed, N);
  gat_gather_k<<<aggGrid, 256, 0, stream>>>((const uint4*)B1h, rowp, col, es, ed, ba2, B2, N);
  graphnorm(2);

  // ---- hub scores (MFMA) ----
  hub_mfma_k<<<gemmGrid, 256, 0, stream>>>(Xb, W1p, nb1, nw2, nb2, hub, N);

  // ---- pooling + graph MLP ----
  hipMemsetAsync(gsum, 0, (size_t)GG * D * 4, stream);
  init_maxu_k<<<(GG * D + 255) / 256, 256, 0, stream>>>(gmaxu, GG * D);
  pool_stats_k<<<GG * SLICES, 256, 0, stream>>>(X, gstart, gcnt, gsum, gmaxu);
  pool_fin_k<<<GG, D, 0, stream>>>(gsum, gmaxu, gcnt, gf);
  mlp_k<<<GG, 128, 0, stream>>>(gf, hw1, hb1, hw2, hb2, hw3, hb3, logits);
}

// Round 10
// 393.295 us; speedup vs baseline: 1.1984x; 1.0288x over previous
//
#include <hip/hip_runtime.h>
#include <cstdint>

#define D 128
#define GG 64
#define SLICES 16
#define NXCD 8

typedef short bf16x8 __attribute__((ext_vector_type(8)));
typedef float f32x4 __attribute__((ext_vector_type(4)));

// ---------- bf16 helpers ----------
__device__ inline unsigned short bf16u(float f) {
  unsigned u = __float_as_uint(f);
  u = (u + 0x7FFFu + ((u >> 16) & 1u)) >> 16;
  return (unsigned short)u;
}
__device__ inline unsigned packbf2(float a, float b) {
  return (unsigned)bf16u(a) | ((unsigned)bf16u(b) << 16);
}
__device__ inline float bfu(unsigned short u) { return __uint_as_float((unsigned)u << 16); }
__device__ inline float2 unpackbf2(unsigned u) {
  return make_float2(__uint_as_float(u << 16), __uint_as_float(u & 0xFFFF0000u));
}
__device__ inline void accum8(float* acc, uint4 v, float w) {
  float2 p0 = unpackbf2(v.x), p1 = unpackbf2(v.y), p2 = unpackbf2(v.z), p3 = unpackbf2(v.w);
  acc[0] += p0.x * w; acc[1] += p0.y * w; acc[2] += p1.x * w; acc[3] += p1.y * w;
  acc[4] += p2.x * w; acc[5] += p2.y * w; acc[6] += p3.x * w; acc[7] += p3.y * w;
}

// ======================= CSR build =======================
// XCD-sliced count: pass = blockIdx&7; each cnt slice (25KB) stays in one XCD's L2.
__global__ __launch_bounds__(256) void count_edges_xcd_k(const int* __restrict__ dst,
                                                         int* __restrict__ cnt, int E, int slice) {
  int pass = blockIdx.x & (NXCD - 1);
  int e = (blockIdx.x >> 3) * 256 + threadIdx.x;
  if (e >= E) return;
  int d = dst[e];
  if ((unsigned)(d - pass * slice) < (unsigned)slice) atomicAdd(&cnt[d], 1);
}

__global__ void bounds_init_k(int* __restrict__ gstart, int* __restrict__ gend) {
  int g = threadIdx.x;
  gstart[g] = 0;
  gend[g] = 0;
}

__global__ void graph_bounds_k(const int* __restrict__ batch, int* __restrict__ gstart,
                               int* __restrict__ gend, int n) {
  int i = blockIdx.x * blockDim.x + threadIdx.x;
  if (i >= n) return;
  int b = batch[i];
  if (i == 0) {
    gstart[b] = 0;
  } else {
    int pb = batch[i - 1];
    if (pb != b) { gstart[b] = i; gend[pb] = i; }
  }
  if (i == n - 1) gend[b] = n;
}

__global__ void gcnt_k(const int* __restrict__ gstart, const int* __restrict__ gend,
                       int* __restrict__ gcnt) {
  int g = threadIdx.x;
  gcnt[g] = gend[g] - gstart[g];
}

__global__ __launch_bounds__(256) void scan1_k(const int* __restrict__ cnt, int* __restrict__ rp,
                                               int* __restrict__ bsum, int n) {
  __shared__ int sd[256];
  int t = threadIdx.x;
  int i = blockIdx.x * 256 + t;
  int v = (i < n) ? cnt[i] : 0;
  sd[t] = v;
  __syncthreads();
#pragma unroll
  for (int off = 1; off < 256; off <<= 1) {
    int u = (t >= off) ? sd[t - off] : 0;
    __syncthreads();
    sd[t] += u;
    __syncthreads();
  }
  if (i < n) rp[i] = sd[t] - v;
  if (t == 255) bsum[blockIdx.x] = sd[255];
}

__global__ __launch_bounds__(256) void scan2_k(int* __restrict__ bsum, int nb) {
  __shared__ int sd[256];
  int t = threadIdx.x;
  int v = (t < nb) ? bsum[t] : 0;
  sd[t] = v;
  __syncthreads();
#pragma unroll
  for (int off = 1; off < 256; off <<= 1) {
    int u = (t >= off) ? sd[t - off] : 0;
    __syncthreads();
    sd[t] += u;
    __syncthreads();
  }
  if (t < nb) bsum[t] = sd[t] - v;
}

__global__ __launch_bounds__(256) void scan3_k(int* __restrict__ rp, const int* __restrict__ bsum,
                                               int* __restrict__ cur, const int* __restrict__ cnt,
                                               float* __restrict__ dinv, int n, int E) {
  int i = blockIdx.x * 256 + threadIdx.x;
  if (i < n) {
    int r = rp[i] + bsum[blockIdx.x];
    rp[i] = r;
    cur[i] = r;
    dinv[i] = rsqrtf((float)cnt[i] + 1.0f);
  }
  if (i == 0) rp[n] = E;
}

__global__ __launch_bounds__(256) void fill_csr_xcd_k(const int* __restrict__ src,
                                                      const int* __restrict__ dst,
                                                      int* __restrict__ cur,
                                                      unsigned short* __restrict__ col,
                                                      int E, int slice) {
  int pass = blockIdx.x & (NXCD - 1);
  int e = (blockIdx.x >> 3) * 256 + threadIdx.x;
  if (e >= E) return;
  int d = dst[e];
  if ((unsigned)(d - pass * slice) < (unsigned)slice) {
    int p = atomicAdd(&cur[d], 1);
    col[p] = (unsigned short)src[e];
  }
}

// ======================= Weight pack into MFMA B-fragment order (all 5 in one launch) ====
__global__ void packAll_k(const float* __restrict__ B0, const float* __restrict__ B1,
                          const float* __restrict__ B2, const float* __restrict__ B3,
                          const float* __restrict__ B4,
                          unsigned short* __restrict__ P0, unsigned short* __restrict__ P1,
                          unsigned short* __restrict__ P2, unsigned short* __restrict__ P3,
                          unsigned short* __restrict__ P4) {
  int b = blockIdx.x;
  const float* B;
  unsigned short* P;
  int ldb, base;
  if (b < 8)       { B = B0; P = P0; ldb = 128; base = b; }
  else if (b < 16) { B = B1; P = P1; ldb = 128; base = b - 8; }
  else if (b < 24) { B = B2; P = P2; ldb = 128; base = b - 16; }
  else if (b < 32) { B = B3; P = P3; ldb = 128; base = b - 24; }
  else             { B = B4; P = P4; ldb = 64;  base = b - 32; }
  int idx = base * 256 + threadIdx.x;
  int lane = idx & 63;
  int kc = (idx >> 6) & 3;
  int c = idx >> 8;
  int kb = kc * 32 + (lane >> 4) * 8;
  int colq = c * 16 + (lane & 15);
  unsigned short o[8];
#pragma unroll
  for (int j = 0; j < 8; ++j) o[j] = bf16u(B[(size_t)(kb + j) * ldb + colq]);
  uint4 p;
  p.x = (unsigned)o[0] | ((unsigned)o[1] << 16);
  p.y = (unsigned)o[2] | ((unsigned)o[3] << 16);
  p.z = (unsigned)o[4] | ((unsigned)o[5] << 16);
  p.w = (unsigned)o[6] | ((unsigned)o[7] << 16);
  *(uint4*)&P[(size_t)idx * 8] = p;
}

// ======================= MFMA GEMM: [M,128]x[128,128] + fused extras ==================
// Af != null: read f32 A and convert in-register (projection path, no cast kernel).
__global__ __launch_bounds__(256) void gemm_mfma_k(const unsigned short* __restrict__ Ab,
                                                   const float* __restrict__ Af,
                                                   const unsigned short* __restrict__ Bp,
                                                   const float* __restrict__ bias,
                                                   float* __restrict__ Cf,
                                                   unsigned short* __restrict__ Cb,
                                                   const float* __restrict__ rowscale,
                                                   const float* __restrict__ as_flat,
                                                   const float* __restrict__ ad_flat,
                                                   float* __restrict__ es, float* __restrict__ ed,
                                                   int M) {
  __shared__ unsigned short Bs[16384];
  int t = threadIdx.x;
  for (int i = t; i < 2048; i += 256) ((uint4*)Bs)[i] = ((const uint4*)Bp)[i];
  __syncthreads();
  int w = t >> 6, lane = t & 63;
  int row0 = blockIdx.x * 64 + w * 16;
  int arow = row0 + (lane & 15);
  f32x4 acc[8];
#pragma unroll
  for (int c = 0; c < 8; ++c) acc[c] = {0.f, 0.f, 0.f, 0.f};
#pragma unroll
  for (int kc = 0; kc < 4; ++kc) {
    bf16x8 a = {0, 0, 0, 0, 0, 0, 0, 0};
    if (arow < M) {
      if (Af) {
        const float4* ap = (const float4*)&Af[(size_t)arow * 128 + kc * 32 + (lane >> 4) * 8];
        float4 f0 = ap[0], f1 = ap[1];
        a[0] = (short)bf16u(f0.x); a[1] = (short)bf16u(f0.y);
        a[2] = (short)bf16u(f0.z); a[3] = (short)bf16u(f0.w);
        a[4] = (short)bf16u(f1.x); a[5] = (short)bf16u(f1.y);
        a[6] = (short)bf16u(f1.z); a[7] = (short)bf16u(f1.w);
      } else {
        a = *(const bf16x8*)&Ab[(size_t)arow * 128 + kc * 32 + (lane >> 4) * 8];
      }
    }
#pragma unroll
    for (int c = 0; c < 8; ++c) {
      bf16x8 b = *(const bf16x8*)&Bs[((c * 4 + kc) * 64 + lane) * 8];
      acc[c] = __builtin_amdgcn_mfma_f32_16x16x32_bf16(a, b, acc[c], 0, 0, 0);
    }
  }
  int l15 = lane & 15;
  int rbase = row0 + (lane >> 4) * 4;
#pragma unroll
  for (int c = 0; c < 8; ++c) {
    int colq = c * 16 + l15;
    float bb = bias ? bias[colq] : 0.f;
#pragma unroll
    for (int r = 0; r < 4; ++r) {
      int row = rbase + r;
      if (row < M) {
        float v = acc[c][r] + bb;
        if (Cf) Cf[(size_t)row * 128 + colq] = v;
        if (Cb) {
          float rs = rowscale ? rowscale[row] : 1.f;
          Cb[(size_t)row * 128 + colq] = bf16u(v * rs);
        }
      }
    }
  }
  if (as_flat) {
    float pe[4][4], pd[4][4];
#pragma unroll
    for (int h = 0; h < 4; ++h) {
      float a0 = as_flat[h * 32 + l15], a1 = as_flat[h * 32 + 16 + l15];
      float d0 = ad_flat[h * 32 + l15], d1 = ad_flat[h * 32 + 16 + l15];
#pragma unroll
      for (int r = 0; r < 4; ++r) {
        pe[h][r] = acc[2 * h][r] * a0 + acc[2 * h + 1][r] * a1;
        pd[h][r] = acc[2 * h][r] * d0 + acc[2 * h + 1][r] * d1;
      }
    }
#pragma unroll
    for (int off = 1; off < 16; off <<= 1) {
#pragma unroll
      for (int h = 0; h < 4; ++h)
#pragma unroll
        for (int r = 0; r < 4; ++r) {
          pe[h][r] += __shfl_xor(pe[h][r], off, 64);
          pd[h][r] += __shfl_xor(pd[h][r], off, 64);
        }
    }
    int hh = l15 & 3, rr = l15 >> 2;
    int row = rbase + rr;
    if (row < M) {
      es[row * 4 + hh] = pe[hh][rr];
      ed[row * 4 + hh] = pd[hh][rr];
    }
  }
}

// ======================= GCN aggregation (predicated 16-edge loop, bf16 out) ============
__global__ __launch_bounds__(256) void gcn_gather_k(const uint4* __restrict__ xw16,
                                                    const int* __restrict__ rp,
                                                    const unsigned short* __restrict__ col,
                                                    const float* __restrict__ dinv, const float* __restrict__ bias,
                                                    unsigned short* __restrict__ outb, int n) {
  int i = blockIdx.x * 4 + (threadIdx.x >> 6);
  if (i >= n) return;
  int lane = threadIdx.x & 63;
  int g = lane >> 4, sub = lane & 15;
  int e0 = __builtin_amdgcn_readfirstlane(rp[i]);
  int e1 = __builtin_amdgcn_readfirstlane(rp[i + 1]);
  float acc[8] = {0.f, 0.f, 0.f, 0.f, 0.f, 0.f, 0.f, 0.f};
  if (g == 0) {
    uint4 v = xw16[(size_t)i * 16 + sub];   // row prescaled by dinv[i]
    accum8(acc, v, 1.f);
  }
  for (int e = e0; e < e1; e += 16) {
    int i0 = e + g, i1 = e + 4 + g, i2 = e + 8 + g, i3 = e + 12 + g;
    int s0 = i0 < e1 ? (int)col[i0] : i;
    int s1 = i1 < e1 ? (int)col[i1] : i;
    int s2 = i2 < e1 ? (int)col[i2] : i;
    int s3 = i3 < e1 ? (int)col[i3] : i;
    float w0 = i0 < e1 ? 1.f : 0.f;
    float w1 = i1 < e1 ? 1.f : 0.f;
    float w2 = i2 < e1 ? 1.f : 0.f;
    float w3 = i3 < e1 ? 1.f : 0.f;
    uint4 v0 = xw16[(size_t)s0 * 16 + sub];
    uint4 v1 = xw16[(size_t)s1 * 16 + sub];
    uint4 v2 = xw16[(size_t)s2 * 16 + sub];
    uint4 v3 = xw16[(size_t)s3 * 16 + sub];
    accum8(acc, v0, w0); accum8(acc, v1, w1); accum8(acc, v2, w2); accum8(acc, v3, w3);
  }
#pragma unroll
  for (int k = 0; k < 8; ++k) {
    acc[k] += __shfl_xor(acc[k], 16, 64);
    acc[k] += __shfl_xor(acc[k], 32, 64);
  }
  if (g == 0) {
    float di = dinv[i];
    float4 b0 = ((const float4*)bias)[sub * 2], b1 = ((const float4*)bias)[sub * 2 + 1];
    uint4 p;
    p.x = packbf2(acc[0] * di + b0.x, acc[1] * di + b0.y);
    p.y = packbf2(acc[2] * di + b0.z, acc[3] * di + b0.w);
    p.z = packbf2(acc[4] * di + b1.x, acc[5] * di + b1.y);
    p.w = packbf2(acc[6] * di + b1.z, acc[7] * di + b1.w);
    ((uint4*)outb)[(size_t)i * 16 + sub] = p;
  }
}

// ======================= GAT gather (predicated loop, exp dedup via shfl, bf16 out) =====
__global__ __launch_bounds__(256) void gat_gather_k(const uint4* __restrict__ hf16,
                                                    const int* __restrict__ rp,
                                                    const unsigned short* __restrict__ col,
                                                    const float* __restrict__ es, const float* __restrict__ ed,
                                                    const float* __restrict__ bias,
                                                    unsigned short* __restrict__ outb, int n) {
  int i = blockIdx.x * 4 + (threadIdx.x >> 6);
  if (i >= n) return;
  int lane = threadIdx.x & 63;
  int g = lane >> 4, sub = lane & 15;
  int hh = sub >> 2;
  int e0 = __builtin_amdgcn_readfirstlane(rp[i]);
  int e1 = __builtin_amdgcn_readfirstlane(rp[i + 1]);
  float edi_g = ed[i * 4 + g];
  float acc[8] = {0.f, 0.f, 0.f, 0.f, 0.f, 0.f, 0.f, 0.f};
  float s = 0.f;
  if (g == 0) {
    float esf = es[i * 4 + hh] + ed[i * 4 + hh];
    esf = esf >= 0.f ? esf : 0.2f * esf;
    float wself = __expf(fminf(esf, 80.f));
    uint4 v = hf16[(size_t)i * 16 + sub];
    accum8(acc, v, wself);
    s = wself;
  }
  for (int e = e0; e < e1; e += 16) {
    int el = e + sub;
    bool okl = el < e1;
    int sl = okl ? (int)col[el] : i;
    float tl = es[sl * 4 + g] + edi_g;
    tl = tl >= 0.f ? tl : 0.2f * tl;
    float wl = okl ? __expf(fminf(tl, 80.f)) : 0.f;
    int base = hh << 4;
    float w0 = __shfl(wl, base | g, 64);
    float w1 = __shfl(wl, base | (g + 4), 64);
    float w2 = __shfl(wl, base | (g + 8), 64);
    float w3 = __shfl(wl, base | (g + 12), 64);
    int i0 = e + g, i1 = e + 4 + g, i2 = e + 8 + g, i3 = e + 12 + g;
    int s0 = i0 < e1 ? (int)col[i0] : i;
    int s1 = i1 < e1 ? (int)col[i1] : i;
    int s2 = i2 < e1 ? (int)col[i2] : i;
    int s3 = i3 < e1 ? (int)col[i3] : i;
    uint4 v0 = hf16[(size_t)s0 * 16 + sub];
    uint4 v1 = hf16[(size_t)s1 * 16 + sub];
    uint4 v2 = hf16[(size_t)s2 * 16 + sub];
    uint4 v3 = hf16[(size_t)s3 * 16 + sub];
    accum8(acc, v0, w0); accum8(acc, v1, w1); accum8(acc, v2, w2); accum8(acc, v3, w3);
    s += w0 + w1 + w2 + w3;
  }
#pragma unroll
  for (int k = 0; k < 8; ++k) {
    acc[k] += __shfl_xor(acc[k], 16, 64);
    acc[k] += __shfl_xor(acc[k], 32, 64);
  }
  s += __shfl_xor(s, 16, 64);
  s += __shfl_xor(s, 32, 64);
  if (g == 0) {
    float wi = 1.0f / s;
    float4 b0 = ((const float4*)bias)[sub * 2], b1 = ((const float4*)bias)[sub * 2 + 1];
    uint4 p;
    p.x = packbf2(acc[0] * wi + b0.x, acc[1] * wi + b0.y);
    p.y = packbf2(acc[2] * wi + b0.z, acc[3] * wi + b0.w);
    p.z = packbf2(acc[4] * wi + b1.x, acc[5] * wi + b1.y);
    p.w = packbf2(acc[6] * wi + b1.z, acc[7] * wi + b1.w);
    ((uint4*)outb)[(size_t)i * 16 + sub] = p;
  }
}

// ======================= GraphNorm (bf16 h) =======================
__global__ __launch_bounds__(256) void gn_stats_k(const unsigned short* __restrict__ h,
                                                  const int* __restrict__ gstart,
                                                  const int* __restrict__ gcnt, float* __restrict__ gsum,
                                                  float* __restrict__ gsq) {
  int g = blockIdx.x / SLICES, sl = blockIdx.x % SLICES;
  int st = gstart[g], cn = gcnt[g];
  int d = threadIdx.x & 127, half = threadIdx.x >> 7;
  float s = 0.f, ss = 0.f;
  for (int r = sl * 2 + half; r < cn; r += 2 * SLICES) {
    float v = bfu(h[(size_t)(st + r) * D + d]);
    s += v; ss += v * v;
  }
  __shared__ float l1[128], l2[128];
  if (half) { l1[d] = s; l2[d] = ss; }
  __syncthreads();
  if (!half) {
    atomicAdd(&gsum[g * D + d], s + l1[d]);
    atomicAdd(&gsq[g * D + d], ss + l2[d]);
  }
}

__global__ void gn_finalize_k(const float* __restrict__ gsum, const float* __restrict__ gsq,
                              const int* __restrict__ gcnt, const float* __restrict__ ms,
                              float* __restrict__ mean, float* __restrict__ rstd) {
  int g = blockIdx.x, d = threadIdx.x;
  float cnt = fmaxf((float)gcnt[g], 1.0f);
  float mu = gsum[g * D + d] / cnt;
  float m2 = gsq[g * D + d] / cnt;
  float s = ms[d];
  float var = m2 - (2.0f * s - s * s) * mu * mu;
  mean[g * D + d] = mu;
  rstd[g * D + d] = rsqrtf(fmaxf(var, 0.0f) + 1e-5f);
}

__global__ void gn_apply_k(const unsigned short* __restrict__ h, float* __restrict__ x,
                           unsigned short* __restrict__ xb,
                           const int* __restrict__ batch, const float* __restrict__ mean,
                           const float* __restrict__ rstd, const float* __restrict__ w,
                           const float* __restrict__ b, const float* __restrict__ ms, int n) {
  int idx = blockIdx.x * blockDim.x + threadIdx.x;
  if (idx >= n * 32) return;
  int node = idx >> 5, q = idx & 31;
  int g = batch[node];
  int d0 = q * 4;
  ushort4 hv = ((const ushort4*)h)[idx];
  float4 xv = ((const float4*)x)[idx];
  float ha[4] = {bfu(hv.x), bfu(hv.y), bfu(hv.z), bfu(hv.w)};
  float xa[4] = {xv.x, xv.y, xv.z, xv.w};
  float ra[4];
#pragma unroll
  for (int j = 0; j < 4; ++j) {
    int d = d0 + j;
    float sub = ha[j] - ms[d] * mean[g * D + d];
    float v = w[d] * sub * rstd[g * D + d] + b[d];
    ra[j] = fmaxf(v, 0.f) + xa[j];
  }
  ((float4*)x)[idx] = make_float4(ra[0], ra[1], ra[2], ra[3]);
  ushort4 o;
  o.x = bf16u(ra[0]); o.y = bf16u(ra[1]); o.z = bf16u(ra[2]); o.w = bf16u(ra[3]);
  ((ushort4*)xb)[idx] = o;
}

// ======================= Hub scores (MFMA) =======================
__global__ __launch_bounds__(256) void hub_mfma_k(const unsigned short* __restrict__ Xb,
                                                  const unsigned short* __restrict__ W1p,
                                                  const float* __restrict__ nb1, const float* __restrict__ nw2,
                                                  const float* __restrict__ nb2, float* __restrict__ out, int n) {
  __shared__ unsigned short Bs[8192];
  int t = threadIdx.x;
  for (int i = t; i < 1024; i += 256) ((uint4*)Bs)[i] = ((const uint4*)W1p)[i];
  __syncthreads();
  int w = t >> 6, lane = t & 63;
  int row0 = blockIdx.x * 64 + w * 16;
  int arow = row0 + (lane & 15);
  f32x4 acc[4];
#pragma unroll
  for (int c = 0; c < 4; ++c) acc[c] = {0.f, 0.f, 0.f, 0.f};
#pragma unroll
  for (int kc = 0; kc < 4; ++kc) {
    bf16x8 a = {0, 0, 0, 0, 0, 0, 0, 0};
    if (arow < n) a = *(const bf16x8*)&Xb[(size_t)arow * 128 + kc * 32 + (lane >> 4) * 8];
#pragma unroll
    for (int c = 0; c < 4; ++c) {
      bf16x8 b = *(const bf16x8*)&Bs[((c * 4 + kc) * 64 + lane) * 8];
      acc[c] = __builtin_amdgcn_mfma_f32_16x16x32_bf16(a, b, acc[c], 0, 0, 0);
    }
  }
  float b2 = nb2[0];
  float s[4] = {0.f, 0.f, 0.f, 0.f};
#pragma unroll
  for (int c = 0; c < 4; ++c) {
    int colq = c * 16 + (lane & 15);
    float b1 = nb1[colq];
    float w2 = nw2[colq];
#pragma unroll
    for (int r = 0; r < 4; ++r) s[r] += fmaxf(acc[c][r] + b1, 0.f) * w2;
  }
#pragma unroll
  for (int off = 1; off < 16; off <<= 1) {
#pragma unroll
    for (int r = 0; r < 4; ++r) s[r] += __shfl_xor(s[r], off, 64);
  }
  if ((lane & 15) == 0) {
    int rbase = row0 + (lane >> 4) * 4;
#pragma unroll
    for (int r = 0; r < 4; ++r) {
      int row = rbase + r;
      if (row < n) out[row] = 1.0f / (1.0f + __expf(-(s[r] + b2)));
    }
  }
}

// ======================= Pooling =======================
__global__ void init_maxu_k(unsigned* __restrict__ p, int n) {
  int i = blockIdx.x * blockDim.x + threadIdx.x;
  if (i < n) p[i] = 0x007FFFFFu;
}

__global__ __launch_bounds__(256) void pool_stats_k(const float* __restrict__ x, const int* __restrict__ gstart,
                                                    const int* __restrict__ gcnt, float* __restrict__ gsum,
                                                    unsigned* __restrict__ gmaxu) {
  int g = blockIdx.x / SLICES, sl = blockIdx.x % SLICES;
  int st = gstart[g], cn = gcnt[g];
  int d = threadIdx.x & 127, half = threadIdx.x >> 7;
  float s = 0.f, mx = __uint_as_float(0xFF800000u);
  for (int r = sl * 2 + half; r < cn; r += 2 * SLICES) {
    float v = x[(size_t)(st + r) * D + d];
    s += v; mx = fmaxf(mx, v);
  }
  __shared__ float l1[128], l2[128];
  if (half) { l1[d] = s; l2[d] = mx; }
  __syncthreads();
  if (!half) {
    s += l1[d];
    mx = fmaxf(mx, l2[d]);
    atomicAdd(&gsum[g * D + d], s);
    unsigned u = __float_as_uint(mx);
    u = (u & 0x80000000u) ? ~u : (u | 0x80000000u);
    atomicMax(&gmaxu[g * D + d], u);
  }
}

__global__ void pool_fin_k(const float* __restrict__ gsum, const unsigned* __restrict__ gmaxu,
                           const int* __restrict__ gcnt, float* __restrict__ gf) {
  int g = blockIdx.x, d = threadIdx.x;
  float cnt = fmaxf((float)gcnt[g], 1.0f);
  gf[g * 256 + d] = gsum[g * D + d] / cnt;
  unsigned u = gmaxu[g * D + d];
  unsigned bits = (u & 0x80000000u) ? (u ^ 0x80000000u) : ~u;
  gf[g * 256 + 128 + d] = __uint_as_float(bits);
}

// ======================= Graph MLP =======================
__global__ __launch_bounds__(128) void mlp_k(const float* __restrict__ gf, const float* __restrict__ hw1,
                                             const float* __restrict__ hb1, const float* __restrict__ hw2,
                                             const float* __restrict__ hb2, const float* __restrict__ hw3,
                                             const float* __restrict__ hb3, float* __restrict__ logits) {
  __shared__ float sg[256], z1[128], z2[64];
  int g = blockIdx.x, t = threadIdx.x;
  sg[t] = gf[g * 256 + t];
  sg[t + 128] = gf[g * 256 + 128 + t];
  __syncthreads();
  float a = hb1[t];
  for (int k = 0; k < 256; ++k) a += sg[k] * hw1[k * 128 + t];
  z1[t] = fmaxf(a, 0.f);
  __syncthreads();
  if (t < 64) {
    float a2 = hb2[t];
    for (int k = 0; k < 128; ++k) a2 += z1[k] * hw2[k * 64 + t];
    z2[t] = fmaxf(a2, 0.f);
  }
  __syncthreads();
  if (t < 2) {
    float a3 = hb3[t];
    for (int k = 0; k < 64; ++k) a3 += z2[k] * hw3[k * 2 + t];
    logits[g * 2 + t] = a3;
  }
}

// ======================= Host =======================
extern "C" void kernel_launch(void* const* d_in, const int* in_sizes, int n_in,
                              void* d_out, int out_size, void* d_ws, size_t ws_size,
                              hipStream_t stream) {
  const float* x_in  = (const float*)d_in[0];
  const int*   eidx  = (const int*)d_in[1];
  const int*   batch = (const int*)d_in[2];
  const float* Wp  = (const float*)d_in[3];
  const float* bp  = (const float*)d_in[4];
  const float* Wg  = (const float*)d_in[5];
  const float* bg  = (const float*)d_in[6];
  const float* Wa1 = (const float*)d_in[7];
  const float* as1 = (const float*)d_in[8];
  const float* ad1 = (const float*)d_in[9];
  const float* ba1 = (const float*)d_in[10];
  const float* Wa2 = (const float*)d_in[11];
  const float* as2 = (const float*)d_in[12];
  const float* ad2 = (const float*)d_in[13];
  const float* ba2 = (const float*)d_in[14];
  const float* gnw[3] = {(const float*)d_in[15], (const float*)d_in[18], (const float*)d_in[21]};
  const float* gnb[3] = {(const float*)d_in[16], (const float*)d_in[19], (const float*)d_in[22]};
  const float* gns[3] = {(const float*)d_in[17], (const float*)d_in[20], (const float*)d_in[23]};
  const float* hw1 = (const float*)d_in[24];
  const float* hb1 = (const float*)d_in[25];
  const float* hw2 = (const float*)d_in[26];
  const float* hb2 = (const float*)d_in[27];
  const float* hw3 = (const float*)d_in[28];
  const float* hb3 = (const float*)d_in[29];
  const float* nw1 = (const float*)d_in[30];
  const float* nb1 = (const float*)d_in[31];
  const float* nw2 = (const float*)d_in[32];
  const float* nb2 = (const float*)d_in[33];

  const int N = in_sizes[0] / D;
  const int E = in_sizes[1] / 2;
  const int* src = eidx;
  const int* dst = eidx + E;

  float* out    = (float*)d_out;
  float* logits = out;
  float* hub    = out + GG * 2;
  float* gf     = out + GG * 2 + N;
  float* X      = out + GG * 2 + N + GG * 256;

  char* wp = (char*)d_ws;
  auto alloc = [&](size_t bytes) { char* p = wp; wp += (bytes + 255) & ~(size_t)255; return p; };
  unsigned short* B2 = (unsigned short*)alloc((size_t)N * D * 2);   // bf16 agg output
  unsigned* B1h   = (unsigned*)alloc((size_t)N * (D / 2) * 4);
  unsigned short* Xb = (unsigned short*)alloc((size_t)N * D * 2);
  unsigned short* col = (unsigned short*)alloc((size_t)E * 2);
  int*   cnt     = (int*)alloc((size_t)N * 4);
  int*   rowp    = (int*)alloc((size_t)(N + 1) * 4);
  int*   cur     = (int*)alloc((size_t)N * 4);
  float* dinv    = (float*)alloc((size_t)N * 4);
  float* es      = (float*)alloc((size_t)N * 4 * 4);
  float* ed      = (float*)alloc((size_t)N * 4 * 4);
  float* gsum    = (float*)alloc((size_t)GG * D * 4);
  float* gsq     = (float*)alloc((size_t)GG * D * 4);
  unsigned* gmaxu = (unsigned*)alloc((size_t)GG * D * 4);
  float* mean    = (float*)alloc((size_t)GG * D * 4);
  float* rstd    = (float*)alloc((size_t)GG * D * 4);
  int*   gcnt    = (int*)alloc((size_t)GG * 4);
  int*   gstart  = (int*)alloc((size_t)GG * 4);
  int*   gend    = (int*)alloc((size_t)GG * 4);
  int*   bsum    = (int*)alloc((size_t)256 * 4);
  unsigned short* Wpp  = (unsigned short*)alloc(16384 * 2);
  unsigned short* Wgp  = (unsigned short*)alloc(16384 * 2);
  unsigned short* Wa1p = (unsigned short*)alloc(16384 * 2);
  unsigned short* Wa2p = (unsigned short*)alloc(16384 * 2);
  unsigned short* W1p  = (unsigned short*)alloc(8192 * 2);
  if ((size_t)(wp - (char*)d_ws) > ws_size) return;

  const int nb = (N + 255) / 256;
  const int chunks = (E + 255) / 256;
  const int nslice = (N + NXCD - 1) / NXCD;

  // ---- CSR + graph ranges ----
  hipMemsetAsync(cnt, 0, (size_t)N * 4, stream);
  count_edges_xcd_k<<<chunks * NXCD, 256, 0, stream>>>(dst, cnt, E, nslice);
  bounds_init_k<<<1, GG, 0, stream>>>(gstart, gend);
  graph_bounds_k<<<nb, 256, 0, stream>>>(batch, gstart, gend, N);
  gcnt_k<<<1, GG, 0, stream>>>(gstart, gend, gcnt);
  scan1_k<<<nb, 256, 0, stream>>>(cnt, rowp, bsum, N);
  scan2_k<<<1, 256, 0, stream>>>(bsum, nb);
  scan3_k<<<nb, 256, 0, stream>>>(rowp, bsum, cur, cnt, dinv, N, E);
  fill_csr_xcd_k<<<chunks * NXCD, 256, 0, stream>>>(src, dst, cur, col, E, nslice);

  // ---- weight packs (single launch) ----
  packAll_k<<<36, 256, 0, stream>>>(Wp, Wg, Wa1, Wa2, nw1, Wpp, Wgp, Wa1p, Wa2p, W1p);

  const int gemmGrid = (N + 63) / 64;
  const int aggGrid  = (N + 3) / 4;

  auto graphnorm = [&](int layer) {
    hipMemsetAsync(gsum, 0, 2 * (size_t)GG * D * 4, stream);
    gn_stats_k<<<GG * SLICES, 256, 0, stream>>>(B2, gstart, gcnt, gsum, gsq);
    gn_finalize_k<<<GG, D, 0, stream>>>(gsum, gsq, gcnt, gns[layer], mean, rstd);
    gn_apply_k<<<(N * 32 + 255) / 256, 256, 0, stream>>>(B2, X, Xb, batch, mean, rstd,
                                                         gnw[layer], gnb[layer], gns[layer], N);
  };

  // ---- projection: X = x@Wp + bp (f32 A read in-register) ----
  gemm_mfma_k<<<gemmGrid, 256, 0, stream>>>(nullptr, x_in, Wpp, bp, X, Xb,
                                            nullptr, nullptr, nullptr, nullptr, nullptr, N);

  // ---- GCN layer ----
  gemm_mfma_k<<<gemmGrid, 256, 0, stream>>>(Xb, nullptr, Wgp, nullptr, nullptr, (unsigned short*)B1h,
                                            dinv, nullptr, nullptr, nullptr, nullptr, N);
  gcn_gather_k<<<aggGrid, 256, 0, stream>>>((const uint4*)B1h, rowp, col, dinv, bg, B2, N);
  graphnorm(0);

  // ---- GAT layer 1 ----
  gemm_mfma_k<<<gemmGrid, 256, 0, stream>>>(Xb, nullptr, Wa1p, nullptr, nullptr, (unsigned short*)B1h,
                                            nullptr, as1, ad1, es, ed, N);
  gat_gather_k<<<aggGrid, 256, 0, stream>>>((const uint4*)B1h, rowp, col, es, ed, ba1, B2, N);
  graphnorm(1);

  // ---- GAT layer 2 ----
  gemm_mfma_k<<<gemmGrid, 256, 0, stream>>>(Xb, nullptr, Wa2p, nullptr, nullptr, (unsigned short*)B1h,
                                            nullptr, as2, ad2, es, ed, N);
  gat_gather_k<<<aggGrid, 256, 0, stream>>>((const uint4*)B1h, rowp, col, es, ed, ba2, B2, N);
  graphnorm(2);

  // ---- hub scores (MFMA) ----
  hub_mfma_k<<<gemmGrid, 256, 0, stream>>>(Xb, W1p, nb1, nw2, nb2, hub, N);

  // ---- pooling + graph MLP ----
  hipMemsetAsync(gsum, 0, (size_t)GG * D * 4, stream);
  init_maxu_k<<<(GG * D + 255) / 256, 256, 0, stream>>>(gmaxu, GG * D);
  pool_stats_k<<<GG * SLICES, 256, 0, stream>>>(X, gstart, gcnt, gsum, gmaxu);
  pool_fin_k<<<GG, D, 0, stream>>>(gsum, gmaxu, gcnt, gf);
  mlp_k<<<GG, 128, 0, stream>>>(gf, hw1, hb1, hw2, hb2, hw3, hb3, logits);
}